// Round 1
// baseline (3088.177 us; speedup 1.0000x reference)
//
#include <hip/hip_runtime.h>
#include <hip/hip_bf16.h>

#define B_ 16
#define C_ 2048
#define N_ 256
#define HEADS_ 4
#define D_ 512

#define TM 64
#define TN 64
#define TK 16

// Generic f32 tiled GEMM: C[m,n] = scale * sum_k A[m,k]*B[k,n] + bias[m] (+ escore[n]*ex[m,n])
// A addressed as A[m*sa_m + k*sa_k], B as B[k*sb_k + n*sb_n].
// Grid: blockIdx.x covers N/64 tiles, blockIdx.y covers M/64 tiles. 256 threads.
// All dims assumed multiples of tile sizes (true for every instance here).
__device__ __forceinline__ void gemm_f32(
    const float* __restrict__ A, int sa_m, int sa_k,
    const float* __restrict__ B, int sb_k, int sb_n,
    int K, float scale,
    const float* __restrict__ bias,    // per-m, nullable
    const float* __restrict__ escore,  // per-n, nullable (used with ex)
    const float* __restrict__ ex,      // [m, N_] row-major, nullable
    float* __restrict__ Cp, int sc_m)
{
    __shared__ float As[TK][TM + 4];   // stride 68 floats = 272 B (16B-aligned rows, conflict-free)
    __shared__ float Bs[TK][TN + 4];

    const int tid = threadIdx.x;
    const int tx = tid & 15;   // n-group
    const int ty = tid >> 4;   // m-group
    const int bm = blockIdx.y * TM;
    const int bn = blockIdx.x * TN;

    float acc[4][4];
#pragma unroll
    for (int i = 0; i < 4; ++i)
#pragma unroll
        for (int j = 0; j < 4; ++j) acc[i][j] = 0.f;

    for (int k0 = 0; k0 < K; k0 += TK) {
        // ---- load A tile (64m x 16k) ----
        if (sa_k == 1) {
#pragma unroll
            for (int r = 0; r < 4; ++r) {
                int idx = tid + r * 256;
                int kk = idx & 15, m = idx >> 4;
                As[kk][m] = A[(size_t)(bm + m) * sa_m + (k0 + kk)];
            }
        } else {
#pragma unroll
            for (int r = 0; r < 4; ++r) {
                int idx = tid + r * 256;
                int m = idx & 63, kk = idx >> 6;
                As[kk][m] = A[(size_t)(bm + m) * sa_m + (size_t)(k0 + kk) * sa_k];
            }
        }
        // ---- load B tile (16k x 64n) ----
        if (sb_n == 1) {
#pragma unroll
            for (int r = 0; r < 4; ++r) {
                int idx = tid + r * 256;
                int n = idx & 63, kk = idx >> 6;
                Bs[kk][n] = B[(size_t)(k0 + kk) * sb_k + (bn + n)];
            }
        } else {
#pragma unroll
            for (int r = 0; r < 4; ++r) {
                int idx = tid + r * 256;
                int kk = idx & 15, n = idx >> 4;
                Bs[kk][n] = B[(size_t)(k0 + kk) + (size_t)(bn + n) * sb_n];
            }
        }
        __syncthreads();

#pragma unroll
        for (int kk = 0; kk < TK; ++kk) {
            const float4 a = *reinterpret_cast<const float4*>(&As[kk][ty * 4]);
            const float4 b = *reinterpret_cast<const float4*>(&Bs[kk][tx * 4]);
            acc[0][0] += a.x * b.x; acc[0][1] += a.x * b.y; acc[0][2] += a.x * b.z; acc[0][3] += a.x * b.w;
            acc[1][0] += a.y * b.x; acc[1][1] += a.y * b.y; acc[1][2] += a.y * b.z; acc[1][3] += a.y * b.w;
            acc[2][0] += a.z * b.x; acc[2][1] += a.z * b.y; acc[2][2] += a.z * b.z; acc[2][3] += a.z * b.w;
            acc[3][0] += a.w * b.x; acc[3][1] += a.w * b.y; acc[3][2] += a.w * b.z; acc[3][3] += a.w * b.w;
        }
        __syncthreads();
    }

    // ---- epilogue ----
    const int n0 = bn + tx * 4;
#pragma unroll
    for (int i = 0; i < 4; ++i) {
        const int m = bm + ty * 4 + i;
        const float bi = bias ? bias[m] : 0.0f;
        float4 v;
        v.x = acc[i][0] * scale + bi;
        v.y = acc[i][1] * scale + bi;
        v.z = acc[i][2] * scale + bi;
        v.w = acc[i][3] * scale + bi;
        if (ex) {
            const float4 xe = *reinterpret_cast<const float4*>(&ex[(size_t)m * N_ + n0]);
            const float4 sc = *reinterpret_cast<const float4*>(&escore[n0]);
            v.x += sc.x * xe.x; v.y += sc.y * xe.y; v.z += sc.z * xe.z; v.w += sc.w * xe.w;
        }
        *reinterpret_cast<float4*>(&Cp[(size_t)m * sc_m + n0]) = v;
    }
}

// ---- stage 1: Qt[bh][d][n], Kt[bh][d][n] = W @ x[b] + bias ----
__global__ __launch_bounds__(256) void k_proj(
    const float* __restrict__ x,
    const float* __restrict__ qw, const float* __restrict__ qb,
    const float* __restrict__ kw, const float* __restrict__ kb,
    float* __restrict__ Qt, float* __restrict__ Kt)
{
    const int z = blockIdx.z;          // 0..127
    const int isK = z >> 6;
    const int bh = z & 63;
    const int b = bh >> 2, h = bh & 3;
    const float* W = (isK ? kw : qw) + (size_t)h * D_ * C_;
    const float* bias = (isK ? kb : qb) + h * D_;
    const float* Bx = x + (size_t)b * C_ * N_;
    float* out = (isK ? Kt : Qt) + (size_t)bh * D_ * N_;
    gemm_f32(W, C_, 1, Bx, N_, 1, C_, 1.0f, bias, nullptr, nullptr, out, N_);
}

// ---- stage 2: sim[bh][q][k] = Qt^T @ Kt / sqrt(512) ----
__global__ __launch_bounds__(256) void k_sim(
    const float* __restrict__ Qt, const float* __restrict__ Kt, float* __restrict__ simP)
{
    const int bh = blockIdx.z;
    gemm_f32(Qt + (size_t)bh * D_ * N_, 1, N_,
             Kt + (size_t)bh * D_ * N_, N_, 1,
             D_, 0.044194173824159216f, nullptr, nullptr, nullptr,
             simP + (size_t)bh * N_ * N_, N_);
}

// ---- stage 3: att[bh][k] = sum_q sim[bh][q][k] ----
__global__ __launch_bounds__(256) void k_att(const float* __restrict__ simP, float* __restrict__ att)
{
    const int bh = blockIdx.x;
    const int k = threadIdx.x;
    const float* s = simP + (size_t)bh * N_ * N_;
    float sum = 0.f;
    for (int q = 0; q < N_; ++q) sum += s[(size_t)q * N_ + k];
    att[bh * N_ + k] = sum;
}

// ---- stage 4: score[b][h][k] = softmax over h of att; also writes output 0 ----
__global__ __launch_bounds__(256) void k_score(
    const float* __restrict__ att, float* __restrict__ score, float* __restrict__ out0)
{
    const int b = blockIdx.x;
    const int k = threadIdx.x;
    float a0 = att[(b * 4 + 0) * N_ + k];
    float a1 = att[(b * 4 + 1) * N_ + k];
    float a2 = att[(b * 4 + 2) * N_ + k];
    float a3 = att[(b * 4 + 3) * N_ + k];
    float mx = fmaxf(fmaxf(a0, a1), fmaxf(a2, a3));
    float e0 = expf(a0 - mx), e1 = expf(a1 - mx), e2 = expf(a2 - mx), e3 = expf(a3 - mx);
    float inv = 1.0f / (e0 + e1 + e2 + e3);
    float s0 = e0 * inv, s1 = e1 * inv, s2 = e2 * inv, s3 = e3 * inv;
    score[(b * 4 + 0) * N_ + k] = s0; out0[(b * 4 + 0) * N_ + k] = s0;
    score[(b * 4 + 1) * N_ + k] = s1; out0[(b * 4 + 1) * N_ + k] = s1;
    score[(b * 4 + 2) * N_ + k] = s2; out0[(b * 4 + 2) * N_ + k] = s2;
    score[(b * 4 + 3) * N_ + k] = s3; out0[(b * 4 + 3) * N_ + k] = s3;
}

// ---- stage 5: P = softmax(sim, axis=k), in place. One wave per row. ----
__global__ __launch_bounds__(64) void k_softP(float* __restrict__ simP)
{
    const size_t row = blockIdx.x;   // 0..16383  (bh*256 + q)
    float* p = simP + row * N_;
    const int t = threadIdx.x;
    float v0 = p[t], v1 = p[t + 64], v2 = p[t + 128], v3 = p[t + 192];
    float mx = fmaxf(fmaxf(v0, v1), fmaxf(v2, v3));
#pragma unroll
    for (int o = 32; o; o >>= 1) mx = fmaxf(mx, __shfl_xor(mx, o, 64));
    float e0 = expf(v0 - mx), e1 = expf(v1 - mx), e2 = expf(v2 - mx), e3 = expf(v3 - mx);
    float s = e0 + e1 + e2 + e3;
#pragma unroll
    for (int o = 32; o; o >>= 1) s += __shfl_xor(s, o, 64);
    const float inv = 1.0f / s;
    p[t] = e0 * inv; p[t + 64] = e1 * inv; p[t + 128] = e2 * inv; p[t + 192] = e3 * inv;
}

// ---- stage 6: T[bh][c][q] = x[b] @ P^T ----
__global__ __launch_bounds__(256) void k_T(
    const float* __restrict__ x, const float* __restrict__ simP, float* __restrict__ T)
{
    const int bh = blockIdx.z;
    const int b = bh >> 2;
    gemm_f32(x + (size_t)b * C_ * N_, N_, 1,
             simP + (size_t)bh * N_ * N_, 1, N_,
             N_, 1.0f, nullptr, nullptr, nullptr,
             T + (size_t)bh * C_ * N_, N_);
}

// ---- stage 7: out1[bh][e][n] = v_w[h] @ T[bh] + v_b[h][e] + score[bh][n]*x[b][e][n] ----
__global__ __launch_bounds__(256) void k_out(
    const float* __restrict__ vw, const float* __restrict__ vb,
    const float* __restrict__ T, const float* __restrict__ score,
    const float* __restrict__ x, float* __restrict__ out1)
{
    const int bh = blockIdx.z;
    const int b = bh >> 2, h = bh & 3;
    gemm_f32(vw + (size_t)h * C_ * C_, C_, 1,
             T + (size_t)bh * C_ * N_, N_, 1,
             C_, 1.0f, vb + h * C_,
             score + (size_t)bh * N_, x + (size_t)b * C_ * N_,
             out1 + (size_t)bh * C_ * N_, N_);
}

extern "C" void kernel_launch(void* const* d_in, const int* in_sizes, int n_in,
                              void* d_out, int out_size, void* d_ws, size_t ws_size,
                              hipStream_t stream)
{
    const float* x  = (const float*)d_in[0];
    const float* qw = (const float*)d_in[1];
    const float* qb = (const float*)d_in[2];
    const float* kw = (const float*)d_in[3];
    const float* kb = (const float*)d_in[4];
    const float* vw = (const float*)d_in[5];
    const float* vb = (const float*)d_in[6];

    float* out0 = (float*)d_out;                      // [B,4,16,16] = 16384 floats
    float* out1 = out0 + (size_t)B_ * HEADS_ * N_;    // [B,4*2048,16,16]

    float* ws   = (float*)d_ws;
    float* Qt   = ws;                                   // B*H*D*N  = 8388608
    float* Kt   = Qt   + (size_t)B_ * HEADS_ * D_ * N_; // 8388608
    float* simP = Kt   + (size_t)B_ * HEADS_ * D_ * N_; // B*H*N*N = 4194304
    float* att  = simP + (size_t)B_ * HEADS_ * N_ * N_; // 16384
    float* score= att  + (size_t)B_ * HEADS_ * N_;      // 16384
    float* T    = score+ (size_t)B_ * HEADS_ * N_;      // B*H*C*N = 33554432

    // stage 1: Q/K projections (2 * 17.2 GF)
    k_proj<<<dim3(N_ / TN, D_ / TM, B_ * HEADS_ * 2), 256, 0, stream>>>(x, qw, qb, kw, kb, Qt, Kt);
    // stage 2: sim (4.3 GF)
    k_sim<<<dim3(N_ / TN, N_ / TM, B_ * HEADS_), 256, 0, stream>>>(Qt, Kt, simP);
    // stage 3: column sums of sim
    k_att<<<dim3(B_ * HEADS_), 256, 0, stream>>>(simP, att);
    // stage 4: head-softmax -> score + output 0
    k_score<<<dim3(B_), 256, 0, stream>>>(att, score, out0);
    // stage 5: row-softmax of sim -> P (in place)
    k_softP<<<dim3(B_ * HEADS_ * N_), 64, 0, stream>>>(simP);
    // stage 6: T = x @ P^T (17.2 GF)
    k_T<<<dim3(N_ / TN, C_ / TM, B_ * HEADS_), 256, 0, stream>>>(x, simP, T);
    // stage 7: out1 = v_w @ T + v_b + score*x (137 GF)
    k_out<<<dim3(N_ / TN, C_ / TM, B_ * HEADS_), 256, 0, stream>>>(vw, vb, T, score, x, out1);
}

// Round 2
// 670.727 us; speedup vs baseline: 4.6042x; 4.6042x over previous
//
#include <hip/hip_runtime.h>
#include <hip/hip_bf16.h>

#define B_ 16
#define C_ 2048
#define N_ 256
#define HEADS_ 4
#define D_ 512

typedef unsigned int u32;
typedef unsigned short ushort_t;
typedef __attribute__((ext_vector_type(8))) short bfx8;   // 8 bf16 in 4 VGPRs
typedef __attribute__((ext_vector_type(4))) float fx4;

__device__ __forceinline__ unsigned short f2bs(float f) {
    __hip_bfloat16 h = __float2bfloat16(f);
    return __builtin_bit_cast(unsigned short, h);
}

__device__ __forceinline__ void gload16(const void* g, void* l) {
    __builtin_amdgcn_global_load_lds((const __attribute__((address_space(1))) u32*)g,
                                     (__attribute__((address_space(3))) u32*)l, 16, 0, 0);
}

// ---------------- MFMA NT GEMM core: C[m][n] = scale*sum_k A[m][k]*B[n][k] + ... -------------
// A, Bm pre-offset to this block's 128-row / 128-col tile. K multiple of 32.
// Per-block tile 128x128, 4 waves in 2x2, each wave 64x64 via 4x4 frags of 16x16x32.
template<int OUTF32, int COLB, int ROWB, int ENH>
__device__ __forceinline__ void mfma_nt(
    const ushort_t* __restrict__ A, const ushort_t* __restrict__ Bm, int K, float scale,
    const float* __restrict__ rowb, const float* __restrict__ colb,
    const float* __restrict__ scor, const float* __restrict__ ex, int exld,
    void* __restrict__ Cq, int ldc)
{
    __shared__ __align__(16) ushort_t As[128 * 32];
    __shared__ __align__(16) ushort_t Bs[128 * 32];

    const int tid = threadIdx.x;
    const int lane = tid & 63, wave = tid >> 6;
    const int l16 = lane & 15, lhi = lane >> 4;
    const int wm = (wave >> 1) * 64, wn = (wave & 1) * 64;

    fx4 acc[4][4];
#pragma unroll
    for (int i = 0; i < 4; ++i)
#pragma unroll
        for (int j = 0; j < 4; ++j) acc[i][j] = (fx4){0.f, 0.f, 0.f, 0.f};

    for (int k0 = 0; k0 < K; k0 += 32) {
#pragma unroll
        for (int i = 0; i < 2; ++i) {
            int f = i * 256 + tid;
            gload16(A + (size_t)(f >> 2) * K + k0 + (f & 3) * 8, As + f * 8);
        }
#pragma unroll
        for (int i = 0; i < 2; ++i) {
            int f = i * 256 + tid;
            gload16(Bm + (size_t)(f >> 2) * K + k0 + (f & 3) * 8, Bs + f * 8);
        }
        __syncthreads();

        bfx8 af[4], bfr[4];
#pragma unroll
        for (int i = 0; i < 4; ++i)
            af[i] = *(const bfx8*)(As + (wm + i * 16 + l16) * 32 + lhi * 8);
#pragma unroll
        for (int j = 0; j < 4; ++j)
            bfr[j] = *(const bfx8*)(Bs + (wn + j * 16 + l16) * 32 + lhi * 8);
#pragma unroll
        for (int i = 0; i < 4; ++i)
#pragma unroll
            for (int j = 0; j < 4; ++j)
                acc[i][j] = __builtin_amdgcn_mfma_f32_16x16x32_bf16(af[i], bfr[j], acc[i][j], 0, 0, 0);
        __syncthreads();
    }

#pragma unroll
    for (int i = 0; i < 4; ++i) {
#pragma unroll
        for (int j = 0; j < 4; ++j) {
#pragma unroll
            for (int r = 0; r < 4; ++r) {
                const int cm = wm + i * 16 + lhi * 4 + r;
                const int cn = wn + j * 16 + l16;
                float v = acc[i][j][r] * scale;
                if (ROWB) v += rowb[cm];
                if (COLB) v += colb[cn];
                if (ENH)  v += scor[cn] * ex[(size_t)cm * exld + cn];
                if (OUTF32) ((float*)Cq)[(size_t)cm * ldc + cn] = v;
                else        ((ushort_t*)Cq)[(size_t)cm * ldc + cn] = f2bs(v);
            }
        }
    }
}

// ---------------- casts ----------------
__global__ __launch_bounds__(256) void k_castw(const float* __restrict__ s, ushort_t* __restrict__ d, int n) {
    int i = (blockIdx.x * 256 + threadIdx.x) * 4;
    if (i >= n) return;
    float4 v = *(const float4*)(s + i);
    ushort4 o = { f2bs(v.x), f2bs(v.y), f2bs(v.z), f2bs(v.w) };
    *(ushort4*)(d + i) = o;
}

// x[b][c][n] -> xb (bf16 same layout) + xbT (bf16 [b][n][c])
__global__ __launch_bounds__(256) void k_cast_x(const float* __restrict__ x,
                                                ushort_t* __restrict__ xb, ushort_t* __restrict__ xbT) {
    __shared__ float t[32][33];
    const int b = blockIdx.z, c0 = blockIdx.y * 32, n0 = blockIdx.x * 32;
    const int tn = threadIdx.x & 31, tc8 = threadIdx.x >> 5;
    const float* xp = x + ((size_t)b * C_ + c0) * N_ + n0;
#pragma unroll
    for (int p = 0; p < 4; ++p) {
        int cc = tc8 + p * 8;
        float v = xp[(size_t)cc * N_ + tn];
        t[cc][tn] = v;
        xb[((size_t)b * C_ + c0 + cc) * N_ + n0 + tn] = f2bs(v);
    }
    __syncthreads();
#pragma unroll
    for (int p = 0; p < 4; ++p) {
        int nn = tc8 + p * 8;
        xbT[((size_t)b * N_ + n0 + nn) * C_ + c0 + tn] = f2bs(t[tn][nn]);
    }
}

// ---------------- exact-f32 score path ----------------
// xsum[b][c] = sum_n x[b][c][n]
__global__ __launch_bounds__(256) void k_xsum(const float* __restrict__ x, float* __restrict__ xsum) {
    const int w = threadIdx.x >> 6, lane = threadIdx.x & 63;
    const int b = blockIdx.y, c0 = blockIdx.x * 32 + w * 8;
    const float* xp = x + ((size_t)b * C_ + c0) * N_;
#pragma unroll
    for (int i = 0; i < 8; ++i) {
        float s = xp[i * N_ + lane] + xp[i * N_ + lane + 64] + xp[i * N_ + lane + 128] + xp[i * N_ + lane + 192];
#pragma unroll
        for (int o = 32; o; o >>= 1) s += __shfl_xor(s, o, 64);
        if (lane == 0) xsum[(size_t)b * C_ + c0 + i] = s;
    }
}

// qsum[bh][d] = sum_c xsum[b][c]*qw[h][d][c] + 256*qb[h][d]
__global__ __launch_bounds__(256) void k_qsum(const float* __restrict__ xsum, const float* __restrict__ qw,
                                              const float* __restrict__ qb, float* __restrict__ qsum) {
    const int h = blockIdx.y;
    const int d = blockIdx.x * 256 + threadIdx.x;
    __shared__ float xs[16 * 256];
    float acc[16];
#pragma unroll
    for (int bb = 0; bb < 16; ++bb) acc[bb] = 0.f;
    for (int c0 = 0; c0 < C_; c0 += 256) {
        __syncthreads();
        for (int i = threadIdx.x; i < 16 * 256; i += 256) {
            int bb = i >> 8, cc = i & 255;
            xs[i] = xsum[(size_t)bb * C_ + c0 + cc];
        }
        __syncthreads();
        const float* wrow = qw + ((size_t)(h * D_ + d)) * C_ + c0;
        for (int cc = 0; cc < 256; ++cc) {
            float w = wrow[cc];
#pragma unroll
            for (int bb = 0; bb < 16; ++bb) acc[bb] += xs[bb * 256 + cc] * w;
        }
    }
#pragma unroll
    for (int bb = 0; bb < 16; ++bb)
        qsum[(size_t)((bb << 2) | h) * D_ + d] = acc[bb] + 256.0f * qb[h * D_ + d];
}

// cst[bh] = sum_d qsum[bh][d]*kb[h][d]
__global__ __launch_bounds__(64) void k_const(const float* __restrict__ qsum, const float* __restrict__ kb,
                                              float* __restrict__ cst) {
    const int bh = blockIdx.x, h = bh & 3, lane = threadIdx.x;
    float s = 0.f;
    for (int d = lane; d < D_; d += 64) s += qsum[(size_t)bh * D_ + d] * kb[h * D_ + d];
#pragma unroll
    for (int o = 32; o; o >>= 1) s += __shfl_xor(s, o, 64);
    if (lane == 0) cst[bh] = s;
}

// vec[bh][c] = sum_d qsum[bh][d]*kw[h][d][c]
__global__ __launch_bounds__(256) void k_vec(const float* __restrict__ qsum, const float* __restrict__ kw,
                                             float* __restrict__ vec) {
    const int h = blockIdx.y;
    const int c = blockIdx.x * 256 + threadIdx.x;
    __shared__ float qs[16 * 512];
    for (int i = threadIdx.x; i < 16 * 512; i += 256) {
        int bb = i >> 9, dd = i & 511;
        qs[i] = qsum[(size_t)((bb << 2) | h) * D_ + dd];
    }
    __syncthreads();
    float acc[16];
#pragma unroll
    for (int bb = 0; bb < 16; ++bb) acc[bb] = 0.f;
    const float* wcol = kw + (size_t)h * D_ * C_ + c;
    for (int dd = 0; dd < D_; ++dd) {
        float w = wcol[(size_t)dd * C_];
#pragma unroll
        for (int bb = 0; bb < 16; ++bb) acc[bb] += qs[bb * 512 + dd] * w;
    }
#pragma unroll
    for (int bb = 0; bb < 16; ++bb) vec[(size_t)((bb << 2) | h) * C_ + c] = acc[bb];
}

// part[s][bh][k] = sum_{c in slice s} vec[bh][c]*x[b][c][k]
__global__ __launch_bounds__(256) void k_att(const float* __restrict__ x, const float* __restrict__ vec,
                                             float* __restrict__ part) {
    const int bh = blockIdx.x, sl = blockIdx.y, b = bh >> 2;
    __shared__ float vs[512];
    const int c0 = sl * 512;
    for (int i = threadIdx.x; i < 512; i += 256) vs[i] = vec[(size_t)bh * C_ + c0 + i];
    __syncthreads();
    float a = 0.f;
    const float* xp = x + ((size_t)b * C_ + c0) * N_ + threadIdx.x;
#pragma unroll 8
    for (int c = 0; c < 512; ++c) a += vs[c] * xp[(size_t)c * N_];
    part[((size_t)sl * 64 + bh) * N_ + threadIdx.x] = a;
}

// softmax over heads of scale*(cst+sum parts); writes score + out0
__global__ __launch_bounds__(256) void k_score(const float* __restrict__ part, const float* __restrict__ cst,
                                               float* __restrict__ score, float* __restrict__ out0) {
    const int b = blockIdx.x, k = threadIdx.x;
    const float scale = 0.044194173824159216f;
    float a[4];
#pragma unroll
    for (int h = 0; h < 4; ++h) {
        const int bh = b * 4 + h;
        float s = cst[bh];
#pragma unroll
        for (int sl = 0; sl < 4; ++sl) s += part[((size_t)sl * 64 + bh) * N_ + k];
        a[h] = s * scale;
    }
    float mx = fmaxf(fmaxf(a[0], a[1]), fmaxf(a[2], a[3]));
    float e0 = expf(a[0] - mx), e1 = expf(a[1] - mx), e2 = expf(a[2] - mx), e3 = expf(a[3] - mx);
    float inv = 1.0f / (e0 + e1 + e2 + e3);
    float r[4] = { e0 * inv, e1 * inv, e2 * inv, e3 * inv };
#pragma unroll
    for (int h = 0; h < 4; ++h) {
        score[(size_t)(b * 4 + h) * N_ + k] = r[h];
        out0[(size_t)(b * 4 + h) * N_ + k] = r[h];
    }
}

// ---------------- MFMA stage wrappers ----------------
__global__ __launch_bounds__(256) void k_projQK(const ushort_t* __restrict__ xbT,
                                                const ushort_t* __restrict__ qwb, const float* __restrict__ qb,
                                                const ushort_t* __restrict__ kwb, const float* __restrict__ kb,
                                                ushort_t* __restrict__ Qr, ushort_t* __restrict__ Kr) {
    const int z = blockIdx.z, isK = z >> 6, bh = z & 63, b = bh >> 2, h = bh & 3;
    const int bm = blockIdx.y * 128, bn = blockIdx.x * 128;
    const ushort_t* A = xbT + (size_t)b * N_ * C_ + (size_t)bm * C_;
    const ushort_t* W = (isK ? kwb : qwb) + (size_t)h * D_ * C_ + (size_t)bn * C_;
    const float* cb = (isK ? kb : qb) + h * D_ + bn;
    ushort_t* Cc = (isK ? Kr : Qr) + (size_t)bh * N_ * D_ + (size_t)bm * D_ + bn;
    mfma_nt<0, 1, 0, 0>(A, W, C_, 1.0f, nullptr, cb, nullptr, nullptr, 0, Cc, D_);
}

__global__ __launch_bounds__(256) void k_sim(const ushort_t* __restrict__ Qr, const ushort_t* __restrict__ Kr,
                                             float* __restrict__ simf) {
    const int bh = blockIdx.z;
    const int bm = blockIdx.y * 128, bn = blockIdx.x * 128;
    const ushort_t* A = Qr + (size_t)bh * N_ * D_ + (size_t)bm * D_;
    const ushort_t* Bm = Kr + (size_t)bh * N_ * D_ + (size_t)bn * D_;
    float* Cc = simf + (size_t)bh * N_ * N_ + (size_t)bm * N_ + bn;
    mfma_nt<1, 0, 0, 0>(A, Bm, D_, 0.044194173824159216f, nullptr, nullptr, nullptr, nullptr, 0, Cc, N_);
}

__global__ __launch_bounds__(64) void k_softP(const float* __restrict__ simf, ushort_t* __restrict__ Pb) {
    const size_t row = blockIdx.x;
    const float* p = simf + row * N_;
    ushort_t* o = Pb + row * N_;
    const int t = threadIdx.x;
    float v0 = p[t], v1 = p[t + 64], v2 = p[t + 128], v3 = p[t + 192];
    float mx = fmaxf(fmaxf(v0, v1), fmaxf(v2, v3));
#pragma unroll
    for (int off = 32; off; off >>= 1) mx = fmaxf(mx, __shfl_xor(mx, off, 64));
    float e0 = expf(v0 - mx), e1 = expf(v1 - mx), e2 = expf(v2 - mx), e3 = expf(v3 - mx);
    float s = e0 + e1 + e2 + e3;
#pragma unroll
    for (int off = 32; off; off >>= 1) s += __shfl_xor(s, off, 64);
    const float inv = 1.0f / s;
    o[t] = f2bs(e0 * inv); o[t + 64] = f2bs(e1 * inv);
    o[t + 128] = f2bs(e2 * inv); o[t + 192] = f2bs(e3 * inv);
}

__global__ __launch_bounds__(256) void k_T(const ushort_t* __restrict__ Pb, const ushort_t* __restrict__ xb,
                                           ushort_t* __restrict__ Tt) {
    const int bh = blockIdx.z, b = bh >> 2;
    const int bm = blockIdx.y * 128, bn = blockIdx.x * 128;
    const ushort_t* A = Pb + (size_t)bh * N_ * N_ + (size_t)bm * N_;
    const ushort_t* Bm = xb + (size_t)b * C_ * N_ + (size_t)bn * N_;
    ushort_t* Cc = Tt + (size_t)bh * N_ * C_ + (size_t)bm * C_ + bn;
    mfma_nt<0, 0, 0, 0>(A, Bm, N_, 1.0f, nullptr, nullptr, nullptr, nullptr, 0, Cc, C_);
}

__global__ __launch_bounds__(256) void k_out(const ushort_t* __restrict__ vwb, const float* __restrict__ vb,
                                             const ushort_t* __restrict__ Tt, const float* __restrict__ score,
                                             const float* __restrict__ x, float* __restrict__ out1) {
    const int bh = blockIdx.z, b = bh >> 2, h = bh & 3;
    const int bm = blockIdx.y * 128, bn = blockIdx.x * 128;
    const ushort_t* A = vwb + (size_t)h * C_ * C_ + (size_t)bm * C_;
    const ushort_t* Bm = Tt + (size_t)bh * N_ * C_ + (size_t)bn * C_;
    const float* rb = vb + h * C_ + bm;
    const float* sc = score + (size_t)bh * N_ + bn;
    const float* ex = x + (size_t)b * C_ * N_ + (size_t)bm * N_ + bn;
    float* Cc = out1 + (size_t)bh * C_ * N_ + (size_t)bm * N_ + bn;
    mfma_nt<1, 0, 1, 1>(A, Bm, C_, 1.0f, rb, nullptr, sc, ex, N_, Cc, N_);
}

extern "C" void kernel_launch(void* const* d_in, const int* in_sizes, int n_in,
                              void* d_out, int out_size, void* d_ws, size_t ws_size,
                              hipStream_t stream)
{
    const float* x  = (const float*)d_in[0];
    const float* qw = (const float*)d_in[1];
    const float* qb = (const float*)d_in[2];
    const float* kw = (const float*)d_in[3];
    const float* kb = (const float*)d_in[4];
    const float* vw = (const float*)d_in[5];
    const float* vb = (const float*)d_in[6];

    float* out0 = (float*)d_out;
    float* out1 = out0 + (size_t)B_ * HEADS_ * N_;

    // ---- workspace layout (bytes) ----
    char* w = (char*)d_ws;
    ushort_t* vwb = (ushort_t*)w;                    w += (size_t)4 * C_ * C_ * 2;       // 33.6MB
    ushort_t* qwb = (ushort_t*)w;                    w += (size_t)4 * D_ * C_ * 2;       // 8.4MB
    ushort_t* kwb = (ushort_t*)w;                    w += (size_t)4 * D_ * C_ * 2;       // 8.4MB
    ushort_t* xb  = (ushort_t*)w;                    w += (size_t)B_ * C_ * N_ * 2;      // 16.8MB
    ushort_t* Qr  = (ushort_t*)w;                    w += (size_t)64 * N_ * D_ * 2;      // 16.8MB
    ushort_t* Kr  = (ushort_t*)w;                    w += (size_t)64 * N_ * D_ * 2;      // 16.8MB
    ushort_t* Pb  = (ushort_t*)w;                    w += (size_t)64 * N_ * N_ * 2;      // 8.4MB
    float*    simf= (float*)w;                       w += (size_t)64 * N_ * N_ * 4;      // 16.8MB
    ushort_t* Tt  = (ushort_t*)w;                    w += (size_t)64 * N_ * C_ * 2;      // 67.1MB
    ushort_t* xbT = Tt;  // alias: xbT dead before k_T writes Tt
    float*    xsum= (float*)w;                       w += (size_t)B_ * C_ * 4;
    float*    qsum= (float*)w;                       w += (size_t)64 * D_ * 4;
    float*    cst = (float*)w;                       w += 1024;
    float*    vec = (float*)w;                       w += (size_t)64 * C_ * 4;
    float*    part= (float*)w;                       w += (size_t)4 * 64 * N_ * 4;
    float*    score=(float*)w;                       w += (size_t)64 * N_ * 4;

    // casts
    k_castw<<<dim3((4 * D_ * C_ / 4 + 255) / 256), 256, 0, stream>>>(qw, qwb, 4 * D_ * C_);
    k_castw<<<dim3((4 * D_ * C_ / 4 + 255) / 256), 256, 0, stream>>>(kw, kwb, 4 * D_ * C_);
    k_castw<<<dim3((4 * C_ * C_ / 4 + 255) / 256), 256, 0, stream>>>(vw, vwb, 4 * C_ * C_);
    k_cast_x<<<dim3(8, 64, 16), 256, 0, stream>>>(x, xb, xbT);

    // exact-f32 score path
    k_xsum <<<dim3(64, 16), 256, 0, stream>>>(x, xsum);
    k_qsum <<<dim3(2, 4), 256, 0, stream>>>(xsum, qw, qb, qsum);
    k_const<<<dim3(64), 64, 0, stream>>>(qsum, kb, cst);
    k_vec  <<<dim3(8, 4), 256, 0, stream>>>(qsum, kw, vec);
    k_att  <<<dim3(64, 4), 256, 0, stream>>>(x, vec, part);
    k_score<<<dim3(16), 256, 0, stream>>>(part, cst, score, out0);

    // MFMA pipeline
    k_projQK<<<dim3(4, 2, 128), 256, 0, stream>>>(xbT, qwb, qb, kwb, kb, Qr, Kr);
    k_sim   <<<dim3(2, 2, 64), 256, 0, stream>>>(Qr, Kr, simf);
    k_softP <<<dim3(64 * N_), 64, 0, stream>>>(simf, Pb);
    k_T     <<<dim3(16, 2, 64), 256, 0, stream>>>(Pb, xb, Tt);
    k_out   <<<dim3(2, 16, 64), 256, 0, stream>>>(vwb, vb, Tt, score, x, out1);
}

// Round 4
// 479.069 us; speedup vs baseline: 6.4462x; 1.4001x over previous
//
#include <hip/hip_runtime.h>
#include <hip/hip_bf16.h>

#define B_ 16
#define C_ 2048
#define N_ 256
#define HEADS_ 4
#define D_ 512

typedef unsigned int u32;
typedef unsigned short ushort_t;
typedef __attribute__((ext_vector_type(8))) short bfx8;
typedef __attribute__((ext_vector_type(4))) float fx4;

__device__ __forceinline__ unsigned short f2bs(float f) {
    __hip_bfloat16 h = __float2bfloat16(f);
    return __builtin_bit_cast(unsigned short, h);
}
__device__ __forceinline__ float bs2f(ushort_t u) {
    u32 v = ((u32)u) << 16;
    return __builtin_bit_cast(float, v);
}
__device__ __forceinline__ void gload16(const void* g, void* l) {
    __builtin_amdgcn_global_load_lds((const __attribute__((address_space(1))) u32*)g,
                                     (__attribute__((address_space(3))) u32*)l, 16, 0, 0);
}
__device__ __forceinline__ int xcd_swz(int bid, int nwg) {
    return (bid & 7) * (nwg >> 3) + (bid >> 3);
}

// ---------------- 128x128 MFMA NT core: acc += A[128][K] * B[128][K]^T ----------------
// 4 waves 2x2, each wave 64x64 via 4x4 frags of 16x16x32 bf16.
__device__ __forceinline__ void mfma_core(const ushort_t* __restrict__ A,
                                          const ushort_t* __restrict__ Bm,
                                          int K, fx4 acc[4][4])
{
    __shared__ __align__(16) ushort_t As[128 * 32];
    __shared__ __align__(16) ushort_t Bs[128 * 32];
    const int tid = threadIdx.x;
    const int lane = tid & 63, wave = tid >> 6;
    const int l16 = lane & 15, lhi = lane >> 4;
    const int wm = (wave >> 1) * 64, wn = (wave & 1) * 64;

    for (int k0 = 0; k0 < K; k0 += 32) {
        const int f0 = tid, f1 = tid + 256;
        gload16(A + (size_t)(f0 >> 2) * K + k0 + (f0 & 3) * 8, As + f0 * 8);
        gload16(A + (size_t)(f1 >> 2) * K + k0 + (f1 & 3) * 8, As + f1 * 8);
        gload16(Bm + (size_t)(f0 >> 2) * K + k0 + (f0 & 3) * 8, Bs + f0 * 8);
        gload16(Bm + (size_t)(f1 >> 2) * K + k0 + (f1 & 3) * 8, Bs + f1 * 8);
        __syncthreads();
        bfx8 af[4], bfr[4];
#pragma unroll
        for (int i = 0; i < 4; ++i)
            af[i] = *(const bfx8*)(As + (wm + i * 16 + l16) * 32 + lhi * 8);
#pragma unroll
        for (int j = 0; j < 4; ++j)
            bfr[j] = *(const bfx8*)(Bs + (wn + j * 16 + l16) * 32 + lhi * 8);
#pragma unroll
        for (int i = 0; i < 4; ++i)
#pragma unroll
            for (int j = 0; j < 4; ++j)
                acc[i][j] = __builtin_amdgcn_mfma_f32_16x16x32_bf16(af[i], bfr[j], acc[i][j], 0, 0, 0);
        __syncthreads();
    }
}

#define EPI_IDX() \
    const int lane = threadIdx.x & 63, wave = threadIdx.x >> 6; \
    const int l16 = lane & 15, lhi = lane >> 4; \
    const int wm = (wave >> 1) * 64, wn = (wave & 1) * 64;

// ---------------- casts ----------------
__global__ __launch_bounds__(256) void k_castw(const float* __restrict__ s, ushort_t* __restrict__ d, int n) {
    int i = (blockIdx.x * 256 + threadIdx.x) * 4;
    if (i >= n) return;
    float4 v = *(const float4*)(s + i);
    ushort4 o = { f2bs(v.x), f2bs(v.y), f2bs(v.z), f2bs(v.w) };
    *(ushort4*)(d + i) = o;
}

// x[b][c][n] -> xb bf16 [b][c][n], xbT bf16 [b][n][c], xpart f32 [ntile=8][b][c] (partial n-sums)
__global__ __launch_bounds__(256) void k_cast_x(const float* __restrict__ x,
                                                ushort_t* __restrict__ xb, ushort_t* __restrict__ xbT,
                                                float* __restrict__ xpart) {
    __shared__ float t[32][33];
    const int b = blockIdx.z, c0 = blockIdx.y * 32, n0 = blockIdx.x * 32;
    const int tn = threadIdx.x & 31, tc8 = threadIdx.x >> 5;
    const float* xp = x + ((size_t)b * C_ + c0) * N_ + n0;
#pragma unroll
    for (int p = 0; p < 4; ++p) {
        int cc = tc8 + p * 8;
        float v = xp[(size_t)cc * N_ + tn];
        t[cc][tn] = v;
        xb[((size_t)b * C_ + c0 + cc) * N_ + n0 + tn] = f2bs(v);
        float s = v;
#pragma unroll
        for (int o = 16; o; o >>= 1) s += __shfl_xor(s, o, 32);
        if (tn == 0) xpart[(size_t)blockIdx.x * B_ * C_ + (size_t)b * C_ + c0 + cc] = s;
    }
    __syncthreads();
#pragma unroll
    for (int p = 0; p < 4; ++p) {
        int nn = tc8 + p * 8;
        xbT[((size_t)b * N_ + n0 + nn) * C_ + c0 + tn] = f2bs(t[tn][nn]);
    }
}

// xsum[b][c] = sum of 8 partials
__global__ __launch_bounds__(256) void k_xsum2(const float* __restrict__ xpart, float* __restrict__ xsum) {
    const int c = blockIdx.x * 256 + threadIdx.x, b = blockIdx.y;
    float s = 0.f;
#pragma unroll
    for (int t = 0; t < 8; ++t) s += xpart[(size_t)t * B_ * C_ + (size_t)b * C_ + c];
    xsum[(size_t)b * C_ + c] = s;
}

// ---------------- exact-f32 score path ----------------
// qsum[bh][d] = sum_c xsum[b][c]*qw[h][d][c] + 256*qb[h][d]   (wave per (h,d) row; 512 blocks x 4 waves)
__global__ __launch_bounds__(256) void k_qsum(const float* __restrict__ xsum, const float* __restrict__ qw,
                                              const float* __restrict__ qb, float* __restrict__ qsum) {
    const int wave = threadIdx.x >> 6, lane = threadIdx.x & 63;
    const int row = blockIdx.x * 4 + wave;            // h*512+d, in [0, 2048)
    const int h = row >> 9, d = row & 511;
    const float* wr = qw + (size_t)row * C_;
    float acc[16];
#pragma unroll
    for (int bb = 0; bb < 16; ++bb) acc[bb] = 0.f;
    for (int it = 0; it < C_ / 64; ++it) {
        const int c = it * 64 + lane;
        const float w = wr[c];
#pragma unroll
        for (int bb = 0; bb < 16; ++bb) acc[bb] += xsum[(size_t)bb * C_ + c] * w;
    }
#pragma unroll
    for (int bb = 0; bb < 16; ++bb) {
        float s = acc[bb];
#pragma unroll
        for (int o = 32; o; o >>= 1) s += __shfl_xor(s, o, 64);
        if (lane == 0) qsum[(size_t)((bb << 2) | h) * D_ + d] = s + 256.0f * qb[row];
    }
}

__global__ __launch_bounds__(64) void k_const(const float* __restrict__ qsum, const float* __restrict__ kb,
                                              float* __restrict__ cst) {
    const int bh = blockIdx.x, h = bh & 3, lane = threadIdx.x;
    float s = 0.f;
    for (int d = lane; d < D_; d += 64) s += qsum[(size_t)bh * D_ + d] * kb[h * D_ + d];
#pragma unroll
    for (int o = 32; o; o >>= 1) s += __shfl_xor(s, o, 64);
    if (lane == 0) cst[bh] = s;
}

// partv[dsl][bh][c] = sum_{d in slice} qsum[bh][d]*kw[h][d][c]
__global__ __launch_bounds__(256) void k_vecp(const float* __restrict__ qsum, const float* __restrict__ kw,
                                              float* __restrict__ partv) {
    const int ct = blockIdx.x, h = blockIdx.y, dsl = blockIdx.z;
    __shared__ float qs[16 * 128];
    for (int i = threadIdx.x; i < 16 * 128; i += 256) {
        int bb = i >> 7, dd = i & 127;
        qs[i] = qsum[(size_t)((bb << 2) | h) * D_ + dsl * 128 + dd];
    }
    __syncthreads();
    const int c = ct * 256 + threadIdx.x;
    const float* wp = kw + ((size_t)h * D_ + dsl * 128) * C_ + c;
    float acc[16];
#pragma unroll
    for (int bb = 0; bb < 16; ++bb) acc[bb] = 0.f;
    for (int dd = 0; dd < 128; ++dd) {
        const float w = wp[(size_t)dd * C_];
#pragma unroll
        for (int bb = 0; bb < 16; ++bb) acc[bb] += qs[bb * 128 + dd] * w;
    }
#pragma unroll
    for (int bb = 0; bb < 16; ++bb)
        partv[((size_t)dsl * 64 + ((bb << 2) | h)) * C_ + c] = acc[bb];
}

// part[sl][bh][k] = sum_{c in 512-slice} vec[bh][c]*x[b][c][k]
__global__ __launch_bounds__(256) void k_att(const float* __restrict__ x, const float* __restrict__ partv,
                                             float* __restrict__ part) {
    const int bh = blockIdx.x, sl = blockIdx.y, b = bh >> 2;
    __shared__ float vs[512];
    const int c0 = sl * 512;
    for (int i = threadIdx.x; i < 512; i += 256) {
        float v = 0.f;
#pragma unroll
        for (int dsl = 0; dsl < 4; ++dsl) v += partv[((size_t)dsl * 64 + bh) * C_ + c0 + i];
        vs[i] = v;
    }
    __syncthreads();
    float a = 0.f;
    const float* xp = x + ((size_t)b * C_ + c0) * N_ + threadIdx.x;
#pragma unroll 8
    for (int c = 0; c < 512; ++c) a += vs[c] * xp[(size_t)c * N_];
    part[((size_t)sl * 64 + bh) * N_ + threadIdx.x] = a;
}

__global__ __launch_bounds__(256) void k_score(const float* __restrict__ part, const float* __restrict__ cst,
                                               float* __restrict__ score, float* __restrict__ out0) {
    const int b = blockIdx.x, k = threadIdx.x;
    const float scale = 0.044194173824159216f;
    float a[4];
#pragma unroll
    for (int h = 0; h < 4; ++h) {
        const int bh = b * 4 + h;
        float s = cst[bh];
#pragma unroll
        for (int sl = 0; sl < 4; ++sl) s += part[((size_t)sl * 64 + bh) * N_ + k];
        a[h] = s * scale;
    }
    float mx = fmaxf(fmaxf(a[0], a[1]), fmaxf(a[2], a[3]));
    float e0 = expf(a[0] - mx), e1 = expf(a[1] - mx), e2 = expf(a[2] - mx), e3 = expf(a[3] - mx);
    float inv = 1.0f / (e0 + e1 + e2 + e3);
    float r[4] = { e0 * inv, e1 * inv, e2 * inv, e3 * inv };
#pragma unroll
    for (int h = 0; h < 4; ++h) {
        score[(size_t)(b * 4 + h) * N_ + k] = r[h];
        out0[(size_t)(b * 4 + h) * N_ + k] = r[h];
    }
}

// ---------------- batched MFMA GEMMs ----------------
// proj: M=(b,n)=4096 rows of xbT, N=(qk,h,d)=4096 cols, K=2048. Writes QKbuf[qk][b][h][n][d] bf16.
__global__ __launch_bounds__(256) void k_proj(const ushort_t* __restrict__ xbT,
                                              const ushort_t* __restrict__ qwb, const ushort_t* __restrict__ kwb,
                                              const float* __restrict__ qb, const float* __restrict__ kb,
                                              ushort_t* __restrict__ QKbuf) {
    const int wg = xcd_swz(blockIdx.x, 1024);
    const int mq = wg >> 7, l2 = wg & 127;
    const int ng = l2 >> 4, l3 = l2 & 15;
    const int mt = mq * 4 + (l3 >> 2);
    const int nt = ng * 4 + (l3 & 3);
    const int qk = nt >> 4, hh = (nt >> 2) & 3, d0 = (nt & 3) * 128;
    const ushort_t* A = xbT + (size_t)mt * 128 * C_;
    const ushort_t* Bm = (qk ? kwb : qwb) + ((size_t)hh * D_ + d0) * C_;
    const float* bias = (qk ? kb : qb) + hh * D_ + d0;

    fx4 acc[4][4];
#pragma unroll
    for (int i = 0; i < 4; ++i)
#pragma unroll
        for (int j = 0; j < 4; ++j) acc[i][j] = (fx4){0.f, 0.f, 0.f, 0.f};
    mfma_core(A, Bm, C_, acc);

    EPI_IDX();
#pragma unroll
    for (int i = 0; i < 4; ++i)
#pragma unroll
        for (int j = 0; j < 4; ++j)
#pragma unroll
            for (int r = 0; r < 4; ++r) {
                const int rowg = mt * 128 + wm + i * 16 + lhi * 4 + r;
                const int b = rowg >> 8, nn = rowg & 255;
                const int dl = wn + j * 16 + l16;
                const float v = acc[i][j][r] + bias[dl];
                QKbuf[((((size_t)(qk * 16 + b) * 4 + hh) * 256) + nn) * 512 + d0 + dl] = f2bs(v);
            }
}

// sim: per bh, 128x128 tiles, K=512. simf f32 [bh][q][k].
__global__ __launch_bounds__(256) void k_sim(const ushort_t* __restrict__ QKbuf, float* __restrict__ simf) {
    const int wg = blockIdx.x;
    const int bh = wg >> 2, mt = (wg >> 1) & 1, ntl = wg & 1;
    const ushort_t* Qr = QKbuf;
    const ushort_t* Kr = QKbuf + (size_t)16 * 4 * 256 * 512;
    const ushort_t* A = Qr + ((size_t)bh * 256 + mt * 128) * 512;
    const ushort_t* Bm = Kr + ((size_t)bh * 256 + ntl * 128) * 512;

    fx4 acc[4][4];
#pragma unroll
    for (int i = 0; i < 4; ++i)
#pragma unroll
        for (int j = 0; j < 4; ++j) acc[i][j] = (fx4){0.f, 0.f, 0.f, 0.f};
    mfma_core(A, Bm, D_, acc);

    EPI_IDX();
    const float scale = 0.044194173824159216f;
#pragma unroll
    for (int i = 0; i < 4; ++i)
#pragma unroll
        for (int j = 0; j < 4; ++j)
#pragma unroll
            for (int r = 0; r < 4; ++r) {
                const int q = mt * 128 + wm + i * 16 + lhi * 4 + r;
                const int k = ntl * 128 + wn + j * 16 + l16;
                simf[(size_t)bh * N_ * N_ + (size_t)q * N_ + k] = acc[i][j][r] * scale;
            }
}

__global__ __launch_bounds__(64) void k_softP(const float* __restrict__ simf, ushort_t* __restrict__ Pb) {
    const size_t row = blockIdx.x;
    const float* p = simf + row * N_;
    ushort_t* o = Pb + row * N_;
    const int t = threadIdx.x;
    float v0 = p[t], v1 = p[t + 64], v2 = p[t + 128], v3 = p[t + 192];
    float mx = fmaxf(fmaxf(v0, v1), fmaxf(v2, v3));
#pragma unroll
    for (int off = 32; off; off >>= 1) mx = fmaxf(mx, __shfl_xor(mx, off, 64));
    float e0 = expf(v0 - mx), e1 = expf(v1 - mx), e2 = expf(v2 - mx), e3 = expf(v3 - mx);
    float s = e0 + e1 + e2 + e3;
#pragma unroll
    for (int off = 32; off; off >>= 1) s += __shfl_xor(s, off, 64);
    const float inv = 1.0f / s;
    o[t] = f2bs(e0 * inv); o[t + 64] = f2bs(e1 * inv);
    o[t + 128] = f2bs(e2 * inv); o[t + 192] = f2bs(e3 * inv);
}

// T: per b, M=(h,q)=1024 rows of Pb[b], N=c=2048 cols of xb[b], K=256. Tt[h][b][q][c] bf16.
__global__ __launch_bounds__(256) void k_T(const ushort_t* __restrict__ Pb, const ushort_t* __restrict__ xb,
                                           ushort_t* __restrict__ Tt) {
    const int wg = xcd_swz(blockIdx.x, 2048);
    const int b = wg >> 7, l = wg & 127;
    const int mt = l >> 4, nt = l & 15;
    const ushort_t* A = Pb + ((size_t)b * 1024 + mt * 128) * 256;
    const ushort_t* Bm = xb + ((size_t)b * 2048 + nt * 128) * 256;

    fx4 acc[4][4];
#pragma unroll
    for (int i = 0; i < 4; ++i)
#pragma unroll
        for (int j = 0; j < 4; ++j) acc[i][j] = (fx4){0.f, 0.f, 0.f, 0.f};
    mfma_core(A, Bm, N_, acc);

    EPI_IDX();
#pragma unroll
    for (int i = 0; i < 4; ++i)
#pragma unroll
        for (int j = 0; j < 4; ++j)
#pragma unroll
            for (int r = 0; r < 4; ++r) {
                const int rowm = mt * 128 + wm + i * 16 + lhi * 4 + r;
                const int h = rowm >> 8, q = rowm & 255;
                const int c = nt * 128 + wn + j * 16 + l16;
                Tt[(((size_t)h * 16 + b) * 256 + q) * 2048 + c] = f2bs(acc[i][j][r]);
            }
}

// out: per h, M=e=2048 rows of vwb[h], N=(b,n)=4096 cols of Tt[h], K=2048.
__global__ __launch_bounds__(256) void k_out(const ushort_t* __restrict__ vwb, const float* __restrict__ vb,
                                             const ushort_t* __restrict__ Tt, const float* __restrict__ score,
                                             const ushort_t* __restrict__ xb, float* __restrict__ out1) {
    const int wg = xcd_swz(blockIdx.x, 2048);
    const int h = wg >> 9, local = wg & 511;
    const int mh = local >> 8, l2 = local & 255;
    const int ng = l2 >> 5, l3 = l2 & 31;
    const int mt = mh * 8 + (l3 >> 2);
    const int nt = ng * 4 + (l3 & 3);
    const ushort_t* A = vwb + (size_t)h * C_ * C_ + (size_t)mt * 128 * C_;
    const ushort_t* Bm = Tt + (size_t)h * 16 * N_ * C_ + (size_t)nt * 128 * C_;

    fx4 acc[4][4];
#pragma unroll
    for (int i = 0; i < 4; ++i)
#pragma unroll
        for (int j = 0; j < 4; ++j) acc[i][j] = (fx4){0.f, 0.f, 0.f, 0.f};
    mfma_core(A, Bm, C_, acc);

    EPI_IDX();
#pragma unroll
    for (int i = 0; i < 4; ++i)
#pragma unroll
        for (int j = 0; j < 4; ++j)
#pragma unroll
            for (int r = 0; r < 4; ++r) {
                const int e = mt * 128 + wm + i * 16 + lhi * 4 + r;
                const int col = nt * 128 + wn + j * 16 + l16;
                const int b = col >> 8, n = col & 255;
                float v = acc[i][j][r] + vb[h * C_ + e]
                        + score[(size_t)(b * 4 + h) * N_ + n] * bs2f(xb[((size_t)b * C_ + e) * N_ + n]);
                out1[((size_t)(b * 4 + h) * C_ + e) * N_ + n] = v;
            }
}

extern "C" void kernel_launch(void* const* d_in, const int* in_sizes, int n_in,
                              void* d_out, int out_size, void* d_ws, size_t ws_size,
                              hipStream_t stream)
{
    const float* x  = (const float*)d_in[0];
    const float* qw = (const float*)d_in[1];
    const float* qb = (const float*)d_in[2];
    const float* kw = (const float*)d_in[3];
    const float* kb = (const float*)d_in[4];
    const float* vw = (const float*)d_in[5];
    const float* vb = (const float*)d_in[6];

    float* out0 = (float*)d_out;
    float* out1 = out0 + (size_t)B_ * HEADS_ * N_;

    char* w = (char*)d_ws;
    ushort_t* vwb  = (ushort_t*)w;  w += (size_t)4 * C_ * C_ * 2;          // 33.6MB
    ushort_t* qwb  = (ushort_t*)w;  w += (size_t)4 * D_ * C_ * 2;          // 8.4MB
    ushort_t* kwb  = (ushort_t*)w;  w += (size_t)4 * D_ * C_ * 2;          // 8.4MB
    ushort_t* xb   = (ushort_t*)w;  w += (size_t)B_ * C_ * N_ * 2;         // 16.8MB
    ushort_t* QKbuf= (ushort_t*)w;  w += (size_t)2 * 16 * 4 * 256 * 512 * 2; // 33.6MB
    ushort_t* Pb   = (ushort_t*)w;  w += (size_t)64 * N_ * N_ * 2;         // 8.4MB
    float*    simf = (float*)w;     w += (size_t)64 * N_ * N_ * 4;         // 16.8MB
    ushort_t* Tt   = (ushort_t*)w;  w += (size_t)64 * N_ * C_ * 2;         // 67.1MB
    ushort_t* xbT  = Tt;  // alias: xbT (16.8MB) dead before k_T writes Tt
    float*    xpart= (float*)w;     w += (size_t)8 * B_ * C_ * 4;          // 1MB
    float*    xsum = (float*)w;     w += (size_t)B_ * C_ * 4;
    float*    qsum = (float*)w;     w += (size_t)64 * D_ * 4;
    float*    cst  = (float*)w;     w += 1024;
    float*    partv= (float*)w;     w += (size_t)4 * 64 * C_ * 4;          // 2.1MB
    float*    part = (float*)w;     w += (size_t)4 * 64 * N_ * 4;
    float*    score= (float*)w;     w += (size_t)64 * N_ * 4;

    // casts
    k_castw<<<dim3(4 * D_ * C_ / 4 / 256), 256, 0, stream>>>(qw, qwb, 4 * D_ * C_);
    k_castw<<<dim3(4 * D_ * C_ / 4 / 256), 256, 0, stream>>>(kw, kwb, 4 * D_ * C_);
    k_castw<<<dim3(4 * C_ * C_ / 4 / 256), 256, 0, stream>>>(vw, vwb, 4 * C_ * C_);
    k_cast_x<<<dim3(8, 64, 16), 256, 0, stream>>>(x, xb, xbT, xpart);

    // exact-f32 score path
    k_xsum2<<<dim3(8, 16), 256, 0, stream>>>(xpart, xsum);
    k_qsum <<<dim3(512), 256, 0, stream>>>(xsum, qw, qb, qsum);   // FIX: 2048 rows / 4 waves = 512 blocks (was 1024 -> OOB read of qw)
    k_const<<<dim3(64), 64, 0, stream>>>(qsum, kb, cst);
    k_vecp <<<dim3(8, 4, 4), 256, 0, stream>>>(qsum, kw, partv);
    k_att  <<<dim3(64, 4), 256, 0, stream>>>(x, partv, part);
    k_score<<<dim3(16), 256, 0, stream>>>(part, cst, score, out0);

    // MFMA pipeline
    k_proj <<<dim3(1024), 256, 0, stream>>>(xbT, qwb, kwb, qb, kb, QKbuf);
    k_sim  <<<dim3(256), 256, 0, stream>>>(QKbuf, simf);
    k_softP<<<dim3(64 * N_), 64, 0, stream>>>(simf, Pb);
    k_T    <<<dim3(2048), 256, 0, stream>>>(Pb, xb, Tt);
    k_out  <<<dim3(2048), 256, 0, stream>>>(vwb, vb, Tt, score, xb, out1);
}

// Round 5
// 397.388 us; speedup vs baseline: 7.7712x; 1.2055x over previous
//
#include <hip/hip_runtime.h>
#include <hip/hip_bf16.h>

#define B_ 16
#define C_ 2048
#define N_ 256
#define HEADS_ 4
#define D_ 512

typedef unsigned int u32;
typedef unsigned short ushort_t;
typedef __attribute__((ext_vector_type(8))) short bfx8;
typedef __attribute__((ext_vector_type(4))) float fx4;

__device__ __forceinline__ unsigned short f2bs(float f) {
    __hip_bfloat16 h = __float2bfloat16(f);
    return __builtin_bit_cast(unsigned short, h);
}
__device__ __forceinline__ float bs2f(ushort_t u) {
    u32 v = ((u32)u) << 16;
    return __builtin_bit_cast(float, v);
}
__device__ __forceinline__ void gload16(const void* g, void* l) {
    __builtin_amdgcn_global_load_lds((const __attribute__((address_space(1))) u32*)g,
                                     (__attribute__((address_space(3))) u32*)l, 16, 0, 0);
}
__device__ __forceinline__ int xcd_swz(int bid, int nwg) {
    return (bid & 7) * (nwg >> 3) + (bid >> 3);
}

// ======================= 256x256 8-phase counted-vmcnt core =======================
// NT GEMM: acc[8][4] (wave 128x64 tile) += A[256][K] * B[256][K]^T, K % 64 == 0, K/64 >= 2.
// 512 threads = 8 waves (2 Mwave x 4 Nwave). LDS 128 KiB. Never drains vmcnt in loop.
#define VMW8() asm volatile("s_waitcnt vmcnt(8)" ::: "memory")
#define SBAR() __builtin_amdgcn_s_barrier()
#define SCB0() __builtin_amdgcn_sched_barrier(0)

#define STAGE8(MAT, BUF, KH, J) do {                                          \
    const ushort_t* s_ = (MAT) ? Bm : A;                                      \
    _Pragma("unroll")                                                         \
    for (int l_ = 0; l_ < 2; ++l_) {                                          \
        const int r_ = l_ * 128 + (tid >> 2);                                 \
        const int k_ = (J) * 64 + (KH) * 32 + (tid & 3) * 8;                  \
        gload16(s_ + (size_t)r_ * K + k_,                                     \
                (char*)(&lds[MAT][BUF][KH][0][0]) + l_ * 8192 + tid * 16);    \
    } } while (0)

#define LDA8(dst, BUF, KH, MH) do {                                           \
    _Pragma("unroll")                                                         \
    for (int i_ = 0; i_ < 4; ++i_)                                            \
        dst[i_] = *(const bfx8*)&lds[0][BUF][KH][wmr + (MH) * 64 + i_ * 16 + l16][lhi * 8]; \
    } while (0)

#define LDB8(dst, BUF, KH) do {                                               \
    _Pragma("unroll")                                                         \
    for (int i_ = 0; i_ < 4; ++i_)                                            \
        dst[i_] = *(const bfx8*)&lds[1][BUF][KH][wnr + i_ * 16 + l16][lhi * 8]; \
    } while (0)

#define MM8(aa, bb, MH) do {                                                  \
    __builtin_amdgcn_s_setprio(1);                                            \
    _Pragma("unroll")                                                         \
    for (int i_ = 0; i_ < 4; ++i_) {                                          \
        _Pragma("unroll")                                                     \
        for (int n_ = 0; n_ < 4; ++n_)                                        \
            acc[(MH) * 4 + i_][n_] = __builtin_amdgcn_mfma_f32_16x16x32_bf16( \
                aa[i_], bb[n_], acc[(MH) * 4 + i_][n_], 0, 0, 0);             \
    }                                                                         \
    __builtin_amdgcn_s_setprio(0);                                            \
} while (0)

// lds must be declared in the kernel (static shared); passed by reference.
typedef ushort_t lds256_t[2][2][2][256][32];

__device__ __forceinline__ void gemm256_8ph(const ushort_t* __restrict__ A,
                                            const ushort_t* __restrict__ Bm,
                                            int K, lds256_t& lds, fx4 acc[8][4])
{
    const int tid = threadIdx.x;
    const int lane = tid & 63;
    const int w = tid >> 6;
    const int l16 = lane & 15, lhi = lane >> 4;
    const int wmr = (w >> 2) * 128;
    const int wnr = (w & 3) * 64;
    const int nkt = K >> 6;

    // prologue: tile0 (k0,k1) + tile1 k0   = 12 loads/wave
    STAGE8(0, 0, 0, 0); STAGE8(1, 0, 0, 0);
    STAGE8(0, 0, 1, 0); STAGE8(1, 0, 1, 0);
    STAGE8(0, 1, 0, 1); STAGE8(1, 1, 0, 1);
    VMW8();
    SBAR();

    for (int j = 0; j < nkt; ++j) {
        const int b = j & 1;
        const int js1 = (j + 1 < nkt) ? j + 1 : j;
        const int js2 = (j + 2 < nkt) ? j + 2 : j;
        bfx8 a0[4], a1[4], b0[4], b1[4];
        // ---- phase 0: (mh0, k0) ----
        LDA8(a0, b, 0, 0);
        LDB8(b0, b, 0);
        STAGE8(0, b ^ 1, 1, js1);            // A of tile j+1, k1
        SBAR();
        MM8(a0, b0, 0);
        SCB0();
        SBAR();
        // ---- phase 1: (mh1, k0) ----
        LDA8(a1, b, 0, 1);
        STAGE8(1, b ^ 1, 1, js1);            // B of tile j+1, k1
        SBAR();
        MM8(a1, b0, 1);
        SCB0();
        VMW8();                              // tile j k1 ready for ph2
        SBAR();
        // ---- phase 2: (mh0, k1) ----
        LDA8(a0, b, 1, 0);
        LDB8(b1, b, 1);
        STAGE8(0, b, 0, js2);                // A of tile j+2, k0 (region released after ph1)
        SBAR();
        MM8(a0, b1, 0);
        SCB0();
        SBAR();
        // ---- phase 3: (mh1, k1) ----
        LDA8(a1, b, 1, 1);
        STAGE8(1, b, 0, js2);                // B of tile j+2, k0
        SBAR();
        MM8(a1, b1, 1);
        SCB0();
        VMW8();                              // tile j+1 k0 ready for next ph0
        SBAR();
    }
}

#define EPI256_IDX() \
    const int lane = threadIdx.x & 63, w = threadIdx.x >> 6; \
    const int l16 = lane & 15, lhi = lane >> 4; \
    const int wmr = (w >> 2) * 128, wnr = (w & 3) * 64;

// ---------------- 128x128 2-phase core (kept for k_sim / k_T) ----------------
__device__ __forceinline__ void mfma_core(const ushort_t* __restrict__ A,
                                          const ushort_t* __restrict__ Bm,
                                          int K, fx4 acc[4][4])
{
    __shared__ __align__(16) ushort_t As[128 * 32];
    __shared__ __align__(16) ushort_t Bs[128 * 32];
    const int tid = threadIdx.x;
    const int lane = tid & 63, wave = tid >> 6;
    const int l16 = lane & 15, lhi = lane >> 4;
    const int wm = (wave >> 1) * 64, wn = (wave & 1) * 64;

    for (int k0 = 0; k0 < K; k0 += 32) {
        const int f0 = tid, f1 = tid + 256;
        gload16(A + (size_t)(f0 >> 2) * K + k0 + (f0 & 3) * 8, As + f0 * 8);
        gload16(A + (size_t)(f1 >> 2) * K + k0 + (f1 & 3) * 8, As + f1 * 8);
        gload16(Bm + (size_t)(f0 >> 2) * K + k0 + (f0 & 3) * 8, Bs + f0 * 8);
        gload16(Bm + (size_t)(f1 >> 2) * K + k0 + (f1 & 3) * 8, Bs + f1 * 8);
        __syncthreads();
        bfx8 af[4], bfr[4];
#pragma unroll
        for (int i = 0; i < 4; ++i)
            af[i] = *(const bfx8*)(As + (wm + i * 16 + l16) * 32 + lhi * 8);
#pragma unroll
        for (int j = 0; j < 4; ++j)
            bfr[j] = *(const bfx8*)(Bs + (wn + j * 16 + l16) * 32 + lhi * 8);
#pragma unroll
        for (int i = 0; i < 4; ++i)
#pragma unroll
            for (int j = 0; j < 4; ++j)
                acc[i][j] = __builtin_amdgcn_mfma_f32_16x16x32_bf16(af[i], bfr[j], acc[i][j], 0, 0, 0);
        __syncthreads();
    }
}

#define EPI_IDX() \
    const int lane = threadIdx.x & 63, wave = threadIdx.x >> 6; \
    const int l16 = lane & 15, lhi = lane >> 4; \
    const int wm = (wave >> 1) * 64, wn = (wave & 1) * 64;

// ---------------- casts ----------------
__global__ __launch_bounds__(256) void k_castw(const float* __restrict__ s, ushort_t* __restrict__ d, int n) {
    int i = (blockIdx.x * 256 + threadIdx.x) * 4;
    if (i >= n) return;
    float4 v = *(const float4*)(s + i);
    ushort4 o = { f2bs(v.x), f2bs(v.y), f2bs(v.z), f2bs(v.w) };
    *(ushort4*)(d + i) = o;
}

__global__ __launch_bounds__(256) void k_cast_x(const float* __restrict__ x,
                                                ushort_t* __restrict__ xb, ushort_t* __restrict__ xbT,
                                                float* __restrict__ xpart) {
    __shared__ float t[32][33];
    const int b = blockIdx.z, c0 = blockIdx.y * 32, n0 = blockIdx.x * 32;
    const int tn = threadIdx.x & 31, tc8 = threadIdx.x >> 5;
    const float* xp = x + ((size_t)b * C_ + c0) * N_ + n0;
#pragma unroll
    for (int p = 0; p < 4; ++p) {
        int cc = tc8 + p * 8;
        float v = xp[(size_t)cc * N_ + tn];
        t[cc][tn] = v;
        xb[((size_t)b * C_ + c0 + cc) * N_ + n0 + tn] = f2bs(v);
        float s = v;
#pragma unroll
        for (int o = 16; o; o >>= 1) s += __shfl_xor(s, o, 32);
        if (tn == 0) xpart[(size_t)blockIdx.x * B_ * C_ + (size_t)b * C_ + c0 + cc] = s;
    }
    __syncthreads();
#pragma unroll
    for (int p = 0; p < 4; ++p) {
        int nn = tc8 + p * 8;
        xbT[((size_t)b * N_ + n0 + nn) * C_ + c0 + tn] = f2bs(t[tn][nn]);
    }
}

__global__ __launch_bounds__(256) void k_xsum2(const float* __restrict__ xpart, float* __restrict__ xsum) {
    const int c = blockIdx.x * 256 + threadIdx.x, b = blockIdx.y;
    float s = 0.f;
#pragma unroll
    for (int t = 0; t < 8; ++t) s += xpart[(size_t)t * B_ * C_ + (size_t)b * C_ + c];
    xsum[(size_t)b * C_ + c] = s;
}

// ---------------- exact-f32 score path ----------------
__global__ __launch_bounds__(256) void k_qsum(const float* __restrict__ xsum, const float* __restrict__ qw,
                                              const float* __restrict__ qb, float* __restrict__ qsum) {
    const int wave = threadIdx.x >> 6, lane = threadIdx.x & 63;
    const int row = blockIdx.x * 4 + wave;            // h*512+d, in [0, 2048)
    const int h = row >> 9, d = row & 511;
    const float* wr = qw + (size_t)row * C_;
    float acc[16];
#pragma unroll
    for (int bb = 0; bb < 16; ++bb) acc[bb] = 0.f;
    for (int it = 0; it < C_ / 64; ++it) {
        const int c = it * 64 + lane;
        const float w = wr[c];
#pragma unroll
        for (int bb = 0; bb < 16; ++bb) acc[bb] += xsum[(size_t)bb * C_ + c] * w;
    }
#pragma unroll
    for (int bb = 0; bb < 16; ++bb) {
        float s = acc[bb];
#pragma unroll
        for (int o = 32; o; o >>= 1) s += __shfl_xor(s, o, 64);
        if (lane == 0) qsum[(size_t)((bb << 2) | h) * D_ + d] = s + 256.0f * qb[row];
    }
}

__global__ __launch_bounds__(64) void k_const(const float* __restrict__ qsum, const float* __restrict__ kb,
                                              float* __restrict__ cst) {
    const int bh = blockIdx.x, h = bh & 3, lane = threadIdx.x;
    float s = 0.f;
    for (int d = lane; d < D_; d += 64) s += qsum[(size_t)bh * D_ + d] * kb[h * D_ + d];
#pragma unroll
    for (int o = 32; o; o >>= 1) s += __shfl_xor(s, o, 64);
    if (lane == 0) cst[bh] = s;
}

__global__ __launch_bounds__(256) void k_vecp(const float* __restrict__ qsum, const float* __restrict__ kw,
                                              float* __restrict__ partv) {
    const int ct = blockIdx.x, h = blockIdx.y, dsl = blockIdx.z;
    __shared__ float qs[16 * 128];
    for (int i = threadIdx.x; i < 16 * 128; i += 256) {
        int bb = i >> 7, dd = i & 127;
        qs[i] = qsum[(size_t)((bb << 2) | h) * D_ + dsl * 128 + dd];
    }
    __syncthreads();
    const int c = ct * 256 + threadIdx.x;
    const float* wp = kw + ((size_t)h * D_ + dsl * 128) * C_ + c;
    float acc[16];
#pragma unroll
    for (int bb = 0; bb < 16; ++bb) acc[bb] = 0.f;
    for (int dd = 0; dd < 128; ++dd) {
        const float w = wp[(size_t)dd * C_];
#pragma unroll
        for (int bb = 0; bb < 16; ++bb) acc[bb] += qs[bb * 128 + dd] * w;
    }
#pragma unroll
    for (int bb = 0; bb < 16; ++bb)
        partv[((size_t)dsl * 64 + ((bb << 2) | h)) * C_ + c] = acc[bb];
}

__global__ __launch_bounds__(256) void k_att(const float* __restrict__ x, const float* __restrict__ partv,
                                             float* __restrict__ part) {
    const int bh = blockIdx.x, sl = blockIdx.y, b = bh >> 2;
    __shared__ float vs[512];
    const int c0 = sl * 512;
    for (int i = threadIdx.x; i < 512; i += 256) {
        float v = 0.f;
#pragma unroll
        for (int dsl = 0; dsl < 4; ++dsl) v += partv[((size_t)dsl * 64 + bh) * C_ + c0 + i];
        vs[i] = v;
    }
    __syncthreads();
    float a = 0.f;
    const float* xp = x + ((size_t)b * C_ + c0) * N_ + threadIdx.x;
#pragma unroll 8
    for (int c = 0; c < 512; ++c) a += vs[c] * xp[(size_t)c * N_];
    part[((size_t)sl * 64 + bh) * N_ + threadIdx.x] = a;
}

__global__ __launch_bounds__(256) void k_score(const float* __restrict__ part, const float* __restrict__ cst,
                                               float* __restrict__ score, float* __restrict__ out0) {
    const int b = blockIdx.x, k = threadIdx.x;
    const float scale = 0.044194173824159216f;
    float a[4];
#pragma unroll
    for (int h = 0; h < 4; ++h) {
        const int bh = b * 4 + h;
        float s = cst[bh];
#pragma unroll
        for (int sl = 0; sl < 4; ++sl) s += part[((size_t)sl * 64 + bh) * N_ + k];
        a[h] = s * scale;
    }
    float mx = fmaxf(fmaxf(a[0], a[1]), fmaxf(a[2], a[3]));
    float e0 = expf(a[0] - mx), e1 = expf(a[1] - mx), e2 = expf(a[2] - mx), e3 = expf(a[3] - mx);
    float inv = 1.0f / (e0 + e1 + e2 + e3);
    float r[4] = { e0 * inv, e1 * inv, e2 * inv, e3 * inv };
#pragma unroll
    for (int h = 0; h < 4; ++h) {
        score[(size_t)(b * 4 + h) * N_ + k] = r[h];
        out0[(size_t)(b * 4 + h) * N_ + k] = r[h];
    }
}

// ---------------- 8-phase MFMA GEMMs ----------------
// proj: M=(b,n)=4096, N=(qk,h,d)=4096, K=2048. 256 wg x 512 thr.
__global__ __launch_bounds__(512, 2) void k_proj(const ushort_t* __restrict__ xbT,
                                                 const ushort_t* __restrict__ qwb, const ushort_t* __restrict__ kwb,
                                                 const float* __restrict__ qb, const float* __restrict__ kb,
                                                 ushort_t* __restrict__ QKbuf) {
    __shared__ __align__(16) lds256_t lds;
    const int wg = xcd_swz(blockIdx.x, 256);
    const int quad = wg >> 2;
    const int mt = quad >> 2;                 // 0..15
    const int nt = (quad & 3) * 4 + (wg & 3); // 0..15
    const int c0 = nt * 256;
    const int qk = c0 >> 11;
    const int rem = c0 & 2047;                // h*512 + d0
    const ushort_t* A  = xbT + (size_t)mt * 256 * C_;
    const ushort_t* Bm = (qk ? kwb : qwb) + (size_t)rem * C_;
    const float* bias  = (qk ? kb : qb) + rem;
    const int K = C_;

    fx4 acc[8][4];
#pragma unroll
    for (int i = 0; i < 8; ++i)
#pragma unroll
        for (int j = 0; j < 4; ++j) acc[i][j] = (fx4){0.f, 0.f, 0.f, 0.f};
    gemm256_8ph(A, Bm, K, lds, acc);

    EPI256_IDX();
#pragma unroll
    for (int i = 0; i < 8; ++i)
#pragma unroll
        for (int n = 0; n < 4; ++n)
#pragma unroll
            for (int r = 0; r < 4; ++r) {
                const int gr = mt * 256 + wmr + i * 16 + lhi * 4 + r;
                const int bq = gr >> 8, nn = gr & 255;
                const int lc = wnr + n * 16 + l16;
                const int hh = (rem + lc) >> 9, dl = (rem + lc) & 511;
                const float v = acc[i][n][r] + bias[lc];
                QKbuf[((((size_t)(qk * 16 + bq) * 4 + hh) * 256) + nn) * 512 + dl] = f2bs(v);
            }
}

// out: per h, M=e=2048, N=(b,n)=4096, K=2048. 512 wg x 512 thr.
__global__ __launch_bounds__(512, 2) void k_out(const ushort_t* __restrict__ vwb, const float* __restrict__ vb,
                                                const ushort_t* __restrict__ Tt, const float* __restrict__ score,
                                                const ushort_t* __restrict__ xb, float* __restrict__ out1) {
    __shared__ __align__(16) lds256_t lds;
    const int wg = xcd_swz(blockIdx.x, 512);
    const int h = wg >> 7, l = wg & 127;
    const int quad = l >> 2;
    const int mt = quad >> 2;                 // 0..7
    const int nt = (quad & 3) * 4 + (l & 3);  // 0..15
    const ushort_t* A  = vwb + (size_t)h * C_ * C_ + (size_t)mt * 256 * C_;
    const ushort_t* Bm = Tt + (size_t)h * 16 * N_ * C_ + (size_t)nt * 256 * C_;
    const int K = C_;

    fx4 acc[8][4];
#pragma unroll
    for (int i = 0; i < 8; ++i)
#pragma unroll
        for (int j = 0; j < 4; ++j) acc[i][j] = (fx4){0.f, 0.f, 0.f, 0.f};
    gemm256_8ph(A, Bm, K, lds, acc);

    EPI256_IDX();
#pragma unroll
    for (int i = 0; i < 8; ++i)
#pragma unroll
        for (int n = 0; n < 4; ++n)
#pragma unroll
            for (int r = 0; r < 4; ++r) {
                const int e = mt * 256 + wmr + i * 16 + lhi * 4 + r;
                const int col = nt * 256 + wnr + n * 16 + l16;
                const int b = col >> 8, nn = col & 255;
                float v = acc[i][n][r] + vb[h * C_ + e]
                        + score[(size_t)(b * 4 + h) * N_ + nn] * bs2f(xb[((size_t)b * C_ + e) * N_ + nn]);
                out1[((size_t)(b * 4 + h) * C_ + e) * N_ + nn] = v;
            }
}

// sim: per bh, 128x128 tiles, K=512 (2-phase core).
__global__ __launch_bounds__(256) void k_sim(const ushort_t* __restrict__ QKbuf, float* __restrict__ simf) {
    const int wg = blockIdx.x;
    const int bh = wg >> 2, mt = (wg >> 1) & 1, ntl = wg & 1;
    const ushort_t* Qr = QKbuf;
    const ushort_t* Kr = QKbuf + (size_t)16 * 4 * 256 * 512;
    const ushort_t* A = Qr + ((size_t)bh * 256 + mt * 128) * 512;
    const ushort_t* Bm = Kr + ((size_t)bh * 256 + ntl * 128) * 512;

    fx4 acc[4][4];
#pragma unroll
    for (int i = 0; i < 4; ++i)
#pragma unroll
        for (int j = 0; j < 4; ++j) acc[i][j] = (fx4){0.f, 0.f, 0.f, 0.f};
    mfma_core(A, Bm, D_, acc);

    EPI_IDX();
    const float scale = 0.044194173824159216f;
#pragma unroll
    for (int i = 0; i < 4; ++i)
#pragma unroll
        for (int j = 0; j < 4; ++j)
#pragma unroll
            for (int r = 0; r < 4; ++r) {
                const int q = mt * 128 + wm + i * 16 + lhi * 4 + r;
                const int k = ntl * 128 + wn + j * 16 + l16;
                simf[(size_t)bh * N_ * N_ + (size_t)q * N_ + k] = acc[i][j][r] * scale;
            }
}

__global__ __launch_bounds__(64) void k_softP(const float* __restrict__ simf, ushort_t* __restrict__ Pb) {
    const size_t row = blockIdx.x;
    const float* p = simf + row * N_;
    ushort_t* o = Pb + row * N_;
    const int t = threadIdx.x;
    float v0 = p[t], v1 = p[t + 64], v2 = p[t + 128], v3 = p[t + 192];
    float mx = fmaxf(fmaxf(v0, v1), fmaxf(v2, v3));
#pragma unroll
    for (int off = 32; off; off >>= 1) mx = fmaxf(mx, __shfl_xor(mx, off, 64));
    float e0 = expf(v0 - mx), e1 = expf(v1 - mx), e2 = expf(v2 - mx), e3 = expf(v3 - mx);
    float s = e0 + e1 + e2 + e3;
#pragma unroll
    for (int off = 32; off; off >>= 1) s += __shfl_xor(s, off, 64);
    const float inv = 1.0f / s;
    o[t] = f2bs(e0 * inv); o[t + 64] = f2bs(e1 * inv);
    o[t + 128] = f2bs(e2 * inv); o[t + 192] = f2bs(e3 * inv);
}

// T: per b, M=(h,q)=1024, N=c=2048, K=256 (2-phase core). Tt[h][b][q][c] bf16.
__global__ __launch_bounds__(256) void k_T(const ushort_t* __restrict__ Pb, const ushort_t* __restrict__ xb,
                                           ushort_t* __restrict__ Tt) {
    const int wg = xcd_swz(blockIdx.x, 2048);
    const int b = wg >> 7, l = wg & 127;
    const int mt = l >> 4, nt = l & 15;
    const ushort_t* A = Pb + ((size_t)b * 1024 + mt * 128) * 256;
    const ushort_t* Bm = xb + ((size_t)b * 2048 + nt * 128) * 256;

    fx4 acc[4][4];
#pragma unroll
    for (int i = 0; i < 4; ++i)
#pragma unroll
        for (int j = 0; j < 4; ++j) acc[i][j] = (fx4){0.f, 0.f, 0.f, 0.f};
    mfma_core(A, Bm, N_, acc);

    EPI_IDX();
#pragma unroll
    for (int i = 0; i < 4; ++i)
#pragma unroll
        for (int j = 0; j < 4; ++j)
#pragma unroll
            for (int r = 0; r < 4; ++r) {
                const int rowm = mt * 128 + wm + i * 16 + lhi * 4 + r;
                const int h = rowm >> 8, q = rowm & 255;
                const int c = nt * 128 + wn + j * 16 + l16;
                Tt[(((size_t)h * 16 + b) * 256 + q) * 2048 + c] = f2bs(acc[i][j][r]);
            }
}

extern "C" void kernel_launch(void* const* d_in, const int* in_sizes, int n_in,
                              void* d_out, int out_size, void* d_ws, size_t ws_size,
                              hipStream_t stream)
{
    const float* x  = (const float*)d_in[0];
    const float* qw = (const float*)d_in[1];
    const float* qb = (const float*)d_in[2];
    const float* kw = (const float*)d_in[3];
    const float* kb = (const float*)d_in[4];
    const float* vw = (const float*)d_in[5];
    const float* vb = (const float*)d_in[6];

    float* out0 = (float*)d_out;
    float* out1 = out0 + (size_t)B_ * HEADS_ * N_;

    char* w = (char*)d_ws;
    ushort_t* vwb  = (ushort_t*)w;  w += (size_t)4 * C_ * C_ * 2;          // 33.6MB
    ushort_t* qwb  = (ushort_t*)w;  w += (size_t)4 * D_ * C_ * 2;          // 8.4MB
    ushort_t* kwb  = (ushort_t*)w;  w += (size_t)4 * D_ * C_ * 2;          // 8.4MB
    ushort_t* xb   = (ushort_t*)w;  w += (size_t)B_ * C_ * N_ * 2;         // 16.8MB
    ushort_t* QKbuf= (ushort_t*)w;  w += (size_t)2 * 16 * 4 * 256 * 512 * 2; // 33.6MB
    ushort_t* Pb   = (ushort_t*)w;  w += (size_t)64 * N_ * N_ * 2;         // 8.4MB
    float*    simf = (float*)w;     w += (size_t)64 * N_ * N_ * 4;         // 16.8MB
    ushort_t* Tt   = (ushort_t*)w;  w += (size_t)64 * N_ * C_ * 2;         // 67.1MB
    ushort_t* xbT  = Tt;  // alias: xbT (16.8MB) dead before k_T writes Tt
    float*    xpart= (float*)w;     w += (size_t)8 * B_ * C_ * 4;          // 1MB
    float*    xsum = (float*)w;     w += (size_t)B_ * C_ * 4;
    float*    qsum = (float*)w;     w += (size_t)64 * D_ * 4;
    float*    cst  = (float*)w;     w += 1024;
    float*    partv= (float*)w;     w += (size_t)4 * 64 * C_ * 4;          // 2.1MB
    float*    part = (float*)w;     w += (size_t)4 * 64 * N_ * 4;
    float*    score= (float*)w;     w += (size_t)64 * N_ * 4;

    // casts
    k_castw<<<dim3(4 * D_ * C_ / 4 / 256), 256, 0, stream>>>(qw, qwb, 4 * D_ * C_);
    k_castw<<<dim3(4 * D_ * C_ / 4 / 256), 256, 0, stream>>>(kw, kwb, 4 * D_ * C_);
    k_castw<<<dim3(4 * C_ * C_ / 4 / 256), 256, 0, stream>>>(vw, vwb, 4 * C_ * C_);
    k_cast_x<<<dim3(8, 64, 16), 256, 0, stream>>>(x, xb, xbT, xpart);

    // exact-f32 score path
    k_xsum2<<<dim3(8, 16), 256, 0, stream>>>(xpart, xsum);
    k_qsum <<<dim3(512), 256, 0, stream>>>(xsum, qw, qb, qsum);
    k_const<<<dim3(64), 64, 0, stream>>>(qsum, kb, cst);
    k_vecp <<<dim3(8, 4, 4), 256, 0, stream>>>(qsum, kw, partv);
    k_att  <<<dim3(64, 4), 256, 0, stream>>>(x, partv, part);
    k_score<<<dim3(16), 256, 0, stream>>>(part, cst, score, out0);

    // MFMA pipeline
    k_proj <<<dim3(256), 512, 0, stream>>>(xbT, qwb, kwb, qb, kb, QKbuf);
    k_sim  <<<dim3(256), 256, 0, stream>>>(QKbuf, simf);
    k_softP<<<dim3(64 * N_), 64, 0, stream>>>(simf, Pb);
    k_T    <<<dim3(2048), 256, 0, stream>>>(Pb, xb, Tt);
    k_out  <<<dim3(512), 512, 0, stream>>>(vwb, vb, Tt, score, xb, out1);
}

// Round 6
// 387.751 us; speedup vs baseline: 7.9643x; 1.0249x over previous
//
#include <hip/hip_runtime.h>
#include <hip/hip_bf16.h>

#define B_ 16
#define C_ 2048
#define N_ 256
#define HEADS_ 4
#define D_ 512

typedef unsigned int u32;
typedef unsigned short ushort_t;
typedef __attribute__((ext_vector_type(8))) short bfx8;
typedef __attribute__((ext_vector_type(4))) float fx4;

__device__ __forceinline__ unsigned short f2bs(float f) {
    __hip_bfloat16 h = __float2bfloat16(f);
    return __builtin_bit_cast(unsigned short, h);
}
__device__ __forceinline__ float bs2f(ushort_t u) {
    u32 v = ((u32)u) << 16;
    return __builtin_bit_cast(float, v);
}
__device__ __forceinline__ void gload16(const void* g, void* l) {
    __builtin_amdgcn_global_load_lds((const __attribute__((address_space(1))) u32*)g,
                                     (__attribute__((address_space(3))) u32*)l, 16, 0, 0);
}
__device__ __forceinline__ int xcd_swz(int bid, int nwg) {
    return (bid & 7) * (nwg >> 3) + (bid >> 3);
}

// ======================= 256x256 8-phase counted-vmcnt core =======================
// NT GEMM: acc[8][4] (wave 128x64 tile) += A[256][K] * B[256][K]^T, K % 64 == 0, K/64 >= 2.
// 512 threads = 8 waves (2 Mwave x 4 Nwave). LDS 128 KiB. Never drains vmcnt in loop.
//
// T2 bank swizzle: physical 16B-slot within a 64B LDS row = logical_slot ^ ((row>>1)&3).
// gload_lds dest stays linear (HW requirement); SOURCE k-octet is pre-swizzled; ds_read
// applies the same involution. row = tid>>2 at stage => c = (tid>>3)&3. At read,
// ((row>>1)&3) reduces to ((l16>>1)&3) (wave/frag bits contribute 0 mod 4).
#define VMW8() asm volatile("s_waitcnt vmcnt(8)" ::: "memory")
#define SBAR() __builtin_amdgcn_s_barrier()
#define SCB0() __builtin_amdgcn_sched_barrier(0)

#define STAGE8(MAT, BUF, KH, J) do {                                          \
    const ushort_t* s_ = (MAT) ? Bm : A;                                      \
    _Pragma("unroll")                                                         \
    for (int l_ = 0; l_ < 2; ++l_) {                                          \
        const int r_ = l_ * 128 + (tid >> 2);                                 \
        const int k_ = (J) * 64 + (KH) * 32 + (((tid & 3) ^ ((tid >> 3) & 3)) * 8); \
        gload16(s_ + (size_t)r_ * K + k_,                                     \
                (char*)(&lds[MAT][BUF][KH][0][0]) + l_ * 8192 + tid * 16);    \
    } } while (0)

#define LDA8(dst, BUF, KH, MH) do {                                           \
    _Pragma("unroll")                                                         \
    for (int i_ = 0; i_ < 4; ++i_)                                            \
        dst[i_] = *(const bfx8*)&lds[0][BUF][KH][wmr + (MH) * 64 + i_ * 16 + l16][swz8]; \
    } while (0)

#define LDB8(dst, BUF, KH) do {                                               \
    _Pragma("unroll")                                                         \
    for (int i_ = 0; i_ < 4; ++i_)                                            \
        dst[i_] = *(const bfx8*)&lds[1][BUF][KH][wnr + i_ * 16 + l16][swz8];  \
    } while (0)

#define MM8(aa, bb, MH) do {                                                  \
    __builtin_amdgcn_s_setprio(1);                                            \
    _Pragma("unroll")                                                         \
    for (int i_ = 0; i_ < 4; ++i_) {                                          \
        _Pragma("unroll")                                                     \
        for (int n_ = 0; n_ < 4; ++n_)                                        \
            acc[(MH) * 4 + i_][n_] = __builtin_amdgcn_mfma_f32_16x16x32_bf16( \
                aa[i_], bb[n_], acc[(MH) * 4 + i_][n_], 0, 0, 0);             \
    }                                                                         \
    __builtin_amdgcn_s_setprio(0);                                            \
} while (0)

// lds must be declared in the kernel (static shared); passed by reference.
typedef ushort_t lds256_t[2][2][2][256][32];

__device__ __forceinline__ void gemm256_8ph(const ushort_t* __restrict__ A,
                                            const ushort_t* __restrict__ Bm,
                                            int K, lds256_t& lds, fx4 acc[8][4])
{
    const int tid = threadIdx.x;
    const int lane = tid & 63;
    const int w = tid >> 6;
    const int l16 = lane & 15, lhi = lane >> 4;
    const int swz8 = (lhi ^ ((l16 >> 1) & 3)) * 8;   // T2 read-side involution
    const int wmr = (w >> 2) * 128;
    const int wnr = (w & 3) * 64;
    const int nkt = K >> 6;

    // prologue: tile0 (k0,k1) + tile1 k0   = 12 loads/wave
    STAGE8(0, 0, 0, 0); STAGE8(1, 0, 0, 0);
    STAGE8(0, 0, 1, 0); STAGE8(1, 0, 1, 0);
    STAGE8(0, 1, 0, 1); STAGE8(1, 1, 0, 1);
    VMW8();
    SBAR();

    for (int j = 0; j < nkt; ++j) {
        const int b = j & 1;
        const int js1 = (j + 1 < nkt) ? j + 1 : j;
        const int js2 = (j + 2 < nkt) ? j + 2 : j;
        bfx8 a0[4], a1[4], b0[4], b1[4];
        // ---- phase 0: (mh0, k0) ----
        LDA8(a0, b, 0, 0);
        LDB8(b0, b, 0);
        STAGE8(0, b ^ 1, 1, js1);            // A of tile j+1, k1
        SBAR();
        MM8(a0, b0, 0);
        SCB0();
        SBAR();
        // ---- phase 1: (mh1, k0) ----
        LDA8(a1, b, 0, 1);
        STAGE8(1, b ^ 1, 1, js1);            // B of tile j+1, k1
        SBAR();
        MM8(a1, b0, 1);
        SCB0();
        VMW8();                              // tile j k1 ready for ph2
        SBAR();
        // ---- phase 2: (mh0, k1) ----
        LDA8(a0, b, 1, 0);
        LDB8(b1, b, 1);
        STAGE8(0, b, 0, js2);                // A of tile j+2, k0 (region released after ph1)
        SBAR();
        MM8(a0, b1, 0);
        SCB0();
        SBAR();
        // ---- phase 3: (mh1, k1) ----
        LDA8(a1, b, 1, 1);
        STAGE8(1, b, 0, js2);                // B of tile j+2, k0
        SBAR();
        MM8(a1, b1, 1);
        SCB0();
        VMW8();                              // tile j+1 k0 ready for next ph0
        SBAR();
    }
}

#define EPI256_IDX() \
    const int lane = threadIdx.x & 63, w = threadIdx.x >> 6; \
    const int l16 = lane & 15, lhi = lane >> 4; \
    const int wmr = (w >> 2) * 128, wnr = (w & 3) * 64;

// ---------------- 128x128 2-phase core (kept for k_sim / k_T), same T2 swizzle ----------------
__device__ __forceinline__ void mfma_core(const ushort_t* __restrict__ A,
                                          const ushort_t* __restrict__ Bm,
                                          int K, fx4 acc[4][4])
{
    __shared__ __align__(16) ushort_t As[128 * 32];
    __shared__ __align__(16) ushort_t Bs[128 * 32];
    const int tid = threadIdx.x;
    const int lane = tid & 63, wave = tid >> 6;
    const int l16 = lane & 15, lhi = lane >> 4;
    const int swz8 = (lhi ^ ((l16 >> 1) & 3)) * 8;
    const int wm = (wave >> 1) * 64, wn = (wave & 1) * 64;

    for (int k0 = 0; k0 < K; k0 += 32) {
        const int f0 = tid, f1 = tid + 256;
        gload16(A + (size_t)(f0 >> 2) * K + k0 + (((f0 & 3) ^ ((f0 >> 3) & 3)) * 8), As + f0 * 8);
        gload16(A + (size_t)(f1 >> 2) * K + k0 + (((f1 & 3) ^ ((f1 >> 3) & 3)) * 8), As + f1 * 8);
        gload16(Bm + (size_t)(f0 >> 2) * K + k0 + (((f0 & 3) ^ ((f0 >> 3) & 3)) * 8), Bs + f0 * 8);
        gload16(Bm + (size_t)(f1 >> 2) * K + k0 + (((f1 & 3) ^ ((f1 >> 3) & 3)) * 8), Bs + f1 * 8);
        __syncthreads();
        bfx8 af[4], bfr[4];
#pragma unroll
        for (int i = 0; i < 4; ++i)
            af[i] = *(const bfx8*)(As + (wm + i * 16 + l16) * 32 + swz8);
#pragma unroll
        for (int j = 0; j < 4; ++j)
            bfr[j] = *(const bfx8*)(Bs + (wn + j * 16 + l16) * 32 + swz8);
#pragma unroll
        for (int i = 0; i < 4; ++i)
#pragma unroll
            for (int j = 0; j < 4; ++j)
                acc[i][j] = __builtin_amdgcn_mfma_f32_16x16x32_bf16(af[i], bfr[j], acc[i][j], 0, 0, 0);
        __syncthreads();
    }
}

#define EPI_IDX() \
    const int lane = threadIdx.x & 63, wave = threadIdx.x >> 6; \
    const int l16 = lane & 15, lhi = lane >> 4; \
    const int wm = (wave >> 1) * 64, wn = (wave & 1) * 64;

// ---------------- casts ----------------
__global__ __launch_bounds__(256) void k_castw(const float* __restrict__ s, ushort_t* __restrict__ d, int n) {
    int i = (blockIdx.x * 256 + threadIdx.x) * 4;
    if (i >= n) return;
    float4 v = *(const float4*)(s + i);
    ushort4 o = { f2bs(v.x), f2bs(v.y), f2bs(v.z), f2bs(v.w) };
    *(ushort4*)(d + i) = o;
}

__global__ __launch_bounds__(256) void k_cast_x(const float* __restrict__ x,
                                                ushort_t* __restrict__ xb, ushort_t* __restrict__ xbT,
                                                float* __restrict__ xpart) {
    __shared__ float t[32][33];
    const int b = blockIdx.z, c0 = blockIdx.y * 32, n0 = blockIdx.x * 32;
    const int tn = threadIdx.x & 31, tc8 = threadIdx.x >> 5;
    const float* xp = x + ((size_t)b * C_ + c0) * N_ + n0;
#pragma unroll
    for (int p = 0; p < 4; ++p) {
        int cc = tc8 + p * 8;
        float v = xp[(size_t)cc * N_ + tn];
        t[cc][tn] = v;
        xb[((size_t)b * C_ + c0 + cc) * N_ + n0 + tn] = f2bs(v);
        float s = v;
#pragma unroll
        for (int o = 16; o; o >>= 1) s += __shfl_xor(s, o, 32);
        if (tn == 0) xpart[(size_t)blockIdx.x * B_ * C_ + (size_t)b * C_ + c0 + cc] = s;
    }
    __syncthreads();
#pragma unroll
    for (int p = 0; p < 4; ++p) {
        int nn = tc8 + p * 8;
        xbT[((size_t)b * N_ + n0 + nn) * C_ + c0 + tn] = f2bs(t[tn][nn]);
    }
}

__global__ __launch_bounds__(256) void k_xsum2(const float* __restrict__ xpart, float* __restrict__ xsum) {
    const int c = blockIdx.x * 256 + threadIdx.x, b = blockIdx.y;
    float s = 0.f;
#pragma unroll
    for (int t = 0; t < 8; ++t) s += xpart[(size_t)t * B_ * C_ + (size_t)b * C_ + c];
    xsum[(size_t)b * C_ + c] = s;
}

// ---------------- exact-f32 score path ----------------
__global__ __launch_bounds__(256) void k_qsum(const float* __restrict__ xsum, const float* __restrict__ qw,
                                              const float* __restrict__ qb, float* __restrict__ qsum) {
    const int wave = threadIdx.x >> 6, lane = threadIdx.x & 63;
    const int row = blockIdx.x * 4 + wave;            // h*512+d, in [0, 2048)
    const int h = row >> 9, d = row & 511;
    const float* wr = qw + (size_t)row * C_;
    float acc[16];
#pragma unroll
    for (int bb = 0; bb < 16; ++bb) acc[bb] = 0.f;
    for (int it = 0; it < C_ / 64; ++it) {
        const int c = it * 64 + lane;
        const float w = wr[c];
#pragma unroll
        for (int bb = 0; bb < 16; ++bb) acc[bb] += xsum[(size_t)bb * C_ + c] * w;
    }
#pragma unroll
    for (int bb = 0; bb < 16; ++bb) {
        float s = acc[bb];
#pragma unroll
        for (int o = 32; o; o >>= 1) s += __shfl_xor(s, o, 64);
        if (lane == 0) qsum[(size_t)((bb << 2) | h) * D_ + d] = s + 256.0f * qb[row];
    }
}

__global__ __launch_bounds__(64) void k_const(const float* __restrict__ qsum, const float* __restrict__ kb,
                                              float* __restrict__ cst) {
    const int bh = blockIdx.x, h = bh & 3, lane = threadIdx.x;
    float s = 0.f;
    for (int d = lane; d < D_; d += 64) s += qsum[(size_t)bh * D_ + d] * kb[h * D_ + d];
#pragma unroll
    for (int o = 32; o; o >>= 1) s += __shfl_xor(s, o, 64);
    if (lane == 0) cst[bh] = s;
}

__global__ __launch_bounds__(256) void k_vecp(const float* __restrict__ qsum, const float* __restrict__ kw,
                                              float* __restrict__ partv) {
    const int ct = blockIdx.x, h = blockIdx.y, dsl = blockIdx.z;
    __shared__ float qs[16 * 128];
    for (int i = threadIdx.x; i < 16 * 128; i += 256) {
        int bb = i >> 7, dd = i & 127;
        qs[i] = qsum[(size_t)((bb << 2) | h) * D_ + dsl * 128 + dd];
    }
    __syncthreads();
    const int c = ct * 256 + threadIdx.x;
    const float* wp = kw + ((size_t)h * D_ + dsl * 128) * C_ + c;
    float acc[16];
#pragma unroll
    for (int bb = 0; bb < 16; ++bb) acc[bb] = 0.f;
    for (int dd = 0; dd < 128; ++dd) {
        const float w = wp[(size_t)dd * C_];
#pragma unroll
        for (int bb = 0; bb < 16; ++bb) acc[bb] += qs[bb * 128 + dd] * w;
    }
#pragma unroll
    for (int bb = 0; bb < 16; ++bb)
        partv[((size_t)dsl * 64 + ((bb << 2) | h)) * C_ + c] = acc[bb];
}

__global__ __launch_bounds__(256) void k_att(const float* __restrict__ x, const float* __restrict__ partv,
                                             float* __restrict__ part) {
    const int bh = blockIdx.x, sl = blockIdx.y, b = bh >> 2;
    __shared__ float vs[512];
    const int c0 = sl * 512;
    for (int i = threadIdx.x; i < 512; i += 256) {
        float v = 0.f;
#pragma unroll
        for (int dsl = 0; dsl < 4; ++dsl) v += partv[((size_t)dsl * 64 + bh) * C_ + c0 + i];
        vs[i] = v;
    }
    __syncthreads();
    float a = 0.f;
    const float* xp = x + ((size_t)b * C_ + c0) * N_ + threadIdx.x;
#pragma unroll 8
    for (int c = 0; c < 512; ++c) a += vs[c] * xp[(size_t)c * N_];
    part[((size_t)sl * 64 + bh) * N_ + threadIdx.x] = a;
}

__global__ __launch_bounds__(256) void k_score(const float* __restrict__ part, const float* __restrict__ cst,
                                               float* __restrict__ score, float* __restrict__ out0) {
    const int b = blockIdx.x, k = threadIdx.x;
    const float scale = 0.044194173824159216f;
    float a[4];
#pragma unroll
    for (int h = 0; h < 4; ++h) {
        const int bh = b * 4 + h;
        float s = cst[bh];
#pragma unroll
        for (int sl = 0; sl < 4; ++sl) s += part[((size_t)sl * 64 + bh) * N_ + k];
        a[h] = s * scale;
    }
    float mx = fmaxf(fmaxf(a[0], a[1]), fmaxf(a[2], a[3]));
    float e0 = expf(a[0] - mx), e1 = expf(a[1] - mx), e2 = expf(a[2] - mx), e3 = expf(a[3] - mx);
    float inv = 1.0f / (e0 + e1 + e2 + e3);
    float r[4] = { e0 * inv, e1 * inv, e2 * inv, e3 * inv };
#pragma unroll
    for (int h = 0; h < 4; ++h) {
        score[(size_t)(b * 4 + h) * N_ + k] = r[h];
        out0[(size_t)(b * 4 + h) * N_ + k] = r[h];
    }
}

// ---------------- 8-phase MFMA GEMMs ----------------
// proj: M=(b,n)=4096, N=(qk,h,d)=4096, K=2048. 256 wg x 512 thr.
__global__ __launch_bounds__(512, 2) void k_proj(const ushort_t* __restrict__ xbT,
                                                 const ushort_t* __restrict__ qwb, const ushort_t* __restrict__ kwb,
                                                 const float* __restrict__ qb, const float* __restrict__ kb,
                                                 ushort_t* __restrict__ QKbuf) {
    __shared__ __align__(16) lds256_t lds;
    const int wg = xcd_swz(blockIdx.x, 256);
    const int quad = wg >> 2;
    const int mt = quad >> 2;                 // 0..15
    const int nt = (quad & 3) * 4 + (wg & 3); // 0..15
    const int c0 = nt * 256;
    const int qk = c0 >> 11;
    const int rem = c0 & 2047;                // h*512 + d0
    const ushort_t* A  = xbT + (size_t)mt * 256 * C_;
    const ushort_t* Bm = (qk ? kwb : qwb) + (size_t)rem * C_;
    const float* bias  = (qk ? kb : qb) + rem;
    const int K = C_;

    fx4 acc[8][4];
#pragma unroll
    for (int i = 0; i < 8; ++i)
#pragma unroll
        for (int j = 0; j < 4; ++j) acc[i][j] = (fx4){0.f, 0.f, 0.f, 0.f};
    gemm256_8ph(A, Bm, K, lds, acc);

    EPI256_IDX();
#pragma unroll
    for (int i = 0; i < 8; ++i)
#pragma unroll
        for (int n = 0; n < 4; ++n)
#pragma unroll
            for (int r = 0; r < 4; ++r) {
                const int gr = mt * 256 + wmr + i * 16 + lhi * 4 + r;
                const int bq = gr >> 8, nn = gr & 255;
                const int lc = wnr + n * 16 + l16;
                const int hh = (rem + lc) >> 9, dl = (rem + lc) & 511;
                const float v = acc[i][n][r] + bias[lc];
                QKbuf[((((size_t)(qk * 16 + bq) * 4 + hh) * 256) + nn) * 512 + dl] = f2bs(v);
            }
}

// out: per h, M=e=2048, N=(b,n)=4096, K=2048. 512 wg x 512 thr.
__global__ __launch_bounds__(512, 2) void k_out(const ushort_t* __restrict__ vwb, const float* __restrict__ vb,
                                                const ushort_t* __restrict__ Tt, const float* __restrict__ score,
                                                const ushort_t* __restrict__ xb, float* __restrict__ out1) {
    __shared__ __align__(16) lds256_t lds;
    const int wg = xcd_swz(blockIdx.x, 512);
    const int h = wg >> 7, l = wg & 127;
    const int quad = l >> 2;
    const int mt = quad >> 2;                 // 0..7
    const int nt = (quad & 3) * 4 + (l & 3);  // 0..15
    const ushort_t* A  = vwb + (size_t)h * C_ * C_ + (size_t)mt * 256 * C_;
    const ushort_t* Bm = Tt + (size_t)h * 16 * N_ * C_ + (size_t)nt * 256 * C_;
    const int K = C_;

    fx4 acc[8][4];
#pragma unroll
    for (int i = 0; i < 8; ++i)
#pragma unroll
        for (int j = 0; j < 4; ++j) acc[i][j] = (fx4){0.f, 0.f, 0.f, 0.f};
    gemm256_8ph(A, Bm, K, lds, acc);

    EPI256_IDX();
#pragma unroll
    for (int i = 0; i < 8; ++i)
#pragma unroll
        for (int n = 0; n < 4; ++n)
#pragma unroll
            for (int r = 0; r < 4; ++r) {
                const int e = mt * 256 + wmr + i * 16 + lhi * 4 + r;
                const int col = nt * 256 + wnr + n * 16 + l16;
                const int b = col >> 8, nn = col & 255;
                float v = acc[i][n][r] + vb[h * C_ + e]
                        + score[(size_t)(b * 4 + h) * N_ + nn] * bs2f(xb[((size_t)b * C_ + e) * N_ + nn]);
                out1[((size_t)(b * 4 + h) * C_ + e) * N_ + nn] = v;
            }
}

// sim: per bh, 128x128 tiles, K=512 (2-phase core).
__global__ __launch_bounds__(256) void k_sim(const ushort_t* __restrict__ QKbuf, float* __restrict__ simf) {
    const int wg = blockIdx.x;
    const int bh = wg >> 2, mt = (wg >> 1) & 1, ntl = wg & 1;
    const ushort_t* Qr = QKbuf;
    const ushort_t* Kr = QKbuf + (size_t)16 * 4 * 256 * 512;
    const ushort_t* A = Qr + ((size_t)bh * 256 + mt * 128) * 512;
    const ushort_t* Bm = Kr + ((size_t)bh * 256 + ntl * 128) * 512;

    fx4 acc[4][4];
#pragma unroll
    for (int i = 0; i < 4; ++i)
#pragma unroll
        for (int j = 0; j < 4; ++j) acc[i][j] = (fx4){0.f, 0.f, 0.f, 0.f};
    mfma_core(A, Bm, D_, acc);

    EPI_IDX();
    const float scale = 0.044194173824159216f;
#pragma unroll
    for (int i = 0; i < 4; ++i)
#pragma unroll
        for (int j = 0; j < 4; ++j)
#pragma unroll
            for (int r = 0; r < 4; ++r) {
                const int q = mt * 128 + wm + i * 16 + lhi * 4 + r;
                const int k = ntl * 128 + wn + j * 16 + l16;
                simf[(size_t)bh * N_ * N_ + (size_t)q * N_ + k] = acc[i][j][r] * scale;
            }
}

__global__ __launch_bounds__(64) void k_softP(const float* __restrict__ simf, ushort_t* __restrict__ Pb) {
    const size_t row = blockIdx.x;
    const float* p = simf + row * N_;
    ushort_t* o = Pb + row * N_;
    const int t = threadIdx.x;
    float v0 = p[t], v1 = p[t + 64], v2 = p[t + 128], v3 = p[t + 192];
    float mx = fmaxf(fmaxf(v0, v1), fmaxf(v2, v3));
#pragma unroll
    for (int off = 32; off; off >>= 1) mx = fmaxf(mx, __shfl_xor(mx, off, 64));
    float e0 = expf(v0 - mx), e1 = expf(v1 - mx), e2 = expf(v2 - mx), e3 = expf(v3 - mx);
    float s = e0 + e1 + e2 + e3;
#pragma unroll
    for (int off = 32; off; off >>= 1) s += __shfl_xor(s, off, 64);
    const float inv = 1.0f / s;
    o[t] = f2bs(e0 * inv); o[t + 64] = f2bs(e1 * inv);
    o[t + 128] = f2bs(e2 * inv); o[t + 192] = f2bs(e3 * inv);
}

// T: per b, M=(h,q)=1024, N=c=2048, K=256 (2-phase core). Tt[h][b][q][c] bf16.
__global__ __launch_bounds__(256) void k_T(const ushort_t* __restrict__ Pb, const ushort_t* __restrict__ xb,
                                           ushort_t* __restrict__ Tt) {
    const int wg = xcd_swz(blockIdx.x, 2048);
    const int b = wg >> 7, l = wg & 127;
    const int mt = l >> 4, nt = l & 15;
    const ushort_t* A = Pb + ((size_t)b * 1024 + mt * 128) * 256;
    const ushort_t* Bm = xb + ((size_t)b * 2048 + nt * 128) * 256;

    fx4 acc[4][4];
#pragma unroll
    for (int i = 0; i < 4; ++i)
#pragma unroll
        for (int j = 0; j < 4; ++j) acc[i][j] = (fx4){0.f, 0.f, 0.f, 0.f};
    mfma_core(A, Bm, N_, acc);

    EPI_IDX();
#pragma unroll
    for (int i = 0; i < 4; ++i)
#pragma unroll
        for (int j = 0; j < 4; ++j)
#pragma unroll
            for (int r = 0; r < 4; ++r) {
                const int rowm = mt * 128 + wm + i * 16 + lhi * 4 + r;
                const int h = rowm >> 8, q = rowm & 255;
                const int c = nt * 128 + wn + j * 16 + l16;
                Tt[(((size_t)h * 16 + b) * 256 + q) * 2048 + c] = f2bs(acc[i][j][r]);
            }
}

extern "C" void kernel_launch(void* const* d_in, const int* in_sizes, int n_in,
                              void* d_out, int out_size, void* d_ws, size_t ws_size,
                              hipStream_t stream)
{
    const float* x  = (const float*)d_in[0];
    const float* qw = (const float*)d_in[1];
    const float* qb = (const float*)d_in[2];
    const float* kw = (const float*)d_in[3];
    const float* kb = (const float*)d_in[4];
    const float* vw = (const float*)d_in[5];
    const float* vb = (const float*)d_in[6];

    float* out0 = (float*)d_out;
    float* out1 = out0 + (size_t)B_ * HEADS_ * N_;

    char* w = (char*)d_ws;
    ushort_t* vwb  = (ushort_t*)w;  w += (size_t)4 * C_ * C_ * 2;          // 33.6MB
    ushort_t* qwb  = (ushort_t*)w;  w += (size_t)4 * D_ * C_ * 2;          // 8.4MB
    ushort_t* kwb  = (ushort_t*)w;  w += (size_t)4 * D_ * C_ * 2;          // 8.4MB
    ushort_t* xb   = (ushort_t*)w;  w += (size_t)B_ * C_ * N_ * 2;         // 16.8MB
    ushort_t* QKbuf= (ushort_t*)w;  w += (size_t)2 * 16 * 4 * 256 * 512 * 2; // 33.6MB
    ushort_t* Pb   = (ushort_t*)w;  w += (size_t)64 * N_ * N_ * 2;         // 8.4MB
    float*    simf = (float*)w;     w += (size_t)64 * N_ * N_ * 4;         // 16.8MB
    ushort_t* Tt   = (ushort_t*)w;  w += (size_t)64 * N_ * C_ * 2;         // 67.1MB
    ushort_t* xbT  = Tt;  // alias: xbT (16.8MB) dead before k_T writes Tt
    float*    xpart= (float*)w;     w += (size_t)8 * B_ * C_ * 4;          // 1MB
    float*    xsum = (float*)w;     w += (size_t)B_ * C_ * 4;
    float*    qsum = (float*)w;     w += (size_t)64 * D_ * 4;
    float*    cst  = (float*)w;     w += 1024;
    float*    partv= (float*)w;     w += (size_t)4 * 64 * C_ * 4;          // 2.1MB
    float*    part = (float*)w;     w += (size_t)4 * 64 * N_ * 4;
    float*    score= (float*)w;     w += (size_t)64 * N_ * 4;

    // casts
    k_castw<<<dim3(4 * D_ * C_ / 4 / 256), 256, 0, stream>>>(qw, qwb, 4 * D_ * C_);
    k_castw<<<dim3(4 * D_ * C_ / 4 / 256), 256, 0, stream>>>(kw, kwb, 4 * D_ * C_);
    k_castw<<<dim3(4 * C_ * C_ / 4 / 256), 256, 0, stream>>>(vw, vwb, 4 * C_ * C_);
    k_cast_x<<<dim3(8, 64, 16), 256, 0, stream>>>(x, xb, xbT, xpart);

    // exact-f32 score path
    k_xsum2<<<dim3(8, 16), 256, 0, stream>>>(xpart, xsum);
    k_qsum <<<dim3(512), 256, 0, stream>>>(xsum, qw, qb, qsum);
    k_const<<<dim3(64), 64, 0, stream>>>(qsum, kb, cst);
    k_vecp <<<dim3(8, 4, 4), 256, 0, stream>>>(qsum, kw, partv);
    k_att  <<<dim3(64, 4), 256, 0, stream>>>(x, partv, part);
    k_score<<<dim3(16), 256, 0, stream>>>(part, cst, score, out0);

    // MFMA pipeline
    k_proj <<<dim3(256), 512, 0, stream>>>(xbT, qwb, kwb, qb, kb, QKbuf);
    k_sim  <<<dim3(256), 256, 0, stream>>>(QKbuf, simf);
    k_softP<<<dim3(64 * N_), 64, 0, stream>>>(simf, Pb);
    k_T    <<<dim3(2048), 256, 0, stream>>>(Pb, xb, Tt);
    k_out  <<<dim3(512), 512, 0, stream>>>(vwb, vb, Tt, score, xb, out1);
}

// Round 7
// 386.588 us; speedup vs baseline: 7.9883x; 1.0030x over previous
//
#include <hip/hip_runtime.h>
#include <hip/hip_bf16.h>

#define B_ 16
#define C_ 2048
#define N_ 256
#define HEADS_ 4
#define D_ 512

typedef unsigned int u32;
typedef unsigned short ushort_t;
typedef __attribute__((ext_vector_type(8))) short bfx8;
typedef __attribute__((ext_vector_type(4))) float fx4;

__device__ __forceinline__ unsigned short f2bs(float f) {
    __hip_bfloat16 h = __float2bfloat16(f);
    return __builtin_bit_cast(unsigned short, h);
}
__device__ __forceinline__ float bs2f(ushort_t u) {
    u32 v = ((u32)u) << 16;
    return __builtin_bit_cast(float, v);
}
__device__ __forceinline__ void gload16(const void* g, void* l) {
    __builtin_amdgcn_global_load_lds((const __attribute__((address_space(1))) u32*)g,
                                     (__attribute__((address_space(3))) u32*)l, 16, 0, 0);
}
__device__ __forceinline__ int xcd_swz(int bid, int nwg) {
    return (bid & 7) * (nwg >> 3) + (bid >> 3);
}

// ======================= 256x256 8-phase counted-vmcnt core =======================
// NT GEMM: acc[8][4] (wave 128x64 tile) += A[256][K] * B[256][K]^T, K % 128 == 0.
// 512 threads = 8 waves (2 Mwave x 4 Nwave). LDS 128 KiB. Never drains vmcnt in loop.
// 2-K-tile unrolled iteration => all LDS buffer indices are compile-time literals.
// Each phase: {ds_read frags; issue 1 stage region; barrier; lgkmcnt(0)+fence; 16 MFMA (setprio);
// [vmcnt(8) at phases 1&3]; barrier}.
//
// T2 bank swizzle: physical 16B-slot within a 64B LDS row = logical_slot ^ ((row>>1)&3).
// gload_lds dest stays linear; SOURCE k-octet pre-swizzled; ds_read applies same involution.
#define VMW8() asm volatile("s_waitcnt vmcnt(8)" ::: "memory")
#define SBAR() __builtin_amdgcn_s_barrier()
#define LGKM0() do { asm volatile("s_waitcnt lgkmcnt(0)" ::: "memory"); \
                     __builtin_amdgcn_sched_barrier(0); } while (0)

#define STAGE8(MAT, BUF, KH, J) do {                                          \
    const ushort_t* s_ = (MAT) ? Bm : A;                                      \
    _Pragma("unroll")                                                         \
    for (int l_ = 0; l_ < 2; ++l_) {                                          \
        const int r_ = l_ * 128 + (tid >> 2);                                 \
        const int k_ = (J) * 64 + (KH) * 32 + (((tid & 3) ^ ((tid >> 3) & 3)) * 8); \
        gload16(s_ + (size_t)r_ * K + k_,                                     \
                (char*)(&lds[MAT][BUF][KH][0][0]) + l_ * 8192 + tid * 16);    \
    } } while (0)

#define LDA8(dst, BUF, KH, MH) do {                                           \
    _Pragma("unroll")                                                         \
    for (int i_ = 0; i_ < 4; ++i_)                                            \
        dst[i_] = *(const bfx8*)&lds[0][BUF][KH][wmr + (MH) * 64 + i_ * 16 + l16][swz8]; \
    } while (0)

#define LDB8(dst, BUF, KH) do {                                               \
    _Pragma("unroll")                                                         \
    for (int i_ = 0; i_ < 4; ++i_)                                            \
        dst[i_] = *(const bfx8*)&lds[1][BUF][KH][wnr + i_ * 16 + l16][swz8];  \
    } while (0)

#define MM8(aa, bb, MH) do {                                                  \
    __builtin_amdgcn_s_setprio(1);                                            \
    _Pragma("unroll")                                                         \
    for (int i_ = 0; i_ < 4; ++i_) {                                          \
        _Pragma("unroll")                                                     \
        for (int n_ = 0; n_ < 4; ++n_)                                        \
            acc[(MH) * 4 + i_][n_] = __builtin_amdgcn_mfma_f32_16x16x32_bf16( \
                aa[i_], bb[n_], acc[(MH) * 4 + i_][n_], 0, 0, 0);             \
    }                                                                         \
    __builtin_amdgcn_s_setprio(0);                                            \
} while (0)

// One K-tile (4 phases), BUF is a literal 0/1.
#define KTILE(BUF, JS1, JS2) do {                                             \
    bfx8 a0[4], a1[4], b0[4], b1[4];                                          \
    /* phase 0: (mh0,k0) */                                                   \
    LDA8(a0, BUF, 0, 0); LDB8(b0, BUF, 0);                                    \
    STAGE8(0, BUF ^ 1, 1, JS1);                                               \
    SBAR(); LGKM0();                                                          \
    MM8(a0, b0, 0);                                                           \
    SBAR();                                                                   \
    /* phase 1: (mh1,k0) */                                                   \
    LDA8(a1, BUF, 0, 1);                                                      \
    STAGE8(1, BUF ^ 1, 1, JS1);                                               \
    SBAR(); LGKM0();                                                          \
    MM8(a1, b0, 1);                                                           \
    VMW8();                                                                   \
    SBAR();                                                                   \
    /* phase 2: (mh0,k1) */                                                   \
    LDA8(a0, BUF, 1, 0); LDB8(b1, BUF, 1);                                    \
    STAGE8(0, BUF, 0, JS2);                                                   \
    SBAR(); LGKM0();                                                          \
    MM8(a0, b1, 0);                                                           \
    SBAR();                                                                   \
    /* phase 3: (mh1,k1) */                                                   \
    LDA8(a1, BUF, 1, 1);                                                      \
    STAGE8(1, BUF, 0, JS2);                                                   \
    SBAR(); LGKM0();                                                          \
    MM8(a1, b1, 1);                                                           \
    VMW8();                                                                   \
    SBAR();                                                                   \
} while (0)

typedef ushort_t lds256_t[2][2][2][256][32];

__device__ __forceinline__ void gemm256_8ph(const ushort_t* __restrict__ A,
                                            const ushort_t* __restrict__ Bm,
                                            int K, lds256_t& lds, fx4 acc[8][4])
{
    const int tid = threadIdx.x;
    const int lane = tid & 63;
    const int w = tid >> 6;
    const int l16 = lane & 15, lhi = lane >> 4;
    const int swz8 = (lhi ^ ((l16 >> 1) & 3)) * 8;   // T2 read-side involution
    const int wmr = (w >> 2) * 128;
    const int wnr = (w & 3) * 64;
    const int nkt = K >> 6;                           // even, >= 4

    // prologue: tile0 (k0,k1) + tile1 k0 = 12 loads/wave-thread
    STAGE8(0, 0, 0, 0); STAGE8(1, 0, 0, 0);
    STAGE8(0, 0, 1, 0); STAGE8(1, 0, 1, 0);
    STAGE8(0, 1, 0, 1); STAGE8(1, 1, 0, 1);
    VMW8();
    SBAR();

    for (int jj = 0; jj < nkt; jj += 2) {
        const int js1a = jj + 1;                              // < nkt always
        const int js2a = (jj + 2 < nkt) ? jj + 2 : nkt - 1;   // clamped (redundant restage at tail)
        const int js1b = js2a;
        const int js2b = (jj + 3 < nkt) ? jj + 3 : nkt - 1;
        KTILE(0, js1a, js2a);     // K-tile jj   (buf 0)
        KTILE(1, js1b, js2b);     // K-tile jj+1 (buf 1)
    }
}

#define EPI256_IDX() \
    const int lane = threadIdx.x & 63, w = threadIdx.x >> 6; \
    const int l16 = lane & 15, lhi = lane >> 4; \
    const int wmr = (w >> 2) * 128, wnr = (w & 3) * 64;

// ---------------- 128x128 2-phase core (kept for k_sim), T2-swizzled ----------------
__device__ __forceinline__ void mfma_core(const ushort_t* __restrict__ A,
                                          const ushort_t* __restrict__ Bm,
                                          int K, fx4 acc[4][4])
{
    __shared__ __align__(16) ushort_t As[128 * 32];
    __shared__ __align__(16) ushort_t Bs[128 * 32];
    const int tid = threadIdx.x;
    const int lane = tid & 63, wave = tid >> 6;
    const int l16 = lane & 15, lhi = lane >> 4;
    const int swz8 = (lhi ^ ((l16 >> 1) & 3)) * 8;
    const int wm = (wave >> 1) * 64, wn = (wave & 1) * 64;

    for (int k0 = 0; k0 < K; k0 += 32) {
        const int f0 = tid, f1 = tid + 256;
        gload16(A + (size_t)(f0 >> 2) * K + k0 + (((f0 & 3) ^ ((f0 >> 3) & 3)) * 8), As + f0 * 8);
        gload16(A + (size_t)(f1 >> 2) * K + k0 + (((f1 & 3) ^ ((f1 >> 3) & 3)) * 8), As + f1 * 8);
        gload16(Bm + (size_t)(f0 >> 2) * K + k0 + (((f0 & 3) ^ ((f0 >> 3) & 3)) * 8), Bs + f0 * 8);
        gload16(Bm + (size_t)(f1 >> 2) * K + k0 + (((f1 & 3) ^ ((f1 >> 3) & 3)) * 8), Bs + f1 * 8);
        __syncthreads();
        bfx8 af[4], bfr[4];
#pragma unroll
        for (int i = 0; i < 4; ++i)
            af[i] = *(const bfx8*)(As + (wm + i * 16 + l16) * 32 + swz8);
#pragma unroll
        for (int j = 0; j < 4; ++j)
            bfr[j] = *(const bfx8*)(Bs + (wn + j * 16 + l16) * 32 + swz8);
#pragma unroll
        for (int i = 0; i < 4; ++i)
#pragma unroll
            for (int j = 0; j < 4; ++j)
                acc[i][j] = __builtin_amdgcn_mfma_f32_16x16x32_bf16(af[i], bfr[j], acc[i][j], 0, 0, 0);
        __syncthreads();
    }
}

#define EPI_IDX() \
    const int lane = threadIdx.x & 63, wave = threadIdx.x >> 6; \
    const int l16 = lane & 15, lhi = lane >> 4; \
    const int wm = (wave >> 1) * 64, wn = (wave & 1) * 64;

// ---------------- casts ----------------
__global__ __launch_bounds__(256) void k_castw(const float* __restrict__ s, ushort_t* __restrict__ d, int n) {
    int i = (blockIdx.x * 256 + threadIdx.x) * 4;
    if (i >= n) return;
    float4 v = *(const float4*)(s + i);
    ushort4 o = { f2bs(v.x), f2bs(v.y), f2bs(v.z), f2bs(v.w) };
    *(ushort4*)(d + i) = o;
}

__global__ __launch_bounds__(256) void k_cast_x(const float* __restrict__ x,
                                                ushort_t* __restrict__ xb, ushort_t* __restrict__ xbT,
                                                float* __restrict__ xpart) {
    __shared__ float t[32][33];
    const int b = blockIdx.z, c0 = blockIdx.y * 32, n0 = blockIdx.x * 32;
    const int tn = threadIdx.x & 31, tc8 = threadIdx.x >> 5;
    const float* xp = x + ((size_t)b * C_ + c0) * N_ + n0;
#pragma unroll
    for (int p = 0; p < 4; ++p) {
        int cc = tc8 + p * 8;
        float v = xp[(size_t)cc * N_ + tn];
        t[cc][tn] = v;
        xb[((size_t)b * C_ + c0 + cc) * N_ + n0 + tn] = f2bs(v);
        float s = v;
#pragma unroll
        for (int o = 16; o; o >>= 1) s += __shfl_xor(s, o, 32);
        if (tn == 0) xpart[(size_t)blockIdx.x * B_ * C_ + (size_t)b * C_ + c0 + cc] = s;
    }
    __syncthreads();
#pragma unroll
    for (int p = 0; p < 4; ++p) {
        int nn = tc8 + p * 8;
        xbT[((size_t)b * N_ + n0 + nn) * C_ + c0 + tn] = f2bs(t[tn][nn]);
    }
}

__global__ __launch_bounds__(256) void k_xsum2(const float* __restrict__ xpart, float* __restrict__ xsum) {
    const int c = blockIdx.x * 256 + threadIdx.x, b = blockIdx.y;
    float s = 0.f;
#pragma unroll
    for (int t = 0; t < 8; ++t) s += xpart[(size_t)t * B_ * C_ + (size_t)b * C_ + c];
    xsum[(size_t)b * C_ + c] = s;
}

// ---------------- exact-f32 score path ----------------
__global__ __launch_bounds__(256) void k_qsum(const float* __restrict__ xsum, const float* __restrict__ qw,
                                              const float* __restrict__ qb, float* __restrict__ qsum) {
    const int wave = threadIdx.x >> 6, lane = threadIdx.x & 63;
    const int row = blockIdx.x * 4 + wave;            // h*512+d, in [0, 2048)
    const int h = row >> 9, d = row & 511;
    const float* wr = qw + (size_t)row * C_;
    float acc[16];
#pragma unroll
    for (int bb = 0; bb < 16; ++bb) acc[bb] = 0.f;
    for (int it = 0; it < C_ / 64; ++it) {
        const int c = it * 64 + lane;
        const float w = wr[c];
#pragma unroll
        for (int bb = 0; bb < 16; ++bb) acc[bb] += xsum[(size_t)bb * C_ + c] * w;
    }
#pragma unroll
    for (int bb = 0; bb < 16; ++bb) {
        float s = acc[bb];
#pragma unroll
        for (int o = 32; o; o >>= 1) s += __shfl_xor(s, o, 64);
        if (lane == 0) qsum[(size_t)((bb << 2) | h) * D_ + d] = s + 256.0f * qb[row];
    }
}

__global__ __launch_bounds__(64) void k_const(const float* __restrict__ qsum, const float* __restrict__ kb,
                                              float* __restrict__ cst) {
    const int bh = blockIdx.x, h = bh & 3, lane = threadIdx.x;
    float s = 0.f;
    for (int d = lane; d < D_; d += 64) s += qsum[(size_t)bh * D_ + d] * kb[h * D_ + d];
#pragma unroll
    for (int o = 32; o; o >>= 1) s += __shfl_xor(s, o, 64);
    if (lane == 0) cst[bh] = s;
}

__global__ __launch_bounds__(256) void k_vecp(const float* __restrict__ qsum, const float* __restrict__ kw,
                                              float* __restrict__ partv) {
    const int ct = blockIdx.x, h = blockIdx.y, dsl = blockIdx.z;
    __shared__ float qs[16 * 128];
    for (int i = threadIdx.x; i < 16 * 128; i += 256) {
        int bb = i >> 7, dd = i & 127;
        qs[i] = qsum[(size_t)((bb << 2) | h) * D_ + dsl * 128 + dd];
    }
    __syncthreads();
    const int c = ct * 256 + threadIdx.x;
    const float* wp = kw + ((size_t)h * D_ + dsl * 128) * C_ + c;
    float acc[16];
#pragma unroll
    for (int bb = 0; bb < 16; ++bb) acc[bb] = 0.f;
    for (int dd = 0; dd < 128; ++dd) {
        const float w = wp[(size_t)dd * C_];
#pragma unroll
        for (int bb = 0; bb < 16; ++bb) acc[bb] += qs[bb * 128 + dd] * w;
    }
#pragma unroll
    for (int bb = 0; bb < 16; ++bb)
        partv[((size_t)dsl * 64 + ((bb << 2) | h)) * C_ + c] = acc[bb];
}

__global__ __launch_bounds__(256) void k_att(const float* __restrict__ x, const float* __restrict__ partv,
                                             float* __restrict__ part) {
    const int bh = blockIdx.x, sl = blockIdx.y, b = bh >> 2;
    __shared__ float vs[512];
    const int c0 = sl * 512;
    for (int i = threadIdx.x; i < 512; i += 256) {
        float v = 0.f;
#pragma unroll
        for (int dsl = 0; dsl < 4; ++dsl) v += partv[((size_t)dsl * 64 + bh) * C_ + c0 + i];
        vs[i] = v;
    }
    __syncthreads();
    float a = 0.f;
    const float* xp = x + ((size_t)b * C_ + c0) * N_ + threadIdx.x;
#pragma unroll 8
    for (int c = 0; c < 512; ++c) a += vs[c] * xp[(size_t)c * N_];
    part[((size_t)sl * 64 + bh) * N_ + threadIdx.x] = a;
}

__global__ __launch_bounds__(256) void k_score(const float* __restrict__ part, const float* __restrict__ cst,
                                               float* __restrict__ score, float* __restrict__ out0) {
    const int b = blockIdx.x, k = threadIdx.x;
    const float scale = 0.044194173824159216f;
    float a[4];
#pragma unroll
    for (int h = 0; h < 4; ++h) {
        const int bh = b * 4 + h;
        float s = cst[bh];
#pragma unroll
        for (int sl = 0; sl < 4; ++sl) s += part[((size_t)sl * 64 + bh) * N_ + k];
        a[h] = s * scale;
    }
    float mx = fmaxf(fmaxf(a[0], a[1]), fmaxf(a[2], a[3]));
    float e0 = expf(a[0] - mx), e1 = expf(a[1] - mx), e2 = expf(a[2] - mx), e3 = expf(a[3] - mx);
    float inv = 1.0f / (e0 + e1 + e2 + e3);
    float r[4] = { e0 * inv, e1 * inv, e2 * inv, e3 * inv };
#pragma unroll
    for (int h = 0; h < 4; ++h) {
        score[(size_t)(b * 4 + h) * N_ + k] = r[h];
        out0[(size_t)(b * 4 + h) * N_ + k] = r[h];
    }
}

// ---------------- 8-phase MFMA GEMMs ----------------
// proj: M=(b,n)=4096, N=(qk,h,d)=4096, K=2048. 256 wg x 512 thr.
__global__ __launch_bounds__(512, 2) void k_proj(const ushort_t* __restrict__ xbT,
                                                 const ushort_t* __restrict__ qwb, const ushort_t* __restrict__ kwb,
                                                 const float* __restrict__ qb, const float* __restrict__ kb,
                                                 ushort_t* __restrict__ QKbuf) {
    __shared__ __align__(16) lds256_t lds;
    const int wg = xcd_swz(blockIdx.x, 256);
    const int quad = wg >> 2;
    const int mt = quad >> 2;                 // 0..15
    const int nt = (quad & 3) * 4 + (wg & 3); // 0..15
    const int c0 = nt * 256;
    const int qk = c0 >> 11;
    const int rem = c0 & 2047;                // h*512 + d0
    const ushort_t* A  = xbT + (size_t)mt * 256 * C_;
    const ushort_t* Bm = (qk ? kwb : qwb) + (size_t)rem * C_;
    const float* bias  = (qk ? kb : qb) + rem;
    const int K = C_;

    fx4 acc[8][4];
#pragma unroll
    for (int i = 0; i < 8; ++i)
#pragma unroll
        for (int j = 0; j < 4; ++j) acc[i][j] = (fx4){0.f, 0.f, 0.f, 0.f};
    gemm256_8ph(A, Bm, K, lds, acc);

    EPI256_IDX();
#pragma unroll
    for (int i = 0; i < 8; ++i)
#pragma unroll
        for (int n = 0; n < 4; ++n)
#pragma unroll
            for (int r = 0; r < 4; ++r) {
                const int gr = mt * 256 + wmr + i * 16 + lhi * 4 + r;
                const int bq = gr >> 8, nn = gr & 255;
                const int lc = wnr + n * 16 + l16;
                const int hh = (rem + lc) >> 9, dl = (rem + lc) & 511;
                const float v = acc[i][n][r] + bias[lc];
                QKbuf[((((size_t)(qk * 16 + bq) * 4 + hh) * 256) + nn) * 512 + dl] = f2bs(v);
            }
}

// out: per h, M=e=2048, N=(b,n)=4096, K=2048. 512 wg x 512 thr.
__global__ __launch_bounds__(512, 2) void k_out(const ushort_t* __restrict__ vwb, const float* __restrict__ vb,
                                                const ushort_t* __restrict__ Tt, const float* __restrict__ score,
                                                const ushort_t* __restrict__ xb, float* __restrict__ out1) {
    __shared__ __align__(16) lds256_t lds;
    const int wg = xcd_swz(blockIdx.x, 512);
    const int h = wg >> 7, l = wg & 127;
    const int quad = l >> 2;
    const int mt = quad >> 2;                 // 0..7
    const int nt = (quad & 3) * 4 + (l & 3);  // 0..15
    const ushort_t* A  = vwb + (size_t)h * C_ * C_ + (size_t)mt * 256 * C_;
    const ushort_t* Bm = Tt + (size_t)h * 16 * N_ * C_ + (size_t)nt * 256 * C_;
    const int K = C_;

    fx4 acc[8][4];
#pragma unroll
    for (int i = 0; i < 8; ++i)
#pragma unroll
        for (int j = 0; j < 4; ++j) acc[i][j] = (fx4){0.f, 0.f, 0.f, 0.f};
    gemm256_8ph(A, Bm, K, lds, acc);

    EPI256_IDX();
#pragma unroll
    for (int i = 0; i < 8; ++i)
#pragma unroll
        for (int n = 0; n < 4; ++n)
#pragma unroll
            for (int r = 0; r < 4; ++r) {
                const int e = mt * 256 + wmr + i * 16 + lhi * 4 + r;
                const int col = nt * 256 + wnr + n * 16 + l16;
                const int b = col >> 8, nn = col & 255;
                float v = acc[i][n][r] + vb[h * C_ + e]
                        + score[(size_t)(b * 4 + h) * N_ + nn] * bs2f(xb[((size_t)b * C_ + e) * N_ + nn]);
                out1[((size_t)(b * 4 + h) * C_ + e) * N_ + nn] = v;
            }
}

// T: per b, M=(h,q)=1024, N=c=2048, K=256. 8-phase 256² core. 512 wg x 512 thr.
__global__ __launch_bounds__(512, 2) void k_T8(const ushort_t* __restrict__ Pb, const ushort_t* __restrict__ xb,
                                               ushort_t* __restrict__ Tt) {
    __shared__ __align__(16) lds256_t lds;
    const int wg = xcd_swz(blockIdx.x, 512);
    const int b = wg >> 5, l = wg & 31;       // 16 b x (4 mt x 8 nt)
    const int mt = l >> 3, nt = l & 7;
    const ushort_t* A  = Pb + ((size_t)b * 1024 + mt * 256) * 256;
    const ushort_t* Bm = xb + ((size_t)b * 2048 + nt * 256) * 256;
    const int K = N_;

    fx4 acc[8][4];
#pragma unroll
    for (int i = 0; i < 8; ++i)
#pragma unroll
        for (int j = 0; j < 4; ++j) acc[i][j] = (fx4){0.f, 0.f, 0.f, 0.f};
    gemm256_8ph(A, Bm, K, lds, acc);

    EPI256_IDX();
#pragma unroll
    for (int i = 0; i < 8; ++i)
#pragma unroll
        for (int n = 0; n < 4; ++n)
#pragma unroll
            for (int r = 0; r < 4; ++r) {
                const int rowm = mt * 256 + wmr + i * 16 + lhi * 4 + r;
                const int h = rowm >> 8, q = rowm & 255;
                const int c = nt * 256 + wnr + n * 16 + l16;
                Tt[(((size_t)h * 16 + b) * 256 + q) * 2048 + c] = f2bs(acc[i][n][r]);
            }
}

// sim: per bh, 128x128 tiles, K=512 (2-phase core).
__global__ __launch_bounds__(256) void k_sim(const ushort_t* __restrict__ QKbuf, float* __restrict__ simf) {
    const int wg = blockIdx.x;
    const int bh = wg >> 2, mt = (wg >> 1) & 1, ntl = wg & 1;
    const ushort_t* Qr = QKbuf;
    const ushort_t* Kr = QKbuf + (size_t)16 * 4 * 256 * 512;
    const ushort_t* A = Qr + ((size_t)bh * 256 + mt * 128) * 512;
    const ushort_t* Bm = Kr + ((size_t)bh * 256 + ntl * 128) * 512;

    fx4 acc[4][4];
#pragma unroll
    for (int i = 0; i < 4; ++i)
#pragma unroll
        for (int j = 0; j < 4; ++j) acc[i][j] = (fx4){0.f, 0.f, 0.f, 0.f};
    mfma_core(A, Bm, D_, acc);

    EPI_IDX();
    const float scale = 0.044194173824159216f;
#pragma unroll
    for (int i = 0; i < 4; ++i)
#pragma unroll
        for (int j = 0; j < 4; ++j)
#pragma unroll
            for (int r = 0; r < 4; ++r) {
                const int q = mt * 128 + wm + i * 16 + lhi * 4 + r;
                const int k = ntl * 128 + wn + j * 16 + l16;
                simf[(size_t)bh * N_ * N_ + (size_t)q * N_ + k] = acc[i][j][r] * scale;
            }
}

__global__ __launch_bounds__(64) void k_softP(const float* __restrict__ simf, ushort_t* __restrict__ Pb) {
    const size_t row = blockIdx.x;
    const float* p = simf + row * N_;
    ushort_t* o = Pb + row * N_;
    const int t = threadIdx.x;
    float v0 = p[t], v1 = p[t + 64], v2 = p[t + 128], v3 = p[t + 192];
    float mx = fmaxf(fmaxf(v0, v1), fmaxf(v2, v3));
#pragma unroll
    for (int off = 32; off; off >>= 1) mx = fmaxf(mx, __shfl_xor(mx, off, 64));
    float e0 = expf(v0 - mx), e1 = expf(v1 - mx), e2 = expf(v2 - mx), e3 = expf(v3 - mx);
    float s = e0 + e1 + e2 + e3;
#pragma unroll
    for (int off = 32; off; off >>= 1) s += __shfl_xor(s, off, 64);
    const float inv = 1.0f / s;
    o[t] = f2bs(e0 * inv); o[t + 64] = f2bs(e1 * inv);
    o[t + 128] = f2bs(e2 * inv); o[t + 192] = f2bs(e3 * inv);
}

extern "C" void kernel_launch(void* const* d_in, const int* in_sizes, int n_in,
                              void* d_out, int out_size, void* d_ws, size_t ws_size,
                              hipStream_t stream)
{
    const float* x  = (const float*)d_in[0];
    const float* qw = (const float*)d_in[1];
    const float* qb = (const float*)d_in[2];
    const float* kw = (const float*)d_in[3];
    const float* kb = (const float*)d_in[4];
    const float* vw = (const float*)d_in[5];
    const float* vb = (const float*)d_in[6];

    float* out0 = (float*)d_out;
    float* out1 = out0 + (size_t)B_ * HEADS_ * N_;

    char* w = (char*)d_ws;
    ushort_t* vwb  = (ushort_t*)w;  w += (size_t)4 * C_ * C_ * 2;          // 33.6MB
    ushort_t* qwb  = (ushort_t*)w;  w += (size_t)4 * D_ * C_ * 2;          // 8.4MB
    ushort_t* kwb  = (ushort_t*)w;  w += (size_t)4 * D_ * C_ * 2;          // 8.4MB
    ushort_t* xb   = (ushort_t*)w;  w += (size_t)B_ * C_ * N_ * 2;         // 16.8MB
    ushort_t* QKbuf= (ushort_t*)w;  w += (size_t)2 * 16 * 4 * 256 * 512 * 2; // 33.6MB
    ushort_t* Pb   = (ushort_t*)w;  w += (size_t)64 * N_ * N_ * 2;         // 8.4MB
    float*    simf = (float*)w;     w += (size_t)64 * N_ * N_ * 4;         // 16.8MB
    ushort_t* Tt   = (ushort_t*)w;  w += (size_t)64 * N_ * C_ * 2;         // 67.1MB
    ushort_t* xbT  = Tt;  // alias: xbT (16.8MB) dead before k_T8 writes Tt
    float*    xpart= (float*)w;     w += (size_t)8 * B_ * C_ * 4;          // 1MB
    float*    xsum = (float*)w;     w += (size_t)B_ * C_ * 4;
    float*    qsum = (float*)w;     w += (size_t)64 * D_ * 4;
    float*    cst  = (float*)w;     w += 1024;
    float*    partv= (float*)w;     w += (size_t)4 * 64 * C_ * 4;          // 2.1MB
    float*    part = (float*)w;     w += (size_t)4 * 64 * N_ * 4;
    float*    score= (float*)w;     w += (size_t)64 * N_ * 4;

    // casts
    k_castw<<<dim3(4 * D_ * C_ / 4 / 256), 256, 0, stream>>>(qw, qwb, 4 * D_ * C_);
    k_castw<<<dim3(4 * D_ * C_ / 4 / 256), 256, 0, stream>>>(kw, kwb, 4 * D_ * C_);
    k_castw<<<dim3(4 * C_ * C_ / 4 / 256), 256, 0, stream>>>(vw, vwb, 4 * C_ * C_);
    k_cast_x<<<dim3(8, 64, 16), 256, 0, stream>>>(x, xb, xbT, xpart);

    // exact-f32 score path
    k_xsum2<<<dim3(8, 16), 256, 0, stream>>>(xpart, xsum);
    k_qsum <<<dim3(512), 256, 0, stream>>>(xsum, qw, qb, qsum);
    k_const<<<dim3(64), 64, 0, stream>>>(qsum, kb, cst);
    k_vecp <<<dim3(8, 4, 4), 256, 0, stream>>>(qsum, kw, partv);
    k_att  <<<dim3(64, 4), 256, 0, stream>>>(x, partv, part);
    k_score<<<dim3(16), 256, 0, stream>>>(part, cst, score, out0);

    // MFMA pipeline
    k_proj <<<dim3(256), 512, 0, stream>>>(xbT, qwb, kwb, qb, kb, QKbuf);
    k_sim  <<<dim3(256), 256, 0, stream>>>(QKbuf, simf);
    k_softP<<<dim3(64 * N_), 64, 0, stream>>>(simf, Pb);
    k_T8   <<<dim3(512), 512, 0, stream>>>(Pb, xb, Tt);
    k_out  <<<dim3(512), 512, 0, stream>>>(vwb, vb, Tt, score, xb, out1);
}

// Round 8
// 367.210 us; speedup vs baseline: 8.4098x; 1.0528x over previous
//
#include <hip/hip_runtime.h>
#include <hip/hip_bf16.h>
#include <hip/hip_fp8.h>

#define B_ 16
#define C_ 2048
#define N_ 256
#define HEADS_ 4
#define D_ 512

typedef unsigned int u32;
typedef unsigned char u8;
typedef unsigned short ushort_t;
typedef __attribute__((ext_vector_type(8))) short bfx8;
typedef __attribute__((ext_vector_type(4))) float fx4;

__device__ __forceinline__ unsigned short f2bs(float f) {
    __hip_bfloat16 h = __float2bfloat16(f);
    return __builtin_bit_cast(unsigned short, h);
}
__device__ __forceinline__ float bs2f(ushort_t u) {
    u32 v = ((u32)u) << 16;
    return __builtin_bit_cast(float, v);
}
__device__ __forceinline__ u8 f2f8(float f) {
    return (u8)__hip_cvt_float_to_fp8(f, __HIP_SATFINITE, __HIP_E4M3);
}
__device__ __forceinline__ void gload16(const void* g, void* l) {
    __builtin_amdgcn_global_load_lds((const __attribute__((address_space(1))) u32*)g,
                                     (__attribute__((address_space(3))) u32*)l, 16, 0, 0);
}
__device__ __forceinline__ int xcd_swz(int bid, int nwg) {
    return (bid & 7) * (nwg >> 3) + (bid >> 3);
}

#define SBAR() __builtin_amdgcn_s_barrier()
#define LGKM0() do { asm volatile("s_waitcnt lgkmcnt(0)" ::: "memory"); \
                     __builtin_amdgcn_sched_barrier(0); } while (0)

// ======================= 256x256 8-phase counted-vmcnt FP8 core =======================
// NT GEMM fp8 e4m3: acc[8][4] (wave 128x64) += A[256][K] * B[256][K]^T, K%128==0.
// 512 thr = 8 waves (2Mw x 4Nw). LDS 64 KiB. Counted vmcnt(4) — never drains in loop.
// K-tile = 64 (two kh halves of 32 = one fp8 MFMA k-step each). Region (mat,buf,kh) = 8KB
// = 1 gload16/thread. Bank swizzle: 16B-half within 32B row: phys = lin ^ ((row>>2)&1);
// source pre-swizzled (gload_lds dest linear), ds_read applies same involution.
#define VMW4() asm volatile("s_waitcnt vmcnt(4)" ::: "memory")

#define STAGEF8(MAT, BUF, KH, J) do {                                         \
    const u8* s_ = (MAT) ? Bm : A;                                            \
    const int r_ = tid >> 1;                                                  \
    const int k_ = (J) * 64 + (KH) * 32 + (((tid & 1) ^ ((tid >> 3) & 1)) * 16); \
    gload16(s_ + (size_t)r_ * K + k_,                                         \
            (u8*)(&lds[MAT][BUF][KH][0][0]) + tid * 16);                      \
} while (0)

#define LDAF8(dst, BUF, KH, MH) do {                                          \
    _Pragma("unroll")                                                         \
    for (int i_ = 0; i_ < 4; ++i_)                                            \
        dst[i_] = *(const long*)(&lds[0][BUF][KH][wmr + (MH) * 64 + i_ * 16 + l16][f8off]); \
} while (0)

#define LDBF8(dst, BUF, KH) do {                                              \
    _Pragma("unroll")                                                         \
    for (int i_ = 0; i_ < 4; ++i_)                                            \
        dst[i_] = *(const long*)(&lds[1][BUF][KH][wnr + i_ * 16 + l16][f8off]); \
} while (0)

#define MMF8(aa, bb, MH) do {                                                 \
    __builtin_amdgcn_s_setprio(1);                                            \
    _Pragma("unroll")                                                         \
    for (int i_ = 0; i_ < 4; ++i_) {                                          \
        _Pragma("unroll")                                                     \
        for (int n_ = 0; n_ < 4; ++n_)                                        \
            acc[(MH) * 4 + i_][n_] = __builtin_amdgcn_mfma_f32_16x16x32_fp8_fp8( \
                aa[i_], bb[n_], acc[(MH) * 4 + i_][n_], 0, 0, 0);             \
    }                                                                         \
    __builtin_amdgcn_s_setprio(0);                                            \
} while (0)

#define KTILEF8(BUF, JS1, JS2) do {                                           \
    long a0[4], a1[4], b0[4], b1[4];                                          \
    /* phase 0: (mh0,k0) */                                                   \
    LDAF8(a0, BUF, 0, 0); LDBF8(b0, BUF, 0);                                  \
    STAGEF8(0, BUF ^ 1, 1, JS1);                                              \
    SBAR(); LGKM0();                                                          \
    MMF8(a0, b0, 0);                                                          \
    SBAR();                                                                   \
    /* phase 1: (mh1,k0) */                                                   \
    LDAF8(a1, BUF, 0, 1);                                                     \
    STAGEF8(1, BUF ^ 1, 1, JS1);                                              \
    SBAR(); LGKM0();                                                          \
    MMF8(a1, b0, 1);                                                          \
    VMW4();                                                                   \
    SBAR();                                                                   \
    /* phase 2: (mh0,k1) */                                                   \
    LDAF8(a0, BUF, 1, 0); LDBF8(b1, BUF, 1);                                  \
    STAGEF8(0, BUF, 0, JS2);                                                  \
    SBAR(); LGKM0();                                                          \
    MMF8(a0, b1, 0);                                                          \
    SBAR();                                                                   \
    /* phase 3: (mh1,k1) */                                                   \
    LDAF8(a1, BUF, 1, 1);                                                     \
    STAGEF8(1, BUF, 0, JS2);                                                  \
    SBAR(); LGKM0();                                                          \
    MMF8(a1, b1, 1);                                                          \
    VMW4();                                                                   \
    SBAR();                                                                   \
} while (0)

typedef u8 ldsf8_t[2][2][2][256][32];   // [mat][buf][kh][row][32B] = 64 KiB

__device__ __forceinline__ void gemm256_f8(const u8* __restrict__ A,
                                           const u8* __restrict__ Bm,
                                           int K, ldsf8_t& lds, fx4 acc[8][4])
{
    const int tid = threadIdx.x;
    const int lane = tid & 63;
    const int w = tid >> 6;
    const int l16 = lane & 15, lhi = lane >> 4;
    const int f8off = (((lhi >> 1) ^ ((l16 >> 2) & 1)) * 16) + (lhi & 1) * 8;
    const int wmr = (w >> 2) * 128;
    const int wnr = (w & 3) * 64;
    const int nkt = K >> 6;                           // even, >= 4

    // prologue: tile0 (k0,k1) + tile1 k0 = 6 loads/thread
    STAGEF8(0, 0, 0, 0); STAGEF8(1, 0, 0, 0);
    STAGEF8(0, 0, 1, 0); STAGEF8(1, 0, 1, 0);
    STAGEF8(0, 1, 0, 1); STAGEF8(1, 1, 0, 1);
    VMW4();
    SBAR();

    for (int jj = 0; jj < nkt; jj += 2) {
        const int js1a = jj + 1;
        const int js2a = (jj + 2 < nkt) ? jj + 2 : nkt - 1;
        const int js1b = js2a;
        const int js2b = (jj + 3 < nkt) ? jj + 3 : nkt - 1;
        KTILEF8(0, js1a, js2a);
        KTILEF8(1, js1b, js2b);
    }
    asm volatile("s_waitcnt vmcnt(0)" ::: "memory");  // drain before epilogue/exit
    SBAR();
}

#define EPI256_IDX() \
    const int lane = threadIdx.x & 63, w = threadIdx.x >> 6; \
    const int l16 = lane & 15, lhi = lane >> 4; \
    const int wmr = (w >> 2) * 128, wnr = (w & 3) * 64;

// ---------------- 128x128 2-phase bf16 core (k_sim only), T2-swizzled ----------------
__device__ __forceinline__ void mfma_core(const ushort_t* __restrict__ A,
                                          const ushort_t* __restrict__ Bm,
                                          int K, fx4 acc[4][4])
{
    __shared__ __align__(16) ushort_t As[128 * 32];
    __shared__ __align__(16) ushort_t Bs[128 * 32];
    const int tid = threadIdx.x;
    const int lane = tid & 63, wave = tid >> 6;
    const int l16 = lane & 15, lhi = lane >> 4;
    const int swz8 = (lhi ^ ((l16 >> 1) & 3)) * 8;
    const int wm = (wave >> 1) * 64, wn = (wave & 1) * 64;

    for (int k0 = 0; k0 < K; k0 += 32) {
        const int f0 = tid, f1 = tid + 256;
        gload16(A + (size_t)(f0 >> 2) * K + k0 + (((f0 & 3) ^ ((f0 >> 3) & 3)) * 8), As + f0 * 8);
        gload16(A + (size_t)(f1 >> 2) * K + k0 + (((f1 & 3) ^ ((f1 >> 3) & 3)) * 8), As + f1 * 8);
        gload16(Bm + (size_t)(f0 >> 2) * K + k0 + (((f0 & 3) ^ ((f0 >> 3) & 3)) * 8), Bs + f0 * 8);
        gload16(Bm + (size_t)(f1 >> 2) * K + k0 + (((f1 & 3) ^ ((f1 >> 3) & 3)) * 8), Bs + f1 * 8);
        __syncthreads();
        bfx8 af[4], bfr[4];
#pragma unroll
        for (int i = 0; i < 4; ++i)
            af[i] = *(const bfx8*)(As + (wm + i * 16 + l16) * 32 + swz8);
#pragma unroll
        for (int j = 0; j < 4; ++j)
            bfr[j] = *(const bfx8*)(Bs + (wn + j * 16 + l16) * 32 + swz8);
#pragma unroll
        for (int i = 0; i < 4; ++i)
#pragma unroll
            for (int j = 0; j < 4; ++j)
                acc[i][j] = __builtin_amdgcn_mfma_f32_16x16x32_bf16(af[i], bfr[j], acc[i][j], 0, 0, 0);
        __syncthreads();
    }
}

#define EPI_IDX() \
    const int lane = threadIdx.x & 63, wave = threadIdx.x >> 6; \
    const int l16 = lane & 15, lhi = lane >> 4; \
    const int wm = (wave >> 1) * 64, wn = (wave & 1) * 64;

// ---------------- casts ----------------
__global__ __launch_bounds__(256) void k_castw8(const float* __restrict__ s, u8* __restrict__ d,
                                                int n, float scale) {
    int i = (blockIdx.x * 256 + threadIdx.x) * 4;
    if (i >= n) return;
    float4 v = *(const float4*)(s + i);
    uchar4 o = { f2f8(v.x * scale), f2f8(v.y * scale), f2f8(v.z * scale), f2f8(v.w * scale) };
    *(uchar4*)(d + i) = o;
}

// x[b][c][n] -> xb bf16 [b][c][n], xb8 fp8x8 [b][c][n], xbT8 fp8x8 [b][n][c], xpart partial sums
__global__ __launch_bounds__(256) void k_cast_x(const float* __restrict__ x,
                                                ushort_t* __restrict__ xb, u8* __restrict__ xb8,
                                                u8* __restrict__ xbT8, float* __restrict__ xpart) {
    __shared__ float t[32][33];
    const int b = blockIdx.z, c0 = blockIdx.y * 32, n0 = blockIdx.x * 32;
    const int tn = threadIdx.x & 31, tc8 = threadIdx.x >> 5;
    const float* xp = x + ((size_t)b * C_ + c0) * N_ + n0;
#pragma unroll
    for (int p = 0; p < 4; ++p) {
        int cc = tc8 + p * 8;
        float v = xp[(size_t)cc * N_ + tn];
        t[cc][tn] = v;
        xb[((size_t)b * C_ + c0 + cc) * N_ + n0 + tn] = f2bs(v);
        xb8[((size_t)b * C_ + c0 + cc) * N_ + n0 + tn] = f2f8(v * 8.0f);
        float s = v;
#pragma unroll
        for (int o = 16; o; o >>= 1) s += __shfl_xor(s, o, 32);
        if (tn == 0) xpart[(size_t)blockIdx.x * B_ * C_ + (size_t)b * C_ + c0 + cc] = s;
    }
    __syncthreads();
#pragma unroll
    for (int p = 0; p < 4; ++p) {
        int nn = tc8 + p * 8;
        xbT8[((size_t)b * N_ + n0 + nn) * C_ + c0 + tn] = f2f8(t[tn][nn] * 8.0f);
    }
}

__global__ __launch_bounds__(256) void k_xsum2(const float* __restrict__ xpart, float* __restrict__ xsum) {
    const int c = blockIdx.x * 256 + threadIdx.x, b = blockIdx.y;
    float s = 0.f;
#pragma unroll
    for (int t = 0; t < 8; ++t) s += xpart[(size_t)t * B_ * C_ + (size_t)b * C_ + c];
    xsum[(size_t)b * C_ + c] = s;
}

// ---------------- exact-f32 score path ----------------
__global__ __launch_bounds__(256) void k_qsum(const float* __restrict__ xsum, const float* __restrict__ qw,
                                              const float* __restrict__ qb, float* __restrict__ qsum) {
    const int wave = threadIdx.x >> 6, lane = threadIdx.x & 63;
    const int row = blockIdx.x * 4 + wave;            // h*512+d, in [0, 2048)
    const int h = row >> 9, d = row & 511;
    const float* wr = qw + (size_t)row * C_;
    float acc[16];
#pragma unroll
    for (int bb = 0; bb < 16; ++bb) acc[bb] = 0.f;
    for (int it = 0; it < C_ / 64; ++it) {
        const int c = it * 64 + lane;
        const float w = wr[c];
#pragma unroll
        for (int bb = 0; bb < 16; ++bb) acc[bb] += xsum[(size_t)bb * C_ + c] * w;
    }
#pragma unroll
    for (int bb = 0; bb < 16; ++bb) {
        float s = acc[bb];
#pragma unroll
        for (int o = 32; o; o >>= 1) s += __shfl_xor(s, o, 64);
        if (lane == 0) qsum[(size_t)((bb << 2) | h) * D_ + d] = s + 256.0f * qb[row];
    }
}

__global__ __launch_bounds__(64) void k_const(const float* __restrict__ qsum, const float* __restrict__ kb,
                                              float* __restrict__ cst) {
    const int bh = blockIdx.x, h = bh & 3, lane = threadIdx.x;
    float s = 0.f;
    for (int d = lane; d < D_; d += 64) s += qsum[(size_t)bh * D_ + d] * kb[h * D_ + d];
#pragma unroll
    for (int o = 32; o; o >>= 1) s += __shfl_xor(s, o, 64);
    if (lane == 0) cst[bh] = s;
}

__global__ __launch_bounds__(256) void k_vecp(const float* __restrict__ qsum, const float* __restrict__ kw,
                                              float* __restrict__ partv) {
    const int ct = blockIdx.x, h = blockIdx.y, dsl = blockIdx.z;
    __shared__ float qs[16 * 128];
    for (int i = threadIdx.x; i < 16 * 128; i += 256) {
        int bb = i >> 7, dd = i & 127;
        qs[i] = qsum[(size_t)((bb << 2) | h) * D_ + dsl * 128 + dd];
    }
    __syncthreads();
    const int c = ct * 256 + threadIdx.x;
    const float* wp = kw + ((size_t)h * D_ + dsl * 128) * C_ + c;
    float acc[16];
#pragma unroll
    for (int bb = 0; bb < 16; ++bb) acc[bb] = 0.f;
    for (int dd = 0; dd < 128; ++dd) {
        const float w = wp[(size_t)dd * C_];
#pragma unroll
        for (int bb = 0; bb < 16; ++bb) acc[bb] += qs[bb * 128 + dd] * w;
    }
#pragma unroll
    for (int bb = 0; bb < 16; ++bb)
        partv[((size_t)dsl * 64 + ((bb << 2) | h)) * C_ + c] = acc[bb];
}

__global__ __launch_bounds__(256) void k_att(const float* __restrict__ x, const float* __restrict__ partv,
                                             float* __restrict__ part) {
    const int bh = blockIdx.x, sl = blockIdx.y, b = bh >> 2;
    __shared__ float vs[512];
    const int c0 = sl * 512;
    for (int i = threadIdx.x; i < 512; i += 256) {
        float v = 0.f;
#pragma unroll
        for (int dsl = 0; dsl < 4; ++dsl) v += partv[((size_t)dsl * 64 + bh) * C_ + c0 + i];
        vs[i] = v;
    }
    __syncthreads();
    float a = 0.f;
    const float* xp = x + ((size_t)b * C_ + c0) * N_ + threadIdx.x;
#pragma unroll 8
    for (int c = 0; c < 512; ++c) a += vs[c] * xp[(size_t)c * N_];
    part[((size_t)sl * 64 + bh) * N_ + threadIdx.x] = a;
}

__global__ __launch_bounds__(256) void k_score(const float* __restrict__ part, const float* __restrict__ cst,
                                               float* __restrict__ score, float* __restrict__ out0) {
    const int b = blockIdx.x, k = threadIdx.x;
    const float scale = 0.044194173824159216f;
    float a[4];
#pragma unroll
    for (int h = 0; h < 4; ++h) {
        const int bh = b * 4 + h;
        float s = cst[bh];
#pragma unroll
        for (int sl = 0; sl < 4; ++sl) s += part[((size_t)sl * 64 + bh) * N_ + k];
        a[h] = s * scale;
    }
    float mx = fmaxf(fmaxf(a[0], a[1]), fmaxf(a[2], a[3]));
    float e0 = expf(a[0] - mx), e1 = expf(a[1] - mx), e2 = expf(a[2] - mx), e3 = expf(a[3] - mx);
    float inv = 1.0f / (e0 + e1 + e2 + e3);
    float r[4] = { e0 * inv, e1 * inv, e2 * inv, e3 * inv };
#pragma unroll
    for (int h = 0; h < 4; ++h) {
        score[(size_t)(b * 4 + h) * N_ + k] = r[h];
        out0[(size_t)(b * 4 + h) * N_ + k] = r[h];
    }
}

// ---------------- fp8 8-phase MFMA GEMMs ----------------
// proj: M=(b,n)=4096, N=(qk,h,d)=4096, K=2048. A=xbT8(x8), B=qw8/kw8(x64) -> /512 + bias -> bf16.
__global__ __launch_bounds__(512, 2) void k_proj(const u8* __restrict__ xbT8,
                                                 const u8* __restrict__ qw8, const u8* __restrict__ kw8,
                                                 const float* __restrict__ qb, const float* __restrict__ kb,
                                                 ushort_t* __restrict__ QKbuf) {
    __shared__ __align__(16) ldsf8_t lds;
    const int wg = xcd_swz(blockIdx.x, 256);
    const int quad = wg >> 2;
    const int mt = quad >> 2;                 // 0..15
    const int nt = (quad & 3) * 4 + (wg & 3); // 0..15
    const int c0 = nt * 256;
    const int qk = c0 >> 11;
    const int rem = c0 & 2047;                // h*512 + d0
    const u8* A  = xbT8 + (size_t)mt * 256 * C_;
    const u8* Bm = (qk ? kw8 : qw8) + (size_t)rem * C_;
    const float* bias  = (qk ? kb : qb) + rem;
    const int K = C_;

    fx4 acc[8][4];
#pragma unroll
    for (int i = 0; i < 8; ++i)
#pragma unroll
        for (int j = 0; j < 4; ++j) acc[i][j] = (fx4){0.f, 0.f, 0.f, 0.f};
    gemm256_f8(A, Bm, K, lds, acc);

    EPI256_IDX();
#pragma unroll
    for (int i = 0; i < 8; ++i)
#pragma unroll
        for (int n = 0; n < 4; ++n)
#pragma unroll
            for (int r = 0; r < 4; ++r) {
                const int gr = mt * 256 + wmr + i * 16 + lhi * 4 + r;
                const int bq = gr >> 8, nn = gr & 255;
                const int lc = wnr + n * 16 + l16;
                const int hh = (rem + lc) >> 9, dl = (rem + lc) & 511;
                const float v = acc[i][n][r] * (1.0f / 512.0f) + bias[lc];
                QKbuf[((((size_t)(qk * 16 + bq) * 4 + hh) * 256) + nn) * 512 + dl] = f2bs(v);
            }
}

// out: per h, M=e=2048, N=(b,n)=4096, K=2048. A=vw8(x64), B=Tt8(x16) -> /1024 + vb + score*x.
__global__ __launch_bounds__(512, 2) void k_out(const u8* __restrict__ vw8, const float* __restrict__ vb,
                                                const u8* __restrict__ Tt8, const float* __restrict__ score,
                                                const ushort_t* __restrict__ xb, float* __restrict__ out1) {
    __shared__ __align__(16) ldsf8_t lds;
    const int wg = xcd_swz(blockIdx.x, 512);
    const int h = wg >> 7, l = wg & 127;
    const int quad = l >> 2;
    const int mt = quad >> 2;                 // 0..7
    const int nt = (quad & 3) * 4 + (l & 3);  // 0..15
    const u8* A  = vw8 + (size_t)h * C_ * C_ + (size_t)mt * 256 * C_;
    const u8* Bm = Tt8 + (size_t)h * 16 * N_ * C_ + (size_t)nt * 256 * C_;
    const int K = C_;

    fx4 acc[8][4];
#pragma unroll
    for (int i = 0; i < 8; ++i)
#pragma unroll
        for (int j = 0; j < 4; ++j) acc[i][j] = (fx4){0.f, 0.f, 0.f, 0.f};
    gemm256_f8(A, Bm, K, lds, acc);

    EPI256_IDX();
#pragma unroll
    for (int i = 0; i < 8; ++i)
#pragma unroll
        for (int n = 0; n < 4; ++n)
#pragma unroll
            for (int r = 0; r < 4; ++r) {
                const int e = mt * 256 + wmr + i * 16 + lhi * 4 + r;
                const int col = nt * 256 + wnr + n * 16 + l16;
                const int b = col >> 8, nn = col & 255;
                float v = acc[i][n][r] * (1.0f / 1024.0f) + vb[h * C_ + e]
                        + score[(size_t)(b * 4 + h) * N_ + nn] * bs2f(xb[((size_t)b * C_ + e) * N_ + nn]);
                out1[((size_t)(b * 4 + h) * C_ + e) * N_ + nn] = v;
            }
}

// T: per b, M=(h,q)=1024, N=c=2048, K=256. A=Pb8(x256), B=xb8(x8) -> acc/2048, store fp8 x16.
__global__ __launch_bounds__(512, 2) void k_T8(const u8* __restrict__ Pb8, const u8* __restrict__ xb8,
                                               u8* __restrict__ Tt8) {
    __shared__ __align__(16) ldsf8_t lds;
    const int wg = xcd_swz(blockIdx.x, 512);
    const int b = wg >> 5, l = wg & 31;       // 16 b x (4 mt x 8 nt)
    const int mt = l >> 3, nt = l & 7;
    const u8* A  = Pb8 + ((size_t)b * 1024 + mt * 256) * 256;
    const u8* Bm = xb8 + ((size_t)b * 2048 + nt * 256) * 256;
    const int K = N_;

    fx4 acc[8][4];
#pragma unroll
    for (int i = 0; i < 8; ++i)
#pragma unroll
        for (int j = 0; j < 4; ++j) acc[i][j] = (fx4){0.f, 0.f, 0.f, 0.f};
    gemm256_f8(A, Bm, K, lds, acc);

    EPI256_IDX();
#pragma unroll
    for (int i = 0; i < 8; ++i)
#pragma unroll
        for (int n = 0; n < 4; ++n)
#pragma unroll
            for (int r = 0; r < 4; ++r) {
                const int rowm = mt * 256 + wmr + i * 16 + lhi * 4 + r;
                const int h = rowm >> 8, q = rowm & 255;
                const int c = nt * 256 + wnr + n * 16 + l16;
                // unscale 1/(256*8), restore T, then store T*16 as fp8:
                Tt8[(((size_t)h * 16 + b) * 256 + q) * 2048 + c] = f2f8(acc[i][n][r] * 0.0078125f);
            }
}

// sim: per bh, 128x128 tiles, K=512 (bf16 2-phase core). simf f32.
__global__ __launch_bounds__(256) void k_sim(const ushort_t* __restrict__ QKbuf, float* __restrict__ simf) {
    const int wg = blockIdx.x;
    const int bh = wg >> 2, mt = (wg >> 1) & 1, ntl = wg & 1;
    const ushort_t* Qr = QKbuf;
    const ushort_t* Kr = QKbuf + (size_t)16 * 4 * 256 * 512;
    const ushort_t* A = Qr + ((size_t)bh * 256 + mt * 128) * 512;
    const ushort_t* Bm = Kr + ((size_t)bh * 256 + ntl * 128) * 512;

    fx4 acc[4][4];
#pragma unroll
    for (int i = 0; i < 4; ++i)
#pragma unroll
        for (int j = 0; j < 4; ++j) acc[i][j] = (fx4){0.f, 0.f, 0.f, 0.f};
    mfma_core(A, Bm, D_, acc);

    EPI_IDX();
    const float scale = 0.044194173824159216f;
#pragma unroll
    for (int i = 0; i < 4; ++i)
#pragma unroll
        for (int j = 0; j < 4; ++j)
#pragma unroll
            for (int r = 0; r < 4; ++r) {
                const int q = mt * 128 + wm + i * 16 + lhi * 4 + r;
                const int k = ntl * 128 + wn + j * 16 + l16;
                simf[(size_t)bh * N_ * N_ + (size_t)q * N_ + k] = acc[i][j][r] * scale;
            }
}

__global__ __launch_bounds__(64) void k_softP(const float* __restrict__ simf, u8* __restrict__ Pb8) {
    const size_t row = blockIdx.x;
    const float* p = simf + row * N_;
    u8* o = Pb8 + row * N_;
    const int t = threadIdx.x;
    float v0 = p[t], v1 = p[t + 64], v2 = p[t + 128], v3 = p[t + 192];
    float mx = fmaxf(fmaxf(v0, v1), fmaxf(v2, v3));
#pragma unroll
    for (int off = 32; off; off >>= 1) mx = fmaxf(mx, __shfl_xor(mx, off, 64));
    float e0 = expf(v0 - mx), e1 = expf(v1 - mx), e2 = expf(v2 - mx), e3 = expf(v3 - mx);
    float s = e0 + e1 + e2 + e3;
#pragma unroll
    for (int off = 32; off; off >>= 1) s += __shfl_xor(s, off, 64);
    const float inv = 256.0f / s;     // store P * 256 as fp8
    o[t] = f2f8(e0 * inv); o[t + 64] = f2f8(e1 * inv);
    o[t + 128] = f2f8(e2 * inv); o[t + 192] = f2f8(e3 * inv);
}

extern "C" void kernel_launch(void* const* d_in, const int* in_sizes, int n_in,
                              void* d_out, int out_size, void* d_ws, size_t ws_size,
                              hipStream_t stream)
{
    const float* x  = (const float*)d_in[0];
    const float* qw = (const float*)d_in[1];
    const float* qb = (const float*)d_in[2];
    const float* kw = (const float*)d_in[3];
    const float* kb = (const float*)d_in[4];
    const float* vw = (const float*)d_in[5];
    const float* vb = (const float*)d_in[6];

    float* out0 = (float*)d_out;
    float* out1 = out0 + (size_t)B_ * HEADS_ * N_;

    char* w = (char*)d_ws;
    u8*       vw8  = (u8*)w;        w += (size_t)4 * C_ * C_;              // 16.8MB
    u8*       qw8  = (u8*)w;        w += (size_t)4 * D_ * C_;              // 4.2MB
    u8*       kw8  = (u8*)w;        w += (size_t)4 * D_ * C_;              // 4.2MB
    ushort_t* xb   = (ushort_t*)w;  w += (size_t)B_ * C_ * N_ * 2;         // 16.8MB (bf16, gating)
    u8*       xb8  = (u8*)w;        w += (size_t)B_ * C_ * N_;             // 8.4MB
    u8*       xbT8 = (u8*)w;        w += (size_t)B_ * N_ * C_;             // 8.4MB
    ushort_t* QKbuf= (ushort_t*)w;  w += (size_t)2 * 16 * 4 * 256 * 512 * 2; // 33.6MB bf16
    u8*       Pb8  = (u8*)w;        w += (size_t)64 * N_ * N_;             // 4.2MB
    float*    simf = (float*)w;     w += (size_t)64 * N_ * N_ * 4;         // 16.8MB
    u8*       Tt8  = (u8*)w;        w += (size_t)64 * N_ * C_;             // 33.6MB
    float*    xpart= (float*)w;     w += (size_t)8 * B_ * C_ * 4;          // 1MB
    float*    xsum = (float*)w;     w += (size_t)B_ * C_ * 4;
    float*    qsum = (float*)w;     w += (size_t)64 * D_ * 4;
    float*    cst  = (float*)w;     w += 1024;
    float*    partv= (float*)w;     w += (size_t)4 * 64 * C_ * 4;          // 2.1MB
    float*    part = (float*)w;     w += (size_t)4 * 64 * N_ * 4;
    float*    score= (float*)w;     w += (size_t)64 * N_ * 4;

    // casts (weights x64 -> fp8; x -> bf16 + fp8 x8 + transposed fp8 x8)
    k_castw8<<<dim3(4 * D_ * C_ / 4 / 256), 256, 0, stream>>>(qw, qw8, 4 * D_ * C_, 64.0f);
    k_castw8<<<dim3(4 * D_ * C_ / 4 / 256), 256, 0, stream>>>(kw, kw8, 4 * D_ * C_, 64.0f);
    k_castw8<<<dim3(4 * C_ * C_ / 4 / 256), 256, 0, stream>>>(vw, vw8, 4 * C_ * C_, 64.0f);
    k_cast_x<<<dim3(8, 64, 16), 256, 0, stream>>>(x, xb, xb8, xbT8, xpart);

    // exact-f32 score path
    k_xsum2<<<dim3(8, 16), 256, 0, stream>>>(xpart, xsum);
    k_qsum <<<dim3(512), 256, 0, stream>>>(xsum, qw, qb, qsum);
    k_const<<<dim3(64), 64, 0, stream>>>(qsum, kb, cst);
    k_vecp <<<dim3(8, 4, 4), 256, 0, stream>>>(qsum, kw, partv);
    k_att  <<<dim3(64, 4), 256, 0, stream>>>(x, partv, part);
    k_score<<<dim3(16), 256, 0, stream>>>(part, cst, score, out0);

    // MFMA pipeline
    k_proj <<<dim3(256), 512, 0, stream>>>(xbT8, qw8, kw8, qb, kb, QKbuf);
    k_sim  <<<dim3(256), 256, 0, stream>>>(QKbuf, simf);
    k_softP<<<dim3(64 * N_), 64, 0, stream>>>(simf, Pb8);
    k_T8   <<<dim3(512), 512, 0, stream>>>(Pb8, xb8, Tt8);
    k_out  <<<dim3(512), 512, 0, stream>>>(vw8, vb, Tt8, score, xb, out1);
}

// Round 9
// 364.253 us; speedup vs baseline: 8.4781x; 1.0081x over previous
//
#include <hip/hip_runtime.h>
#include <hip/hip_bf16.h>
#include <hip/hip_fp8.h>

#define B_ 16
#define C_ 2048
#define N_ 256
#define HEADS_ 4
#define D_ 512

typedef unsigned int u32;
typedef unsigned char u8;
typedef unsigned short ushort_t;
typedef __attribute__((ext_vector_type(8))) short bfx8;
typedef __attribute__((ext_vector_type(4))) float fx4;

__device__ __forceinline__ unsigned short f2bs(float f) {
    __hip_bfloat16 h = __float2bfloat16(f);
    return __builtin_bit_cast(unsigned short, h);
}
__device__ __forceinline__ float bs2f(ushort_t u) {
    u32 v = ((u32)u) << 16;
    return __builtin_bit_cast(float, v);
}
__device__ __forceinline__ u8 f2f8(float f) {
    return (u8)__hip_cvt_float_to_fp8(f, __HIP_SATFINITE, __HIP_E4M3);
}
__device__ __forceinline__ void gload16(const void* g, void* l) {
    __builtin_amdgcn_global_load_lds((const __attribute__((address_space(1))) u32*)g,
                                     (__attribute__((address_space(3))) u32*)l, 16, 0, 0);
}
__device__ __forceinline__ int xcd_swz(int bid, int nwg) {
    return (bid & 7) * (nwg >> 3) + (bid >> 3);
}

#define SBAR() __builtin_amdgcn_s_barrier()
#define LGKM0() do { asm volatile("s_waitcnt lgkmcnt(0)" ::: "memory"); \
                     __builtin_amdgcn_sched_barrier(0); } while (0)

// ======================= 256x256 merged-phase counted-vmcnt FP8 core =======================
// NT GEMM fp8 e4m3: acc[8][4] (wave 128x64) += A[256][K] * B[256][K]^T, K%128==0.
// 512 thr = 8 waves (2Mw x 4Nw). LDS 64 KiB. 2 phases per K-tile(64): each phase =
// {12 ds_read_b64; stage 2 regions; barrier; lgkm0; 32 MFMA (setprio); vmcnt(4); barrier}.
// Halves sync-point count vs the 4-phase variant (per-phase overhead was the binder).
#define VMW4() asm volatile("s_waitcnt vmcnt(4)" ::: "memory")

#define STAGEF8(MAT, BUF, KH, J) do {                                         \
    const u8* s_ = (MAT) ? Bm : A;                                            \
    const int r_ = tid >> 1;                                                  \
    const int k_ = (J) * 64 + (KH) * 32 + (((tid & 1) ^ ((tid >> 3) & 1)) * 16); \
    gload16(s_ + (size_t)r_ * K + k_,                                         \
            (u8*)(&lds[MAT][BUF][KH][0][0]) + tid * 16);                      \
} while (0)

#define LDAF8(dst, BUF, KH, MH) do {                                          \
    _Pragma("unroll")                                                         \
    for (int i_ = 0; i_ < 4; ++i_)                                            \
        dst[i_] = *(const long*)(&lds[0][BUF][KH][wmr + (MH) * 64 + i_ * 16 + l16][f8off]); \
} while (0)

#define LDBF8(dst, BUF, KH) do {                                              \
    _Pragma("unroll")                                                         \
    for (int i_ = 0; i_ < 4; ++i_)                                            \
        dst[i_] = *(const long*)(&lds[1][BUF][KH][wnr + i_ * 16 + l16][f8off]); \
} while (0)

#define MMF8(aa, bb, MH) do {                                                 \
    _Pragma("unroll")                                                         \
    for (int i_ = 0; i_ < 4; ++i_) {                                          \
        _Pragma("unroll")                                                     \
        for (int n_ = 0; n_ < 4; ++n_)                                        \
            acc[(MH) * 4 + i_][n_] = __builtin_amdgcn_mfma_f32_16x16x32_fp8_fp8( \
                aa[i_], bb[n_], acc[(MH) * 4 + i_][n_], 0, 0, 0);             \
    }                                                                         \
} while (0)

// One K-tile of 64 = 2 merged phases. BUF literal 0/1.
#define KTILE2F8(BUF, JS1, JS2) do {                                          \
    long a0[4], a1[4], b0[4];                                                 \
    /* phase 0: kh0, both row-halves (32 MFMA) */                             \
    LDAF8(a0, BUF, 0, 0); LDAF8(a1, BUF, 0, 1); LDBF8(b0, BUF, 0);            \
    STAGEF8(0, BUF ^ 1, 1, JS1);                                              \
    STAGEF8(1, BUF ^ 1, 1, JS1);                                              \
    SBAR(); LGKM0();                                                          \
    __builtin_amdgcn_s_setprio(1);                                            \
    MMF8(a0, b0, 0); MMF8(a1, b0, 1);                                         \
    __builtin_amdgcn_s_setprio(0);                                            \
    VMW4();                                                                   \
    SBAR();                                                                   \
    /* phase 1: kh1, both row-halves */                                       \
    LDAF8(a0, BUF, 1, 0); LDAF8(a1, BUF, 1, 1); LDBF8(b0, BUF, 1);            \
    STAGEF8(0, BUF, 0, JS2);                                                  \
    STAGEF8(1, BUF, 0, JS2);                                                  \
    SBAR(); LGKM0();                                                          \
    __builtin_amdgcn_s_setprio(1);                                            \
    MMF8(a0, b0, 0); MMF8(a1, b0, 1);                                         \
    __builtin_amdgcn_s_setprio(0);                                            \
    VMW4();                                                                   \
    SBAR();                                                                   \
} while (0)

typedef u8 ldsf8_t[2][2][2][256][32];   // [mat][buf][kh][row][32B] = 64 KiB

__device__ __forceinline__ void gemm256_f8(const u8* __restrict__ A,
                                           const u8* __restrict__ Bm,
                                           int K, ldsf8_t& lds, fx4 acc[8][4])
{
    const int tid = threadIdx.x;
    const int lane = tid & 63;
    const int w = tid >> 6;
    const int l16 = lane & 15, lhi = lane >> 4;
    const int f8off = (((lhi >> 1) ^ ((l16 >> 2) & 1)) * 16) + (lhi & 1) * 8;
    const int wmr = (w >> 2) * 128;
    const int wnr = (w & 3) * 64;
    const int nkt = K >> 6;                           // even, >= 4

    // prologue: tile0 (k0,k1) + tile1 k0 = 6 loads/thread
    STAGEF8(0, 0, 0, 0); STAGEF8(1, 0, 0, 0);
    STAGEF8(0, 0, 1, 0); STAGEF8(1, 0, 1, 0);
    STAGEF8(0, 1, 0, 1); STAGEF8(1, 1, 0, 1);
    VMW4();
    SBAR();

    for (int jj = 0; jj < nkt; jj += 2) {
        const int js1a = jj + 1;
        const int js2a = (jj + 2 < nkt) ? jj + 2 : nkt - 1;
        const int js1b = js2a;
        const int js2b = (jj + 3 < nkt) ? jj + 3 : nkt - 1;
        KTILE2F8(0, js1a, js2a);
        KTILE2F8(1, js1b, js2b);
    }
    asm volatile("s_waitcnt vmcnt(0)" ::: "memory");  // drain before epilogue/exit
    SBAR();
}

#define EPI256_IDX() \
    const int lane = threadIdx.x & 63, w = threadIdx.x >> 6; \
    const int l16 = lane & 15, lhi = lane >> 4; \
    const int wmr = (w >> 2) * 128, wnr = (w & 3) * 64;

// ---------------- 128x128 2-phase bf16 core (k_sim only), T2-swizzled ----------------
__device__ __forceinline__ void mfma_core(const ushort_t* __restrict__ A,
                                          const ushort_t* __restrict__ Bm,
                                          int K, fx4 acc[4][4])
{
    __shared__ __align__(16) ushort_t As[128 * 32];
    __shared__ __align__(16) ushort_t Bs[128 * 32];
    const int tid = threadIdx.x;
    const int lane = tid & 63, wave = tid >> 6;
    const int l16 = lane & 15, lhi = lane >> 4;
    const int swz8 = (lhi ^ ((l16 >> 1) & 3)) * 8;
    const int wm = (wave >> 1) * 64, wn = (wave & 1) * 64;

    for (int k0 = 0; k0 < K; k0 += 32) {
        const int f0 = tid, f1 = tid + 256;
        gload16(A + (size_t)(f0 >> 2) * K + k0 + (((f0 & 3) ^ ((f0 >> 3) & 3)) * 8), As + f0 * 8);
        gload16(A + (size_t)(f1 >> 2) * K + k0 + (((f1 & 3) ^ ((f1 >> 3) & 3)) * 8), As + f1 * 8);
        gload16(Bm + (size_t)(f0 >> 2) * K + k0 + (((f0 & 3) ^ ((f0 >> 3) & 3)) * 8), Bs + f0 * 8);
        gload16(Bm + (size_t)(f1 >> 2) * K + k0 + (((f1 & 3) ^ ((f1 >> 3) & 3)) * 8), Bs + f1 * 8);
        __syncthreads();
        bfx8 af[4], bfr[4];
#pragma unroll
        for (int i = 0; i < 4; ++i)
            af[i] = *(const bfx8*)(As + (wm + i * 16 + l16) * 32 + swz8);
#pragma unroll
        for (int j = 0; j < 4; ++j)
            bfr[j] = *(const bfx8*)(Bs + (wn + j * 16 + l16) * 32 + swz8);
#pragma unroll
        for (int i = 0; i < 4; ++i)
#pragma unroll
            for (int j = 0; j < 4; ++j)
                acc[i][j] = __builtin_amdgcn_mfma_f32_16x16x32_bf16(af[i], bfr[j], acc[i][j], 0, 0, 0);
        __syncthreads();
    }
}

#define EPI_IDX() \
    const int lane = threadIdx.x & 63, wave = threadIdx.x >> 6; \
    const int l16 = lane & 15, lhi = lane >> 4; \
    const int wm = (wave >> 1) * 64, wn = (wave & 1) * 64;

// ---------------- casts ----------------
__global__ __launch_bounds__(256) void k_castw8(const float* __restrict__ s, u8* __restrict__ d,
                                                int n, float scale) {
    int i = (blockIdx.x * 256 + threadIdx.x) * 4;
    if (i >= n) return;
    float4 v = *(const float4*)(s + i);
    uchar4 o = { f2f8(v.x * scale), f2f8(v.y * scale), f2f8(v.z * scale), f2f8(v.w * scale) };
    *(uchar4*)(d + i) = o;
}

// x[b][c][n] -> xb bf16 [b][c][n], xb8 fp8x8 [b][c][n], xbT8 fp8x8 [b][n][c], xpart partial sums
__global__ __launch_bounds__(256) void k_cast_x(const float* __restrict__ x,
                                                ushort_t* __restrict__ xb, u8* __restrict__ xb8,
                                                u8* __restrict__ xbT8, float* __restrict__ xpart) {
    __shared__ float t[32][33];
    const int b = blockIdx.z, c0 = blockIdx.y * 32, n0 = blockIdx.x * 32;
    const int tn = threadIdx.x & 31, tc8 = threadIdx.x >> 5;
    const float* xp = x + ((size_t)b * C_ + c0) * N_ + n0;
#pragma unroll
    for (int p = 0; p < 4; ++p) {
        int cc = tc8 + p * 8;
        float v = xp[(size_t)cc * N_ + tn];
        t[cc][tn] = v;
        xb[((size_t)b * C_ + c0 + cc) * N_ + n0 + tn] = f2bs(v);
        xb8[((size_t)b * C_ + c0 + cc) * N_ + n0 + tn] = f2f8(v * 8.0f);
        float s = v;
#pragma unroll
        for (int o = 16; o; o >>= 1) s += __shfl_xor(s, o, 32);
        if (tn == 0) xpart[(size_t)blockIdx.x * B_ * C_ + (size_t)b * C_ + c0 + cc] = s;
    }
    __syncthreads();
#pragma unroll
    for (int p = 0; p < 4; ++p) {
        int nn = tc8 + p * 8;
        xbT8[((size_t)b * N_ + n0 + nn) * C_ + c0 + tn] = f2f8(t[tn][nn] * 8.0f);
    }
}

__global__ __launch_bounds__(256) void k_xsum2(const float* __restrict__ xpart, float* __restrict__ xsum) {
    const int c = blockIdx.x * 256 + threadIdx.x, b = blockIdx.y;
    float s = 0.f;
#pragma unroll
    for (int t = 0; t < 8; ++t) s += xpart[(size_t)t * B_ * C_ + (size_t)b * C_ + c];
    xsum[(size_t)b * C_ + c] = s;
}

// ---------------- exact-f32 score path ----------------
__global__ __launch_bounds__(256) void k_qsum(const float* __restrict__ xsum, const float* __restrict__ qw,
                                              const float* __restrict__ qb, float* __restrict__ qsum) {
    const int wave = threadIdx.x >> 6, lane = threadIdx.x & 63;
    const int row = blockIdx.x * 4 + wave;            // h*512+d, in [0, 2048)
    const int h = row >> 9, d = row & 511;
    const float* wr = qw + (size_t)row * C_;
    float acc[16];
#pragma unroll
    for (int bb = 0; bb < 16; ++bb) acc[bb] = 0.f;
    for (int it = 0; it < C_ / 64; ++it) {
        const int c = it * 64 + lane;
        const float w = wr[c];
#pragma unroll
        for (int bb = 0; bb < 16; ++bb) acc[bb] += xsum[(size_t)bb * C_ + c] * w;
    }
#pragma unroll
    for (int bb = 0; bb < 16; ++bb) {
        float s = acc[bb];
#pragma unroll
        for (int o = 32; o; o >>= 1) s += __shfl_xor(s, o, 64);
        if (lane == 0) qsum[(size_t)((bb << 2) | h) * D_ + d] = s + 256.0f * qb[row];
    }
}

__global__ __launch_bounds__(64) void k_const(const float* __restrict__ qsum, const float* __restrict__ kb,
                                              float* __restrict__ cst) {
    const int bh = blockIdx.x, h = bh & 3, lane = threadIdx.x;
    float s = 0.f;
    for (int d = lane; d < D_; d += 64) s += qsum[(size_t)bh * D_ + d] * kb[h * D_ + d];
#pragma unroll
    for (int o = 32; o; o >>= 1) s += __shfl_xor(s, o, 64);
    if (lane == 0) cst[bh] = s;
}

__global__ __launch_bounds__(256) void k_vecp(const float* __restrict__ qsum, const float* __restrict__ kw,
                                              float* __restrict__ partv) {
    const int ct = blockIdx.x, h = blockIdx.y, dsl = blockIdx.z;
    __shared__ float qs[16 * 128];
    for (int i = threadIdx.x; i < 16 * 128; i += 256) {
        int bb = i >> 7, dd = i & 127;
        qs[i] = qsum[(size_t)((bb << 2) | h) * D_ + dsl * 128 + dd];
    }
    __syncthreads();
    const int c = ct * 256 + threadIdx.x;
    const float* wp = kw + ((size_t)h * D_ + dsl * 128) * C_ + c;
    float acc[16];
#pragma unroll
    for (int bb = 0; bb < 16; ++bb) acc[bb] = 0.f;
    for (int dd = 0; dd < 128; ++dd) {
        const float w = wp[(size_t)dd * C_];
#pragma unroll
        for (int bb = 0; bb < 16; ++bb) acc[bb] += qs[bb * 128 + dd] * w;
    }
#pragma unroll
    for (int bb = 0; bb < 16; ++bb)
        partv[((size_t)dsl * 64 + ((bb << 2) | h)) * C_ + c] = acc[bb];
}

__global__ __launch_bounds__(256) void k_att(const float* __restrict__ x, const float* __restrict__ partv,
                                             float* __restrict__ part) {
    const int bh = blockIdx.x, sl = blockIdx.y, b = bh >> 2;
    __shared__ float vs[512];
    const int c0 = sl * 512;
    for (int i = threadIdx.x; i < 512; i += 256) {
        float v = 0.f;
#pragma unroll
        for (int dsl = 0; dsl < 4; ++dsl) v += partv[((size_t)dsl * 64 + bh) * C_ + c0 + i];
        vs[i] = v;
    }
    __syncthreads();
    float a = 0.f;
    const float* xp = x + ((size_t)b * C_ + c0) * N_ + threadIdx.x;
#pragma unroll 8
    for (int c = 0; c < 512; ++c) a += vs[c] * xp[(size_t)c * N_];
    part[((size_t)sl * 64 + bh) * N_ + threadIdx.x] = a;
}

__global__ __launch_bounds__(256) void k_score(const float* __restrict__ part, const float* __restrict__ cst,
                                               float* __restrict__ score, float* __restrict__ out0) {
    const int b = blockIdx.x, k = threadIdx.x;
    const float scale = 0.044194173824159216f;
    float a[4];
#pragma unroll
    for (int h = 0; h < 4; ++h) {
        const int bh = b * 4 + h;
        float s = cst[bh];
#pragma unroll
        for (int sl = 0; sl < 4; ++sl) s += part[((size_t)sl * 64 + bh) * N_ + k];
        a[h] = s * scale;
    }
    float mx = fmaxf(fmaxf(a[0], a[1]), fmaxf(a[2], a[3]));
    float e0 = expf(a[0] - mx), e1 = expf(a[1] - mx), e2 = expf(a[2] - mx), e3 = expf(a[3] - mx);
    float inv = 1.0f / (e0 + e1 + e2 + e3);
    float r[4] = { e0 * inv, e1 * inv, e2 * inv, e3 * inv };
#pragma unroll
    for (int h = 0; h < 4; ++h) {
        score[(size_t)(b * 4 + h) * N_ + k] = r[h];
        out0[(size_t)(b * 4 + h) * N_ + k] = r[h];
    }
}

// ---------------- fp8 merged-phase MFMA GEMMs ----------------
// proj: M=(b,n)=4096, N=(qk,h,d)=4096, K=2048. A=xbT8(x8), B=qw8/kw8(x64) -> /512 + bias -> bf16.
__global__ __launch_bounds__(512, 2) void k_proj(const u8* __restrict__ xbT8,
                                                 const u8* __restrict__ qw8, const u8* __restrict__ kw8,
                                                 const float* __restrict__ qb, const float* __restrict__ kb,
                                                 ushort_t* __restrict__ QKbuf) {
    __shared__ __align__(16) ldsf8_t lds;
    const int wg = xcd_swz(blockIdx.x, 256);
    const int quad = wg >> 2;
    const int mt = quad >> 2;                 // 0..15
    const int nt = (quad & 3) * 4 + (wg & 3); // 0..15
    const int c0 = nt * 256;
    const int qk = c0 >> 11;
    const int rem = c0 & 2047;                // h*512 + d0
    const u8* A  = xbT8 + (size_t)mt * 256 * C_;
    const u8* Bm = (qk ? kw8 : qw8) + (size_t)rem * C_;
    const float* bias  = (qk ? kb : qb) + rem;
    const int K = C_;

    fx4 acc[8][4];
#pragma unroll
    for (int i = 0; i < 8; ++i)
#pragma unroll
        for (int j = 0; j < 4; ++j) acc[i][j] = (fx4){0.f, 0.f, 0.f, 0.f};
    gemm256_f8(A, Bm, K, lds, acc);

    EPI256_IDX();
#pragma unroll
    for (int i = 0; i < 8; ++i)
#pragma unroll
        for (int n = 0; n < 4; ++n)
#pragma unroll
            for (int r = 0; r < 4; ++r) {
                const int gr = mt * 256 + wmr + i * 16 + lhi * 4 + r;
                const int bq = gr >> 8, nn = gr & 255;
                const int lc = wnr + n * 16 + l16;
                const int hh = (rem + lc) >> 9, dl = (rem + lc) & 511;
                const float v = acc[i][n][r] * (1.0f / 512.0f) + bias[lc];
                QKbuf[((((size_t)(qk * 16 + bq) * 4 + hh) * 256) + nn) * 512 + dl] = f2bs(v);
            }
}

// out: per h, M=e=2048, N=(b,n)=4096, K=2048. A=vw8(x64), B=Tt8(x16) -> /1024 + vb + score*x.
__global__ __launch_bounds__(512, 2) void k_out(const u8* __restrict__ vw8, const float* __restrict__ vb,
                                                const u8* __restrict__ Tt8, const float* __restrict__ score,
                                                const ushort_t* __restrict__ xb, float* __restrict__ out1) {
    __shared__ __align__(16) ldsf8_t lds;
    const int wg = xcd_swz(blockIdx.x, 512);
    const int h = wg >> 7, l = wg & 127;
    const int quad = l >> 2;
    const int mt = quad >> 2;                 // 0..7
    const int nt = (quad & 3) * 4 + (l & 3);  // 0..15
    const u8* A  = vw8 + (size_t)h * C_ * C_ + (size_t)mt * 256 * C_;
    const u8* Bm = Tt8 + (size_t)h * 16 * N_ * C_ + (size_t)nt * 256 * C_;
    const int K = C_;

    fx4 acc[8][4];
#pragma unroll
    for (int i = 0; i < 8; ++i)
#pragma unroll
        for (int j = 0; j < 4; ++j) acc[i][j] = (fx4){0.f, 0.f, 0.f, 0.f};
    gemm256_f8(A, Bm, K, lds, acc);

    EPI256_IDX();
#pragma unroll
    for (int i = 0; i < 8; ++i)
#pragma unroll
        for (int n = 0; n < 4; ++n)
#pragma unroll
            for (int r = 0; r < 4; ++r) {
                const int e = mt * 256 + wmr + i * 16 + lhi * 4 + r;
                const int col = nt * 256 + wnr + n * 16 + l16;
                const int b = col >> 8, nn = col & 255;
                float v = acc[i][n][r] * (1.0f / 1024.0f) + vb[h * C_ + e]
                        + score[(size_t)(b * 4 + h) * N_ + nn] * bs2f(xb[((size_t)b * C_ + e) * N_ + nn]);
                out1[((size_t)(b * 4 + h) * C_ + e) * N_ + nn] = v;
            }
}

// T: per b, M=(h,q)=1024, N=c=2048, K=256. A=Pb8(x256), B=xb8(x8) -> acc/2048, store fp8 x16.
__global__ __launch_bounds__(512, 2) void k_T8(const u8* __restrict__ Pb8, const u8* __restrict__ xb8,
                                               u8* __restrict__ Tt8) {
    __shared__ __align__(16) ldsf8_t lds;
    const int wg = xcd_swz(blockIdx.x, 512);
    const int b = wg >> 5, l = wg & 31;       // 16 b x (4 mt x 8 nt)
    const int mt = l >> 3, nt = l & 7;
    const u8* A  = Pb8 + ((size_t)b * 1024 + mt * 256) * 256;
    const u8* Bm = xb8 + ((size_t)b * 2048 + nt * 256) * 256;
    const int K = N_;

    fx4 acc[8][4];
#pragma unroll
    for (int i = 0; i < 8; ++i)
#pragma unroll
        for (int j = 0; j < 4; ++j) acc[i][j] = (fx4){0.f, 0.f, 0.f, 0.f};
    gemm256_f8(A, Bm, K, lds, acc);

    EPI256_IDX();
#pragma unroll
    for (int i = 0; i < 8; ++i)
#pragma unroll
        for (int n = 0; n < 4; ++n)
#pragma unroll
            for (int r = 0; r < 4; ++r) {
                const int rowm = mt * 256 + wmr + i * 16 + lhi * 4 + r;
                const int h = rowm >> 8, q = rowm & 255;
                const int c = nt * 256 + wnr + n * 16 + l16;
                // unscale 1/(256*8), restore T, then store T*16 as fp8:
                Tt8[(((size_t)h * 16 + b) * 256 + q) * 2048 + c] = f2f8(acc[i][n][r] * 0.0078125f);
            }
}

// sim: per bh, 128x128 tiles, K=512 (bf16 2-phase core). simf f32.
__global__ __launch_bounds__(256) void k_sim(const ushort_t* __restrict__ QKbuf, float* __restrict__ simf) {
    const int wg = blockIdx.x;
    const int bh = wg >> 2, mt = (wg >> 1) & 1, ntl = wg & 1;
    const ushort_t* Qr = QKbuf;
    const ushort_t* Kr = QKbuf + (size_t)16 * 4 * 256 * 512;
    const ushort_t* A = Qr + ((size_t)bh * 256 + mt * 128) * 512;
    const ushort_t* Bm = Kr + ((size_t)bh * 256 + ntl * 128) * 512;

    fx4 acc[4][4];
#pragma unroll
    for (int i = 0; i < 4; ++i)
#pragma unroll
        for (int j = 0; j < 4; ++j) acc[i][j] = (fx4){0.f, 0.f, 0.f, 0.f};
    mfma_core(A, Bm, D_, acc);

    EPI_IDX();
    const float scale = 0.044194173824159216f;
#pragma unroll
    for (int i = 0; i < 4; ++i)
#pragma unroll
        for (int j = 0; j < 4; ++j)
#pragma unroll
            for (int r = 0; r < 4; ++r) {
                const int q = mt * 128 + wm + i * 16 + lhi * 4 + r;
                const int k = ntl * 128 + wn + j * 16 + l16;
                simf[(size_t)bh * N_ * N_ + (size_t)q * N_ + k] = acc[i][j][r] * scale;
            }
}

__global__ __launch_bounds__(64) void k_softP(const float* __restrict__ simf, u8* __restrict__ Pb8) {
    const size_t row = blockIdx.x;
    const float* p = simf + row * N_;
    u8* o = Pb8 + row * N_;
    const int t = threadIdx.x;
    float v0 = p[t], v1 = p[t + 64], v2 = p[t + 128], v3 = p[t + 192];
    float mx = fmaxf(fmaxf(v0, v1), fmaxf(v2, v3));
#pragma unroll
    for (int off = 32; off; off >>= 1) mx = fmaxf(mx, __shfl_xor(mx, off, 64));
    float e0 = expf(v0 - mx), e1 = expf(v1 - mx), e2 = expf(v2 - mx), e3 = expf(v3 - mx);
    float s = e0 + e1 + e2 + e3;
#pragma unroll
    for (int off = 32; off; off >>= 1) s += __shfl_xor(s, off, 64);
    const float inv = 256.0f / s;     // store P * 256 as fp8
    o[t] = f2f8(e0 * inv); o[t + 64] = f2f8(e1 * inv);
    o[t + 128] = f2f8(e2 * inv); o[t + 192] = f2f8(e3 * inv);
}

extern "C" void kernel_launch(void* const* d_in, const int* in_sizes, int n_in,
                              void* d_out, int out_size, void* d_ws, size_t ws_size,
                              hipStream_t stream)
{
    const float* x  = (const float*)d_in[0];
    const float* qw = (const float*)d_in[1];
    const float* qb = (const float*)d_in[2];
    const float* kw = (const float*)d_in[3];
    const float* kb = (const float*)d_in[4];
    const float* vw = (const float*)d_in[5];
    const float* vb = (const float*)d_in[6];

    float* out0 = (float*)d_out;
    float* out1 = out0 + (size_t)B_ * HEADS_ * N_;

    char* w = (char*)d_ws;
    u8*       vw8  = (u8*)w;        w += (size_t)4 * C_ * C_;              // 16.8MB
    u8*       qw8  = (u8*)w;        w += (size_t)4 * D_ * C_;              // 4.2MB
    u8*       kw8  = (u8*)w;        w += (size_t)4 * D_ * C_;              // 4.2MB
    ushort_t* xb   = (ushort_t*)w;  w += (size_t)B_ * C_ * N_ * 2;         // 16.8MB (bf16, gating)
    u8*       xb8  = (u8*)w;        w += (size_t)B_ * C_ * N_;             // 8.4MB
    u8*       xbT8 = (u8*)w;        w += (size_t)B_ * N_ * C_;             // 8.4MB
    ushort_t* QKbuf= (ushort_t*)w;  w += (size_t)2 * 16 * 4 * 256 * 512 * 2; // 33.6MB bf16
    u8*       Pb8  = (u8*)w;        w += (size_t)64 * N_ * N_;             // 4.2MB
    float*    simf = (float*)w;     w += (size_t)64 * N_ * N_ * 4;         // 16.8MB
    u8*       Tt8  = (u8*)w;        w += (size_t)64 * N_ * C_;             // 33.6MB
    float*    xpart= (float*)w;     w += (size_t)8 * B_ * C_ * 4;          // 1MB
    float*    xsum = (float*)w;     w += (size_t)B_ * C_ * 4;
    float*    qsum = (float*)w;     w += (size_t)64 * D_ * 4;
    float*    cst  = (float*)w;     w += 1024;
    float*    partv= (float*)w;     w += (size_t)4 * 64 * C_ * 4;          // 2.1MB
    float*    part = (float*)w;     w += (size_t)4 * 64 * N_ * 4;
    float*    score= (float*)w;     w += (size_t)64 * N_ * 4;

    // casts (weights x64 -> fp8; x -> bf16 + fp8 x8 + transposed fp8 x8)
    k_castw8<<<dim3(4 * D_ * C_ / 4 / 256), 256, 0, stream>>>(qw, qw8, 4 * D_ * C_, 64.0f);
    k_castw8<<<dim3(4 * D_ * C_ / 4 / 256), 256, 0, stream>>>(kw, kw8, 4 * D_ * C_, 64.0f);
    k_castw8<<<dim3(4 * C_ * C_ / 4 / 256), 256, 0, stream>>>(vw, vw8, 4 * C_ * C_, 64.0f);
    k_cast_x<<<dim3(8, 64, 16), 256, 0, stream>>>(x, xb, xb8, xbT8, xpart);

    // exact-f32 score path
    k_xsum2<<<dim3(8, 16), 256, 0, stream>>>(xpart, xsum);
    k_qsum <<<dim3(512), 256, 0, stream>>>(xsum, qw, qb, qsum);
    k_const<<<dim3(64), 64, 0, stream>>>(qsum, kb, cst);
    k_vecp <<<dim3(8, 4, 4), 256, 0, stream>>>(qsum, kw, partv);
    k_att  <<<dim3(64, 4), 256, 0, stream>>>(x, partv, part);
    k_score<<<dim3(16), 256, 0, stream>>>(part, cst, score, out0);

    // MFMA pipeline
    k_proj <<<dim3(256), 512, 0, stream>>>(xbT8, qw8, kw8, qb, kb, QKbuf);
    k_sim  <<<dim3(256), 256, 0, stream>>>(QKbuf, simf);
    k_softP<<<dim3(64 * N_), 64, 0, stream>>>(simf, Pb8);
    k_T8   <<<dim3(512), 512, 0, stream>>>(Pb8, xb8, Tt8);
    k_out  <<<dim3(512), 512, 0, stream>>>(vw8, vb, Tt8, score, xb, out1);
}